// Round 1
// baseline (7272.333 us; speedup 1.0000x reference)
//
#include <hip/hip_runtime.h>
#include <math.h>

// ComplexTransformerBlock: B=4 S=1024 L=256 F=512 CD=768 NH=8 (d=64) E=8 HID=2048
// Round 1: correct fp32 baseline. Routed MoE (8x fewer FLOPs than dense reference,
// numerically identical per token). All math fp32 + accurate libm; routing uses
// fp64 reductions (discrete expert index must match np reference).

#define NTOK 4096          // B*S
#define FF   512
#define NCTX 1024          // B*L
#define CDIM 768
#define NEXP 8
#define HID  2048
#define TMAX 72            // max padded 64-row tiles: (4096 + 8*63)/64 <= 71, +margin
#define NPAD (TMAX * 64)   // 4608

// ---------------------------------------------------------------- complex LN
__global__ __launch_bounds__(256)
void cln_kernel(const float* __restrict__ xr, const float* __restrict__ xi,
                const float* __restrict__ g,
                float* __restrict__ hr, float* __restrict__ hi)
{
    const int F = FF;
    long base = (long)blockIdx.x * F;
    int t = threadIdx.x;
    int j0 = t, j1 = t + 256;
    float xr0 = xr[base + j0], xi0 = xi[base + j0];
    float xr1 = xr[base + j1], xi1 = xi[base + j1];
    float a0 = sqrtf(xr0 * xr0 + xi0 * xi0 + 1e-6f);
    float a1 = sqrtf(xr1 * xr1 + xi1 * xi1 + 1e-6f);
    float s = a0 + a1;
#pragma unroll
    for (int off = 32; off >= 1; off >>= 1) s += __shfl_xor(s, off);
    __shared__ float wsum[4];
    if ((t & 63) == 0) wsum[t >> 6] = s;
    __syncthreads();
    float mean = (wsum[0] + wsum[1] + wsum[2] + wsum[3]) * (1.0f / 512.0f);
    float d0 = g[j0] * (a0 / (mean + 1e-6f)) / (a0 + 1e-6f);
    float d1 = g[j1] * (a1 / (mean + 1e-6f)) / (a1 + 1e-6f);
    hr[base + j0] = xr0 * d0;  hi[base + j0] = xi0 * d0;
    hr[base + j1] = xr1 * d1;  hi[base + j1] = xi1 * d1;
}

// ------------------------------------------------- complex GEMM (fp32, 64x64x16)
// C[M,N] = A[M,K] (*) W[K,N] + bias, complex. Optional: per-expert weights
// (EXPERT, tileExpert[tileM]), row gather through `order` (GATHER), modReLU
// epilogue (MODRELU), residual add (RESID), accumulate into C (ACC; skips bias).
template<bool EXPERT, bool GATHER, bool MODRELU, bool RESID, bool ACC>
__global__ __launch_bounds__(256)
void cgemm_kernel(const float* __restrict__ Ar, const float* __restrict__ Ai, int lda,
                  const float* __restrict__ Wr, const float* __restrict__ Wi, int ldw,
                  long wstride,
                  const float* __restrict__ br, const float* __restrict__ bi, int bstride,
                  const float* __restrict__ mb,
                  const float* __restrict__ Rr, const float* __restrict__ Ri,
                  float* __restrict__ Cr, float* __restrict__ Ci, int ldc,
                  int K,
                  const int* __restrict__ order, const int* __restrict__ tileExpert)
{
    alignas(16) __shared__ float sAr[16][68], sAi[16][68], sWr[16][68], sWi[16][68];
    int tm = blockIdx.x, tn = blockIdx.y;
    if (EXPERT) {
        int e = tileExpert[tm];
        if (e < 0) return;
        Wr += (long)e * wstride;  Wi += (long)e * wstride;
        br += (long)e * bstride;  bi += (long)e * bstride;
        if (MODRELU) mb += (long)e * bstride;
    }
    int t  = threadIdx.x;
    int lk = t & 15, lm = t >> 4;    // A-tile load coords (k, m-base)
    int ln = t & 63, lk2 = t >> 6;   // W-tile load coords (n, k-base)
    int tx = t & 15, ty = t >> 4;    // compute coords

    long arow[4];
#pragma unroll
    for (int u = 0; u < 4; u++) {
        int grow = tm * 64 + lm + u * 16;
        if (GATHER) {
            int tok = order[grow];
            arow[u] = (tok < 0) ? -1L : (long)tok * lda;
        } else {
            arow[u] = (long)grow * lda;
        }
    }
    long wcol = (long)(tn * 64 + ln);

    float cr[4][4] = {}, cim[4][4] = {};
    for (int k0 = 0; k0 < K; k0 += 16) {
#pragma unroll
        for (int u = 0; u < 4; u++) {
            int m = lm + u * 16;
            float av = 0.f, bv = 0.f;
            if (!GATHER || arow[u] >= 0) {
                av = Ar[arow[u] + k0 + lk];
                bv = Ai[arow[u] + k0 + lk];
            }
            sAr[lk][m] = av;  sAi[lk][m] = bv;
        }
#pragma unroll
        for (int u = 0; u < 4; u++) {
            int kk = lk2 + u * 4;
            long widx = (long)(k0 + kk) * ldw + wcol;
            sWr[kk][ln] = Wr[widx];
            sWi[kk][ln] = Wi[widx];
        }
        __syncthreads();
#pragma unroll
        for (int k = 0; k < 16; k++) {
            float4 a_r = *(const float4*)&sAr[k][ty * 4];
            float4 a_i = *(const float4*)&sAi[k][ty * 4];
            float4 w_r = *(const float4*)&sWr[k][tx * 4];
            float4 w_i = *(const float4*)&sWi[k][tx * 4];
            float arv[4] = {a_r.x, a_r.y, a_r.z, a_r.w};
            float aiv[4] = {a_i.x, a_i.y, a_i.z, a_i.w};
            float wrv[4] = {w_r.x, w_r.y, w_r.z, w_r.w};
            float wiv[4] = {w_i.x, w_i.y, w_i.z, w_i.w};
#pragma unroll
            for (int i = 0; i < 4; i++)
#pragma unroll
                for (int j = 0; j < 4; j++) {
                    cr[i][j]  += arv[i] * wrv[j] - aiv[i] * wiv[j];
                    cim[i][j] += arv[i] * wiv[j] + aiv[i] * wrv[j];
                }
        }
        __syncthreads();
    }
#pragma unroll
    for (int i = 0; i < 4; i++) {
        long row = (long)(tm * 64 + ty * 4 + i);
#pragma unroll
        for (int j = 0; j < 4; j++) {
            long col = (long)(tn * 64 + tx * 4 + j);
            float vr = cr[i][j], vi = cim[i][j];
            if (!ACC) { vr += br[col]; vi += bi[col]; }
            if (MODRELU) {
                float amp = sqrtf(vr * vr + vi * vi + 1e-10f);
                float sc = fmaxf(amp + mb[col], 0.f) / (amp + 1e-10f);
                vr *= sc; vi *= sc;
            }
            long cidx = row * ldc + col;
            if (RESID) { vr += Rr[cidx]; vi += Ri[cidx]; }
            if (ACC)   { vr += Cr[cidx]; vi += Ci[cidx]; }
            Cr[cidx] = vr;  Ci[cidx] = vi;
        }
    }
}

// -------------------------------------------- flash-style complex attention
// scores = (Qr.Kr^T + Qi.Ki^T)/sqrt(d); w = softmax; out_{r,i} = w @ V_{r,i}.
// Block: 32 q-rows x one head x one batch; K processed in 32-row tiles with
// online softmax. Layout: rows of q/k/v are tokens, cols = head*64 + d.
__global__ __launch_bounds__(256)
void cattn_kernel(const float* __restrict__ qr, const float* __restrict__ qi,
                  const float* __restrict__ kr, const float* __restrict__ ki,
                  const float* __restrict__ vr, const float* __restrict__ vi,
                  float* __restrict__ mr, float* __restrict__ mi,
                  int S, int Sk)
{
    const int F = FF;
    int qt = blockIdx.x, head = blockIdx.y, b = blockIdx.z;
    int t = threadIdx.x;
    int r = t >> 3, c = t & 7;   // r: 0..31 q-row, c: 0..7 slot

    alignas(16) __shared__ float sQr[64][36], sQi[64][36];   // [d][row]
    alignas(16) __shared__ float sKr[64][36], sKi[64][36];   // [d][kj]
    alignas(16) __shared__ float sVr[32][68], sVi[32][68];   // [kj][d]
    alignas(16) __shared__ float sP[32][36];                  // [row][kj]

    long qbase = ((long)(b * S + qt * 32)) * F + head * 64;
#pragma unroll
    for (int u = 0; u < 8; u++) {
        int i = t + 256 * u;
        int d = i & 63, rr = i >> 6;
        sQr[d][rr] = qr[qbase + (long)rr * F + d];
        sQi[d][rr] = qi[qbase + (long)rr * F + d];
    }

    float accr[8], acci[8];
#pragma unroll
    for (int j = 0; j < 8; j++) { accr[j] = 0.f; acci[j] = 0.f; }
    float m_run = -3.0e38f, l_run = 0.f;

    int nkt = Sk >> 5;
    for (int kt = 0; kt < nkt; kt++) {
        long kbase = ((long)(b * Sk + kt * 32)) * F + head * 64;
#pragma unroll
        for (int u = 0; u < 8; u++) {
            int i = t + 256 * u;
            int d = i & 63, kk = i >> 6;
            sKr[d][kk] = kr[kbase + (long)kk * F + d];
            sKi[d][kk] = ki[kbase + (long)kk * F + d];
            sVr[kk][d] = vr[kbase + (long)kk * F + d];
            sVi[kk][d] = vi[kbase + (long)kk * F + d];
        }
        __syncthreads();

        float s0 = 0.f, s1 = 0.f, s2 = 0.f, s3 = 0.f;   // kj = c*4 + {0..3}
        for (int d = 0; d < 64; d++) {
            float qrv = sQr[d][r], qiv = sQi[d][r];
            float4 k4r = *(const float4*)&sKr[d][c * 4];
            float4 k4i = *(const float4*)&sKi[d][c * 4];
            s0 += qrv * k4r.x + qiv * k4i.x;
            s1 += qrv * k4r.y + qiv * k4i.y;
            s2 += qrv * k4r.z + qiv * k4i.z;
            s3 += qrv * k4r.w + qiv * k4i.w;
        }
        const float scale = 0.125f;  // 1/sqrt(64)
        s0 *= scale; s1 *= scale; s2 *= scale; s3 *= scale;
        float tmx = fmaxf(fmaxf(s0, s1), fmaxf(s2, s3));
        tmx = fmaxf(tmx, __shfl_xor(tmx, 1));
        tmx = fmaxf(tmx, __shfl_xor(tmx, 2));
        tmx = fmaxf(tmx, __shfl_xor(tmx, 4));
        float m_new = fmaxf(m_run, tmx);
        float p0 = expf(s0 - m_new), p1 = expf(s1 - m_new);
        float p2 = expf(s2 - m_new), p3 = expf(s3 - m_new);
        float ps = p0 + p1 + p2 + p3;
        ps += __shfl_xor(ps, 1); ps += __shfl_xor(ps, 2); ps += __shfl_xor(ps, 4);
        float alpha = expf(m_run - m_new);
        l_run = l_run * alpha + ps;
        m_run = m_new;
#pragma unroll
        for (int j = 0; j < 8; j++) { accr[j] *= alpha; acci[j] *= alpha; }
        *(float4*)&sP[r][c * 4] = make_float4(p0, p1, p2, p3);
        __syncthreads();

        for (int kk = 0; kk < 32; kk++) {
            float p = sP[r][kk];
            float4 v0 = *(const float4*)&sVr[kk][c * 8];
            float4 v1 = *(const float4*)&sVr[kk][c * 8 + 4];
            float4 w0 = *(const float4*)&sVi[kk][c * 8];
            float4 w1 = *(const float4*)&sVi[kk][c * 8 + 4];
            accr[0] += p * v0.x; accr[1] += p * v0.y; accr[2] += p * v0.z; accr[3] += p * v0.w;
            accr[4] += p * v1.x; accr[5] += p * v1.y; accr[6] += p * v1.z; accr[7] += p * v1.w;
            acci[0] += p * w0.x; acci[1] += p * w0.y; acci[2] += p * w0.z; acci[3] += p * w0.w;
            acci[4] += p * w1.x; acci[5] += p * w1.y; acci[6] += p * w1.z; acci[7] += p * w1.w;
        }
        __syncthreads();
    }
    float inv = 1.0f / l_run;
    long obase = qbase + (long)r * F + c * 8;
    float4 o0 = make_float4(accr[0]*inv, accr[1]*inv, accr[2]*inv, accr[3]*inv);
    float4 o1 = make_float4(accr[4]*inv, accr[5]*inv, accr[6]*inv, accr[7]*inv);
    float4 o2 = make_float4(acci[0]*inv, acci[1]*inv, acci[2]*inv, acci[3]*inv);
    float4 o3 = make_float4(acci[4]*inv, acci[5]*inv, acci[6]*inv, acci[7]*inv);
    *(float4*)&mr[obase]     = o0;
    *(float4*)&mr[obase + 4] = o1;
    *(float4*)&mi[obase]     = o2;
    *(float4*)&mi[obase + 4] = o3;
}

// ----------------------------------------------------------------- routing
__global__ __launch_bounds__(256)
void route_kernel(const float* __restrict__ hr, const float* __restrict__ hi,
                  int* __restrict__ eidx)
{
    const int F = FF;
    long base = (long)blockIdx.x * F;
    int t = threadIdx.x;
    double ss = 0.0, cc = 0.0;
#pragma unroll
    for (int u = 0; u < 2; u++) {
        int j = t + u * 256;
        float ph = atan2f(hi[base + j], hr[base + j]);
        ss += (double)sinf(ph);
        cc += (double)cosf(ph);
    }
#pragma unroll
    for (int off = 32; off >= 1; off >>= 1) {
        ss += __shfl_xor(ss, off);
        cc += __shfl_xor(cc, off);
    }
    __shared__ double wss[4], wcc[4];
    if ((t & 63) == 0) { wss[t >> 6] = ss; wcc[t >> 6] = cc; }
    __syncthreads();
    if (t == 0) {
        float msin = (float)((wss[0] + wss[1] + wss[2] + wss[3]) * (1.0 / 512.0));
        float mcos = (float)((wcc[0] + wcc[1] + wcc[2] + wcc[3]) * (1.0 / 512.0));
        float tp = atan2f(msin, mcos);
        float a = (tp + 3.14159274101257324f) / 6.28318548202514648f * 8.0f;
        int k = (int)floorf(a);
        k = min(max(k, 0), NEXP - 1);
        eidx[blockIdx.x] = k;
    }
}

// Build per-expert token segments padded to 64-row tiles. order[NPAD] holds
// token ids (-1 = padding), tileExpert[TMAX] the expert per tile (-1 = dead).
__global__ __launch_bounds__(256)
void moe_build_kernel(const int* __restrict__ eidx, int* __restrict__ order,
                      int* __restrict__ tileExpert)
{
    __shared__ int cnt[NEXP], segbase[NEXP], cursor[NEXP], tbase[NEXP];
    int t = threadIdx.x;
    if (t < NEXP) { cnt[t] = 0; cursor[t] = 0; }
    __syncthreads();
    for (int i = t; i < NTOK; i += 256) atomicAdd(&cnt[eidx[i]], 1);
    __syncthreads();
    if (t == 0) {
        int ob = 0, tb = 0;
        for (int e = 0; e < NEXP; e++) {
            segbase[e] = ob; tbase[e] = tb;
            int tiles = (cnt[e] + 63) >> 6;
            ob += tiles << 6; tb += tiles;
        }
    }
    __syncthreads();
    for (int i = t; i < NPAD; i += 256) order[i] = -1;
    if (t < TMAX) {
        int ex = -1;
        for (int e = 0; e < NEXP; e++) {
            int tiles = (cnt[e] + 63) >> 6;
            if (t >= tbase[e] && t < tbase[e] + tiles) ex = e;
        }
        tileExpert[t] = ex;
    }
    __syncthreads();
    for (int i = t; i < NTOK; i += 256) {
        int e = eidx[i];
        int pos = atomicAdd(&cursor[e], 1);
        order[segbase[e] + pos] = i;
    }
}

// out[0] = x_r + scatter(y_r), out[1] = x_i + scatter(y_i)
__global__ __launch_bounds__(256)
void combine_kernel(const int* __restrict__ order,
                    const float* __restrict__ xr, const float* __restrict__ xi,
                    const float* __restrict__ yr, const float* __restrict__ yi,
                    float* __restrict__ out)
{
    const int F = FF;
    int p = blockIdx.x;
    int tok = order[p];
    if (tok < 0) return;
    int t = threadIdx.x;
    float* outr = out;
    float* outi = out + (long)NTOK * FF;
#pragma unroll
    for (int u = 0; u < 2; u++) {
        int j = t + u * 256;
        long src = (long)p * F + j;
        long dst = (long)tok * F + j;
        outr[dst] = xr[dst] + yr[src];
        outi[dst] = xi[dst] + yi[src];
    }
}

// ------------------------------------------------------------------- launch
extern "C" void kernel_launch(void* const* d_in, const int* in_sizes, int n_in,
                              void* d_out, int out_size, void* d_ws, size_t ws_size,
                              hipStream_t stream)
{
    (void)in_sizes; (void)n_in; (void)out_size; (void)ws_size;
    const float* x_r   = (const float*)d_in[0];
    const float* x_i   = (const float*)d_in[1];
    const float* ctx_r = (const float*)d_in[2];
    const float* ctx_i = (const float*)d_in[3];
    const float* ln1_g = (const float*)d_in[4];
    const float* ln2_g = (const float*)d_in[5];
    const float* ln3_g = (const float*)d_in[6];
    // attn weight packs: Wr, Wi, br, bi starting at 7, stride 4
    const float* sa_qWr = (const float*)d_in[7];   const float* sa_qWi = (const float*)d_in[8];
    const float* sa_qbr = (const float*)d_in[9];   const float* sa_qbi = (const float*)d_in[10];
    const float* sa_kWr = (const float*)d_in[11];  const float* sa_kWi = (const float*)d_in[12];
    const float* sa_kbr = (const float*)d_in[13];  const float* sa_kbi = (const float*)d_in[14];
    const float* sa_vWr = (const float*)d_in[15];  const float* sa_vWi = (const float*)d_in[16];
    const float* sa_vbr = (const float*)d_in[17];  const float* sa_vbi = (const float*)d_in[18];
    const float* sa_oWr = (const float*)d_in[19];  const float* sa_oWi = (const float*)d_in[20];
    const float* sa_obr = (const float*)d_in[21];  const float* sa_obi = (const float*)d_in[22];
    const float* ca_qWr = (const float*)d_in[23];  const float* ca_qWi = (const float*)d_in[24];
    const float* ca_qbr = (const float*)d_in[25];  const float* ca_qbi = (const float*)d_in[26];
    const float* ca_kWr = (const float*)d_in[27];  const float* ca_kWi = (const float*)d_in[28];
    const float* ca_kbr = (const float*)d_in[29];  const float* ca_kbi = (const float*)d_in[30];
    const float* ca_vWr = (const float*)d_in[31];  const float* ca_vWi = (const float*)d_in[32];
    const float* ca_vbr = (const float*)d_in[33];  const float* ca_vbi = (const float*)d_in[34];
    const float* ca_oWr = (const float*)d_in[35];  const float* ca_oWi = (const float*)d_in[36];
    const float* ca_obr = (const float*)d_in[37];  const float* ca_obi = (const float*)d_in[38];
    const float* moe_W1r = (const float*)d_in[39]; const float* moe_W1i = (const float*)d_in[40];
    const float* moe_b1r = (const float*)d_in[41]; const float* moe_b1i = (const float*)d_in[42];
    const float* moe_mb  = (const float*)d_in[43];
    const float* moe_W2r = (const float*)d_in[44]; const float* moe_W2i = (const float*)d_in[45];
    const float* moe_b2r = (const float*)d_in[46]; const float* moe_b2i = (const float*)d_in[47];
    float* out = (float*)d_out;

    // workspace layout (floats): 12*NF + routing ints  (~101 MB)
    float* ws = (float*)d_ws;
    const long NF = (long)NTOK * FF;     // 2,097,152
    float* xr = ws;             float* xi = ws + NF;
    float* hr = ws + 2 * NF;    float* hi = ws + 3 * NF;
    float* pool = ws + 4 * NF;  // 8*NF floats
    float* qr = pool;           float* qi = pool + NF;
    float* kr = pool + 2 * NF;  float* ki = pool + 3 * NF;
    float* vr = pool + 4 * NF;  float* vi = pool + 5 * NF;
    float* mr = pool + 6 * NF;  float* mi = pool + 7 * NF;
    // MoE aliases over the (now-dead) attention pool
    float* ur = pool;                                  // NPAD*1024
    float* ui = pool + (long)NPAD * 1024;
    float* yr = pool + 2L * NPAD * 1024;               // NPAD*512
    float* yi = pool + 2L * NPAD * 1024 + (long)NPAD * 512;
    int* eidx       = (int*)(ws + 12 * NF);
    int* order      = eidx + NTOK;
    int* tileExpert = order + NPAD;

    dim3 blk(256);
    const long WS_ATT = (long)FF * FF;        // 512*512 expert-less stride unused

    // ---- self-attention block
    cln_kernel<<<NTOK, blk, 0, stream>>>(x_r, x_i, ln1_g, hr, hi);
    cgemm_kernel<false,false,false,false,false><<<dim3(64, 8), blk, 0, stream>>>(
        hr, hi, FF, sa_qWr, sa_qWi, FF, WS_ATT, sa_qbr, sa_qbi, 0, nullptr,
        nullptr, nullptr, qr, qi, FF, FF, nullptr, nullptr);
    cgemm_kernel<false,false,false,false,false><<<dim3(64, 8), blk, 0, stream>>>(
        hr, hi, FF, sa_kWr, sa_kWi, FF, WS_ATT, sa_kbr, sa_kbi, 0, nullptr,
        nullptr, nullptr, kr, ki, FF, FF, nullptr, nullptr);
    cgemm_kernel<false,false,false,false,false><<<dim3(64, 8), blk, 0, stream>>>(
        hr, hi, FF, sa_vWr, sa_vWi, FF, WS_ATT, sa_vbr, sa_vbi, 0, nullptr,
        nullptr, nullptr, vr, vi, FF, FF, nullptr, nullptr);
    cattn_kernel<<<dim3(32, 8, 4), blk, 0, stream>>>(qr, qi, kr, ki, vr, vi,
                                                     mr, mi, 1024, 1024);
    cgemm_kernel<false,false,false,true,false><<<dim3(64, 8), blk, 0, stream>>>(
        mr, mi, FF, sa_oWr, sa_oWi, FF, WS_ATT, sa_obr, sa_obi, 0, nullptr,
        x_r, x_i, xr, xi, FF, FF, nullptr, nullptr);

    // ---- cross-attention block
    cln_kernel<<<NTOK, blk, 0, stream>>>(xr, xi, ln2_g, hr, hi);
    cgemm_kernel<false,false,false,false,false><<<dim3(64, 8), blk, 0, stream>>>(
        hr, hi, FF, ca_qWr, ca_qWi, FF, WS_ATT, ca_qbr, ca_qbi, 0, nullptr,
        nullptr, nullptr, qr, qi, FF, FF, nullptr, nullptr);
    cgemm_kernel<false,false,false,false,false><<<dim3(16, 8), blk, 0, stream>>>(
        ctx_r, ctx_i, CDIM, ca_kWr, ca_kWi, FF, WS_ATT, ca_kbr, ca_kbi, 0, nullptr,
        nullptr, nullptr, kr, ki, FF, CDIM, nullptr, nullptr);
    cgemm_kernel<false,false,false,false,false><<<dim3(16, 8), blk, 0, stream>>>(
        ctx_r, ctx_i, CDIM, ca_vWr, ca_vWi, FF, WS_ATT, ca_vbr, ca_vbi, 0, nullptr,
        nullptr, nullptr, vr, vi, FF, CDIM, nullptr, nullptr);
    cattn_kernel<<<dim3(32, 8, 4), blk, 0, stream>>>(qr, qi, kr, ki, vr, vi,
                                                     mr, mi, 1024, 256);
    cgemm_kernel<false,false,false,true,false><<<dim3(64, 8), blk, 0, stream>>>(
        mr, mi, FF, ca_oWr, ca_oWi, FF, WS_ATT, ca_obr, ca_obi, 0, nullptr,
        xr, xi, xr, xi, FF, FF, nullptr, nullptr);   // in-place residual (elementwise)

    // ---- phase-routed MoE
    cln_kernel<<<NTOK, blk, 0, stream>>>(xr, xi, ln3_g, hr, hi);
    route_kernel<<<NTOK, blk, 0, stream>>>(hr, hi, eidx);
    moe_build_kernel<<<1, blk, 0, stream>>>(eidx, order, tileExpert);

    const long W1S = (long)FF * HID;   // per-expert stride, both layers
    // HID chunked in halves so u fits the aliased pool
    for (int ch = 0; ch < 2; ch++) {
        long c0 = (long)ch * 1024;
        // u = modReLU( h @ W1[:, c0:c0+1024] + b1 )   (gathered rows)
        cgemm_kernel<true,true,true,false,false><<<dim3(TMAX, 16), blk, 0, stream>>>(
            hr, hi, FF, moe_W1r + c0, moe_W1i + c0, HID, W1S,
            moe_b1r + c0, moe_b1i + c0, HID, moe_mb + c0,
            nullptr, nullptr, ur, ui, 1024, FF, order, tileExpert);
        if (ch == 0) {
            // y = u @ W2[0:1024, :] + b2
            cgemm_kernel<true,false,false,false,false><<<dim3(TMAX, 8), blk, 0, stream>>>(
                ur, ui, 1024, moe_W2r, moe_W2i, FF, W1S,
                moe_b2r, moe_b2i, FF, nullptr,
                nullptr, nullptr, yr, yi, FF, 1024, order, tileExpert);
        } else {
            // y += u @ W2[1024:2048, :]
            cgemm_kernel<true,false,false,false,true><<<dim3(TMAX, 8), blk, 0, stream>>>(
                ur, ui, 1024, moe_W2r + c0 * FF, moe_W2i + c0 * FF, FF, W1S,
                moe_b2r, moe_b2i, FF, nullptr,
                nullptr, nullptr, yr, yi, FF, 1024, order, tileExpert);
        }
    }
    combine_kernel<<<NPAD, blk, 0, stream>>>(order, xr, xi, yr, yi, out);
}

// Round 2
// 1410.565 us; speedup vs baseline: 5.1556x; 5.1556x over previous
//
#include <hip/hip_runtime.h>
#include <hip/hip_bf16.h>
#include <math.h>

// ComplexTransformerBlock: B=4 S=1024 L=256 F=512 CD=768 NH=8 (d=64) E=8 HID=2048
// Round 2: all GEMMs -> bf16 MFMA (16x16x32). Routing-critical GEMMs use bf16x3
// K-expansion (fp32-accurate); MoE uses plain bf16. Attention/LN/routing fp32.

#define NTOK 4096
#define FF   512
#define CDIM 768
#define NEXP 8
#define HID  2048
#define TMAX 72
#define NPAD (TMAX * 64)

typedef __hip_bfloat16 bf16;
typedef short bf16x8 __attribute__((ext_vector_type(8)));
typedef float f32x4  __attribute__((ext_vector_type(4)));

// ---------------------------------------------------------------- complex LN
__global__ __launch_bounds__(256)
void cln_kernel(const float* __restrict__ xr, const float* __restrict__ xi,
                const float* __restrict__ g,
                float* __restrict__ hr, float* __restrict__ hi)
{
    const int F = FF;
    long base = (long)blockIdx.x * F;
    int t = threadIdx.x;
    int j0 = t, j1 = t + 256;
    float xr0 = xr[base + j0], xi0 = xi[base + j0];
    float xr1 = xr[base + j1], xi1 = xi[base + j1];
    float a0 = sqrtf(xr0 * xr0 + xi0 * xi0 + 1e-6f);
    float a1 = sqrtf(xr1 * xr1 + xi1 * xi1 + 1e-6f);
    float s = a0 + a1;
#pragma unroll
    for (int off = 32; off >= 1; off >>= 1) s += __shfl_xor(s, off);
    __shared__ float wsum[4];
    if ((t & 63) == 0) wsum[t >> 6] = s;
    __syncthreads();
    float mean = (wsum[0] + wsum[1] + wsum[2] + wsum[3]) * (1.0f / 512.0f);
    float d0 = g[j0] * (a0 / (mean + 1e-6f)) / (a0 + 1e-6f);
    float d1 = g[j1] * (a1 / (mean + 1e-6f)) / (a1 + 1e-6f);
    hr[base + j0] = xr0 * d0;  hi[base + j0] = xi0 * d0;
    hr[base + j1] = xr1 * d1;  hi[base + j1] = xi1 * d1;
}

// --------------------------------------------------- fp32 -> bf16x3 A expand
// dst (M x 3K) = [Ah | Al | Ah]
__global__ __launch_bounds__(256)
void expandA_x3(const float* __restrict__ sR, const float* __restrict__ sI,
                bf16* __restrict__ dR, bf16* __restrict__ dI, int K)
{
    int k = blockIdx.x * 256 + threadIdx.x;
    int m = blockIdx.y;
    long s = (long)m * K + k;
    long d = (long)m * 3 * K + k;
    float a = sR[s];
    bf16 ah = __float2bfloat16(a);
    bf16 al = __float2bfloat16(a - __bfloat162float(ah));
    dR[d] = ah; dR[d + K] = al; dR[d + 2 * K] = ah;
    float b = sI[s];
    bf16 bh = __float2bfloat16(b);
    bf16 bl = __float2bfloat16(b - __bfloat162float(bh));
    dI[d] = bh; dI[d + K] = bl; dI[d + 2 * K] = bh;
}

// fp32 -> bf16 plain rowmajor (for MoE h)
__global__ __launch_bounds__(256)
void convA_plain(const float* __restrict__ sR, const float* __restrict__ sI,
                 bf16* __restrict__ dR, bf16* __restrict__ dI, int K)
{
    int k = blockIdx.x * 256 + threadIdx.x;
    long s = (long)blockIdx.y * K + k;
    dR[s] = __float2bfloat16(sR[s]);
    dI[s] = __float2bfloat16(sI[s]);
}

// ---------------------------------- W -> packed MFMA-fragment layout, bf16x3
// dst layout: [kc (3K/32)] [nt (N/16)] [lane 64] [8]; lane=q*16+nn holds
// W'[kc*32 + q*8 + j][nt*16+nn].  Row order along K': [Wh ; Wh ; Wl].
__global__ __launch_bounds__(256)
void expandW_x3_packed(const float* __restrict__ sR, const float* __restrict__ sI,
                       bf16* __restrict__ dR, bf16* __restrict__ dI,
                       int N, int kdiv /*K/32*/)
{
    int g = blockIdx.x * 256 + threadIdx.x;
    int nt = g >> 6, l = g & 63;
    int kc = blockIdx.y;
    int t3 = (kc >= kdiv) + (kc >= 2 * kdiv);
    int kb = (kc - t3 * kdiv) * 32 + (l >> 4) * 8;
    int n  = nt * 16 + (l & 15);
    long dbase = ((long)kc * (N >> 4) + nt) * 512 + l * 8;
#pragma unroll
    for (int j = 0; j < 8; j++) {
        float a = sR[(long)(kb + j) * N + n];
        bf16 ah = __float2bfloat16(a);
        dR[dbase + j] = (t3 < 2) ? ah : __float2bfloat16(a - __bfloat162float(ah));
        float b = sI[(long)(kb + j) * N + n];
        bf16 bh = __float2bfloat16(b);
        dI[dbase + j] = (t3 < 2) ? bh : __float2bfloat16(b - __bfloat162float(bh));
    }
}

// W -> packed plain bf16, expert-strided (MoE weights)
__global__ __launch_bounds__(256)
void convW_packed(const float* __restrict__ sR, const float* __restrict__ sI,
                  bf16* __restrict__ dR, bf16* __restrict__ dI,
                  int N, long estride)
{
    int g = blockIdx.x * 256 + threadIdx.x;
    int nt = g >> 6, l = g & 63;
    int kc = blockIdx.y;
    int e  = blockIdx.z;
    const float* srcR = sR + (long)e * estride;
    const float* srcI = sI + (long)e * estride;
    bf16* dstR = dR + (long)e * estride;
    bf16* dstI = dI + (long)e * estride;
    int kb = kc * 32 + (l >> 4) * 8;
    int n  = nt * 16 + (l & 15);
    long dbase = ((long)kc * (N >> 4) + nt) * 512 + l * 8;
#pragma unroll
    for (int j = 0; j < 8; j++) {
        dstR[dbase + j] = __float2bfloat16(srcR[(long)(kb + j) * N + n]);
        dstI[dbase + j] = __float2bfloat16(srcI[(long)(kb + j) * N + n]);
    }
}

// -------------------------------------------------- complex MFMA GEMM 64x64
// C(M,N fp32/bf16 pair) = A(bf16 pair, M x Kp) x Wpacked(bf16 pair) + bias.
// Block 256 thr = 4 waves in 2x2; each wave 32x32 via 2x2 16x16 MFMA tiles.
template<bool EXPERT, bool GATHER, bool MODRELU, bool RESID, bool OUTBF16>
__global__ __launch_bounds__(256)
void cgemm_mfma(const bf16* __restrict__ Ar, const bf16* __restrict__ Ai, int lda,
                const bf16* __restrict__ Wr, const bf16* __restrict__ Wi,
                long wstride, int ntTot,
                const float* __restrict__ br, const float* __restrict__ bi, int bstride,
                const float* __restrict__ mb,
                const float* __restrict__ Rr, const float* __restrict__ Ri,
                void* __restrict__ Crv, void* __restrict__ Civ, int ldc, int Kp,
                const int* __restrict__ order, const int* __restrict__ tileExpert)
{
    __shared__ short sA[8192];   // [ri*2+kc][mtile 4][lane 64][8]  (16 KB)
    __shared__ short sW[8192];   // [ri*2+kc][ntile 4][lane 64][8]  (16 KB)
    int tm = blockIdx.x, tn = blockIdx.y;
    if (EXPERT) {
        int e = tileExpert[tm];
        if (e < 0) return;
        Wr += (long)e * wstride;  Wi += (long)e * wstride;
        br += (long)e * bstride;  bi += (long)e * bstride;
        if (MODRELU) mb += (long)e * bstride;
    }
    int t = threadIdx.x;
    // A staging coords
    int m = t & 63, jj = t >> 6;
    int aldsLane = (jj << 4) + (m & 15);
    int mt = m >> 4;
    long abase; bool aok = true;
    {
        int arow = tm * 64 + m;
        if (GATHER) { int g = order[arow]; aok = (g >= 0); abase = (long)(aok ? g : 0) * lda; }
        else abase = (long)arow * lda;
    }
    // W staging coords
    int wl = t & 63, wb = t >> 6;
    // compute coords
    int l = t & 63, w = t >> 6;
    int wm = w & 1, wn = w >> 1;

    f32x4 z = {0.f, 0.f, 0.f, 0.f};
    f32x4 accR[2][2], accI[2][2];
#pragma unroll
    for (int a = 0; a < 2; a++)
#pragma unroll
        for (int b = 0; b < 2; b++) { accR[a][b] = z; accI[a][b] = z; }

    const bf16x8 sgn = {(short)0x8000,(short)0x8000,(short)0x8000,(short)0x8000,
                        (short)0x8000,(short)0x8000,(short)0x8000,(short)0x8000};

    for (int k0 = 0; k0 < Kp; k0 += 64) {
        __syncthreads();
        // ---- stage A (4 x 16B per thread)
#pragma unroll
        for (int ri = 0; ri < 2; ri++) {
            const bf16* src = ri ? Ai : Ar;
#pragma unroll
            for (int kc = 0; kc < 2; kc++) {
                bf16x8 v = {};
                if (!GATHER || aok)
                    v = *(const bf16x8*)&src[abase + k0 + kc * 32 + jj * 8];
                *(bf16x8*)&sA[((((ri * 2 + kc) << 2) + mt) << 9) + aldsLane * 8] = v;
            }
        }
        // ---- stage W (4 x 16B per thread; packed source is contiguous)
        int kc0 = k0 >> 5;
#pragma unroll
        for (int it = 0; it < 4; it++) {
            int b  = (it << 2) + wb;
            int ri = b >> 3, kc = (b >> 2) & 1, ntl = b & 3;
            const bf16* src = ri ? Wi : Wr;
            bf16x8 v = *(const bf16x8*)&src[(((long)(kc0 + kc) * ntTot + tn * 4 + ntl) << 9) + wl * 8];
            *(bf16x8*)&sW[((((ri * 2 + kc) << 2) + ntl) << 9) + wl * 8] = v;
        }
        __syncthreads();
        // ---- compute
#pragma unroll
        for (int kc = 0; kc < 2; kc++) {
            bf16x8 arf[2], aif[2], naf[2], wrf[2], wif[2];
#pragma unroll
            for (int s = 0; s < 2; s++) {
                arf[s] = *(const bf16x8*)&sA[(((kc << 2) + wm * 2 + s) << 9) + l * 8];
                aif[s] = *(const bf16x8*)&sA[((((2 + kc) << 2) + wm * 2 + s) << 9) + l * 8];
                naf[s] = aif[s] ^ sgn;
                wrf[s] = *(const bf16x8*)&sW[(((kc << 2) + wn * 2 + s) << 9) + l * 8];
                wif[s] = *(const bf16x8*)&sW[((((2 + kc) << 2) + wn * 2 + s) << 9) + l * 8];
            }
#pragma unroll
            for (int sm = 0; sm < 2; sm++)
#pragma unroll
                for (int sn = 0; sn < 2; sn++) {
                    accR[sm][sn] = __builtin_amdgcn_mfma_f32_16x16x32_bf16(arf[sm], wrf[sn], accR[sm][sn], 0, 0, 0);
                    accR[sm][sn] = __builtin_amdgcn_mfma_f32_16x16x32_bf16(naf[sm], wif[sn], accR[sm][sn], 0, 0, 0);
                    accI[sm][sn] = __builtin_amdgcn_mfma_f32_16x16x32_bf16(arf[sm], wif[sn], accI[sm][sn], 0, 0, 0);
                    accI[sm][sn] = __builtin_amdgcn_mfma_f32_16x16x32_bf16(aif[sm], wrf[sn], accI[sm][sn], 0, 0, 0);
                }
        }
    }
    // ---- epilogue: C/D layout col=lane&15, row=(lane>>4)*4+reg
#pragma unroll
    for (int sm = 0; sm < 2; sm++)
#pragma unroll
        for (int sn = 0; sn < 2; sn++) {
            int row0 = tm * 64 + (wm * 2 + sm) * 16 + (l >> 4) * 4;
            int col  = tn * 64 + (wn * 2 + sn) * 16 + (l & 15);
            float bre = br[col], bie = bi[col];
            float mbe = MODRELU ? mb[col] : 0.f;
#pragma unroll
            for (int v = 0; v < 4; v++) {
                int row = row0 + v;
                float vr = accR[sm][sn][v] + bre;
                float vi = accI[sm][sn][v] + bie;
                if (MODRELU) {
                    float amp = sqrtf(vr * vr + vi * vi + 1e-10f);
                    float sc = fmaxf(amp + mbe, 0.f) / (amp + 1e-10f);
                    vr *= sc; vi *= sc;
                }
                long cidx = (long)row * ldc + col;
                if (RESID) { vr += Rr[cidx]; vi += Ri[cidx]; }
                if (OUTBF16) {
                    ((bf16*)Crv)[cidx] = __float2bfloat16(vr);
                    ((bf16*)Civ)[cidx] = __float2bfloat16(vi);
                } else {
                    ((float*)Crv)[cidx] = vr;
                    ((float*)Civ)[cidx] = vi;
                }
            }
        }
}

// -------------------------------------------- flash-style complex attention
__global__ __launch_bounds__(256)
void cattn_kernel(const float* __restrict__ qr, const float* __restrict__ qi,
                  const float* __restrict__ kr, const float* __restrict__ ki,
                  const float* __restrict__ vr, const float* __restrict__ vi,
                  float* __restrict__ mr, float* __restrict__ mi,
                  int S, int Sk)
{
    const int F = FF;
    int qt = blockIdx.x, head = blockIdx.y, b = blockIdx.z;
    int t = threadIdx.x;
    int r = t >> 3, c = t & 7;

    alignas(16) __shared__ float sQr[64][36], sQi[64][36];
    alignas(16) __shared__ float sKr[64][36], sKi[64][36];
    alignas(16) __shared__ float sVr[32][68], sVi[32][68];
    alignas(16) __shared__ float sP[32][36];

    long qbase = ((long)(b * S + qt * 32)) * F + head * 64;
#pragma unroll
    for (int u = 0; u < 8; u++) {
        int i = t + 256 * u;
        int d = i & 63, rr = i >> 6;
        sQr[d][rr] = qr[qbase + (long)rr * F + d];
        sQi[d][rr] = qi[qbase + (long)rr * F + d];
    }

    float accr[8], acci[8];
#pragma unroll
    for (int j = 0; j < 8; j++) { accr[j] = 0.f; acci[j] = 0.f; }
    float m_run = -3.0e38f, l_run = 0.f;

    int nkt = Sk >> 5;
    for (int kt = 0; kt < nkt; kt++) {
        long kbase = ((long)(b * Sk + kt * 32)) * F + head * 64;
#pragma unroll
        for (int u = 0; u < 8; u++) {
            int i = t + 256 * u;
            int d = i & 63, kk = i >> 6;
            sKr[d][kk] = kr[kbase + (long)kk * F + d];
            sKi[d][kk] = ki[kbase + (long)kk * F + d];
            sVr[kk][d] = vr[kbase + (long)kk * F + d];
            sVi[kk][d] = vi[kbase + (long)kk * F + d];
        }
        __syncthreads();

        float s0 = 0.f, s1 = 0.f, s2 = 0.f, s3 = 0.f;
        for (int d = 0; d < 64; d++) {
            float qrv = sQr[d][r], qiv = sQi[d][r];
            float4 k4r = *(const float4*)&sKr[d][c * 4];
            float4 k4i = *(const float4*)&sKi[d][c * 4];
            s0 += qrv * k4r.x + qiv * k4i.x;
            s1 += qrv * k4r.y + qiv * k4i.y;
            s2 += qrv * k4r.z + qiv * k4i.z;
            s3 += qrv * k4r.w + qiv * k4i.w;
        }
        const float scale = 0.125f;
        s0 *= scale; s1 *= scale; s2 *= scale; s3 *= scale;
        float tmx = fmaxf(fmaxf(s0, s1), fmaxf(s2, s3));
        tmx = fmaxf(tmx, __shfl_xor(tmx, 1));
        tmx = fmaxf(tmx, __shfl_xor(tmx, 2));
        tmx = fmaxf(tmx, __shfl_xor(tmx, 4));
        float m_new = fmaxf(m_run, tmx);
        float p0 = expf(s0 - m_new), p1 = expf(s1 - m_new);
        float p2 = expf(s2 - m_new), p3 = expf(s3 - m_new);
        float ps = p0 + p1 + p2 + p3;
        ps += __shfl_xor(ps, 1); ps += __shfl_xor(ps, 2); ps += __shfl_xor(ps, 4);
        float alpha = expf(m_run - m_new);
        l_run = l_run * alpha + ps;
        m_run = m_new;
#pragma unroll
        for (int j = 0; j < 8; j++) { accr[j] *= alpha; acci[j] *= alpha; }
        *(float4*)&sP[r][c * 4] = make_float4(p0, p1, p2, p3);
        __syncthreads();

        for (int kk = 0; kk < 32; kk++) {
            float p = sP[r][kk];
            float4 v0 = *(const float4*)&sVr[kk][c * 8];
            float4 v1 = *(const float4*)&sVr[kk][c * 8 + 4];
            float4 w0 = *(const float4*)&sVi[kk][c * 8];
            float4 w1 = *(const float4*)&sVi[kk][c * 8 + 4];
            accr[0] += p * v0.x; accr[1] += p * v0.y; accr[2] += p * v0.z; accr[3] += p * v0.w;
            accr[4] += p * v1.x; accr[5] += p * v1.y; accr[6] += p * v1.z; accr[7] += p * v1.w;
            acci[0] += p * w0.x; acci[1] += p * w0.y; acci[2] += p * w0.z; acci[3] += p * w0.w;
            acci[4] += p * w1.x; acci[5] += p * w1.y; acci[6] += p * w1.z; acci[7] += p * w1.w;
        }
        __syncthreads();
    }
    float inv = 1.0f / l_run;
    long obase = qbase + (long)r * F + c * 8;
    *(float4*)&mr[obase]     = make_float4(accr[0]*inv, accr[1]*inv, accr[2]*inv, accr[3]*inv);
    *(float4*)&mr[obase + 4] = make_float4(accr[4]*inv, accr[5]*inv, accr[6]*inv, accr[7]*inv);
    *(float4*)&mi[obase]     = make_float4(acci[0]*inv, acci[1]*inv, acci[2]*inv, acci[3]*inv);
    *(float4*)&mi[obase + 4] = make_float4(acci[4]*inv, acci[5]*inv, acci[6]*inv, acci[7]*inv);
}

// ----------------------------------------------------------------- routing
__global__ __launch_bounds__(256)
void route_kernel(const float* __restrict__ hr, const float* __restrict__ hi,
                  int* __restrict__ eidx)
{
    const int F = FF;
    long base = (long)blockIdx.x * F;
    int t = threadIdx.x;
    double ss = 0.0, cc = 0.0;
#pragma unroll
    for (int u = 0; u < 2; u++) {
        int j = t + u * 256;
        float ph = atan2f(hi[base + j], hr[base + j]);
        ss += (double)sinf(ph);
        cc += (double)cosf(ph);
    }
#pragma unroll
    for (int off = 32; off >= 1; off >>= 1) {
        ss += __shfl_xor(ss, off);
        cc += __shfl_xor(cc, off);
    }
    __shared__ double wss[4], wcc[4];
    if ((t & 63) == 0) { wss[t >> 6] = ss; wcc[t >> 6] = cc; }
    __syncthreads();
    if (t == 0) {
        float msin = (float)((wss[0] + wss[1] + wss[2] + wss[3]) * (1.0 / 512.0));
        float mcos = (float)((wcc[0] + wcc[1] + wcc[2] + wcc[3]) * (1.0 / 512.0));
        float tp = atan2f(msin, mcos);
        float a = (tp + 3.14159274101257324f) / 6.28318548202514648f * 8.0f;
        int k = (int)floorf(a);
        k = min(max(k, 0), NEXP - 1);
        eidx[blockIdx.x] = k;
    }
}

__global__ __launch_bounds__(256)
void moe_build_kernel(const int* __restrict__ eidx, int* __restrict__ order,
                      int* __restrict__ tileExpert)
{
    __shared__ int cnt[NEXP], segbase[NEXP], cursor[NEXP], tbase[NEXP];
    int t = threadIdx.x;
    if (t < NEXP) { cnt[t] = 0; cursor[t] = 0; }
    __syncthreads();
    for (int i = t; i < NTOK; i += 256) atomicAdd(&cnt[eidx[i]], 1);
    __syncthreads();
    if (t == 0) {
        int ob = 0, tb = 0;
        for (int e = 0; e < NEXP; e++) {
            segbase[e] = ob; tbase[e] = tb;
            int tiles = (cnt[e] + 63) >> 6;
            ob += tiles << 6; tb += tiles;
        }
    }
    __syncthreads();
    for (int i = t; i < NPAD; i += 256) order[i] = -1;
    if (t < TMAX) {
        int ex = -1;
        for (int e = 0; e < NEXP; e++) {
            int tiles = (cnt[e] + 63) >> 6;
            if (t >= tbase[e] && t < tbase[e] + tiles) ex = e;
        }
        tileExpert[t] = ex;
    }
    __syncthreads();
    for (int i = t; i < NTOK; i += 256) {
        int e = eidx[i];
        int pos = atomicAdd(&cursor[e], 1);
        order[segbase[e] + pos] = i;
    }
}

__global__ __launch_bounds__(256)
void combine_kernel(const int* __restrict__ order,
                    const float* __restrict__ xr, const float* __restrict__ xi,
                    const float* __restrict__ yr, const float* __restrict__ yi,
                    float* __restrict__ out)
{
    const int F = FF;
    int p = blockIdx.x;
    int tok = order[p];
    if (tok < 0) return;
    int t = threadIdx.x;
    float* outr = out;
    float* outi = out + (long)NTOK * FF;
#pragma unroll
    for (int u = 0; u < 2; u++) {
        int j = t + u * 256;
        long src = (long)p * F + j;
        long dst = (long)tok * F + j;
        outr[dst] = xr[dst] + yr[src];
        outi[dst] = xi[dst] + yi[src];
    }
}

// ------------------------------------------------------------------- launch
extern "C" void kernel_launch(void* const* d_in, const int* in_sizes, int n_in,
                              void* d_out, int out_size, void* d_ws, size_t ws_size,
                              hipStream_t stream)
{
    (void)in_sizes; (void)n_in; (void)out_size; (void)ws_size;
    const float* x_r   = (const float*)d_in[0];
    const float* x_i   = (const float*)d_in[1];
    const float* ctx_r = (const float*)d_in[2];
    const float* ctx_i = (const float*)d_in[3];
    const float* ln1_g = (const float*)d_in[4];
    const float* ln2_g = (const float*)d_in[5];
    const float* ln3_g = (const float*)d_in[6];
    const float* sa_qWr = (const float*)d_in[7];   const float* sa_qWi = (const float*)d_in[8];
    const float* sa_qbr = (const float*)d_in[9];   const float* sa_qbi = (const float*)d_in[10];
    const float* sa_kWr = (const float*)d_in[11];  const float* sa_kWi = (const float*)d_in[12];
    const float* sa_kbr = (const float*)d_in[13];  const float* sa_kbi = (const float*)d_in[14];
    const float* sa_vWr = (const float*)d_in[15];  const float* sa_vWi = (const float*)d_in[16];
    const float* sa_vbr = (const float*)d_in[17];  const float* sa_vbi = (const float*)d_in[18];
    const float* sa_oWr = (const float*)d_in[19];  const float* sa_oWi = (const float*)d_in[20];
    const float* sa_obr = (const float*)d_in[21];  const float* sa_obi = (const float*)d_in[22];
    const float* ca_qWr = (const float*)d_in[23];  const float* ca_qWi = (const float*)d_in[24];
    const float* ca_qbr = (const float*)d_in[25];  const float* ca_qbi = (const float*)d_in[26];
    const float* ca_kWr = (const float*)d_in[27];  const float* ca_kWi = (const float*)d_in[28];
    const float* ca_kbr = (const float*)d_in[29];  const float* ca_kbi = (const float*)d_in[30];
    const float* ca_vWr = (const float*)d_in[31];  const float* ca_vWi = (const float*)d_in[32];
    const float* ca_vbr = (const float*)d_in[33];  const float* ca_vbi = (const float*)d_in[34];
    const float* ca_oWr = (const float*)d_in[35];  const float* ca_oWi = (const float*)d_in[36];
    const float* ca_obr = (const float*)d_in[37];  const float* ca_obi = (const float*)d_in[38];
    const float* moe_W1r = (const float*)d_in[39]; const float* moe_W1i = (const float*)d_in[40];
    const float* moe_b1r = (const float*)d_in[41]; const float* moe_b1i = (const float*)d_in[42];
    const float* moe_mb  = (const float*)d_in[43];
    const float* moe_W2r = (const float*)d_in[44]; const float* moe_W2i = (const float*)d_in[45];
    const float* moe_b2r = (const float*)d_in[46]; const float* moe_b2i = (const float*)d_in[47];
    float* out = (float*)d_out;

    char* W = (char*)d_ws;
    const long NF = (long)NTOK * FF;          // 2,097,152 floats = 8 MB
    float* xr = (float*)(W + 0 * NF * 4);
    float* xi = (float*)(W + 1 * NF * 4);
    float* hr = (float*)(W + 2 * NF * 4);
    float* hi = (float*)(W + 3 * NF * 4);
    char* poolB = W + 4 * NF * 4;             // 67.1 MB pool
    float* qr = (float*)poolB;                float* qi = (float*)(poolB + NF * 4);
    float* kr = (float*)(poolB + 2 * NF * 4); float* ki = (float*)(poolB + 3 * NF * 4);
    float* vr = (float*)(poolB + 4 * NF * 4); float* vi = (float*)(poolB + 5 * NF * 4);
    float* mr = (float*)(poolB + 6 * NF * 4); float* mi = (float*)(poolB + 7 * NF * 4);
    // MoE overlay on pool
    bf16* u_r = (bf16*)poolB;                                   // 4608*2048
    bf16* u_i = (bf16*)(poolB + 18874368);
    float* y_r = (float*)(poolB + 37748736);                    // 4608*512 f32
    float* y_i = (float*)(poolB + 37748736 + 9437184);
    bf16* h3r = (bf16*)(poolB + 56623104);                      // 4096*512 bf16
    bf16* h3i = (bf16*)(poolB + 56623104 + 4194304);
    // region Q (attn operands / MoE weights overlay)
    char* Q = W + 12 * NF * 4;                                  // offset 100.7 MB
    bf16* A1r = (bf16*)Q;                   bf16* A1i = (bf16*)(Q + 12582912);   // 4096x1536
    bf16* A2r = (bf16*)(Q + 25165824);      bf16* A2i = (bf16*)(Q + 25165824 + 4718592); // 1024x2304
    char* WQ = Q + 34603008;
    bf16* saq_r = (bf16*)(WQ + 0 * 1572864);  bf16* saq_i = (bf16*)(WQ + 1 * 1572864);
    bf16* sak_r = (bf16*)(WQ + 2 * 1572864);  bf16* sak_i = (bf16*)(WQ + 3 * 1572864);
    bf16* sav_r = (bf16*)(WQ + 4 * 1572864);  bf16* sav_i = (bf16*)(WQ + 5 * 1572864);
    bf16* sao_r = (bf16*)(WQ + 6 * 1572864);  bf16* sao_i = (bf16*)(WQ + 7 * 1572864);
    bf16* caq_r = (bf16*)(WQ + 8 * 1572864);  bf16* caq_i = (bf16*)(WQ + 9 * 1572864);
    bf16* cao_r = (bf16*)(WQ + 10 * 1572864); bf16* cao_i = (bf16*)(WQ + 11 * 1572864);
    bf16* cak_r = (bf16*)(WQ + 12 * 1572864);                   // 2304x512
    bf16* cak_i = (bf16*)(WQ + 12 * 1572864 + 2359296);
    bf16* cav_r = (bf16*)(WQ + 12 * 1572864 + 2 * 2359296);
    bf16* cav_i = (bf16*)(WQ + 12 * 1572864 + 3 * 2359296);
    // MoE weight overlay (reused for W1 then W2): at Q base
    bf16* Wm_r = (bf16*)Q;                  // 8*512*2048 bf16 = 16.8 MB
    bf16* Wm_i = (bf16*)(Q + 16777216);
    int* eidx       = (int*)(W + 12 * NF * 4 + 62914560);
    int* order      = eidx + NTOK;
    int* tileExpert = order + NPAD;

    dim3 blk(256);
    const long W1S = (long)FF * HID;

    // ---- attention weight conversions (bf16x3 packed)
    expandW_x3_packed<<<dim3(8, 48), blk, 0, stream>>>(sa_qWr, sa_qWi, saq_r, saq_i, FF, 16);
    expandW_x3_packed<<<dim3(8, 48), blk, 0, stream>>>(sa_kWr, sa_kWi, sak_r, sak_i, FF, 16);
    expandW_x3_packed<<<dim3(8, 48), blk, 0, stream>>>(sa_vWr, sa_vWi, sav_r, sav_i, FF, 16);
    expandW_x3_packed<<<dim3(8, 48), blk, 0, stream>>>(sa_oWr, sa_oWi, sao_r, sao_i, FF, 16);
    expandW_x3_packed<<<dim3(8, 48), blk, 0, stream>>>(ca_qWr, ca_qWi, caq_r, caq_i, FF, 16);
    expandW_x3_packed<<<dim3(8, 48), blk, 0, stream>>>(ca_oWr, ca_oWi, cao_r, cao_i, FF, 16);
    expandW_x3_packed<<<dim3(8, 72), blk, 0, stream>>>(ca_kWr, ca_kWi, cak_r, cak_i, FF, 24);
    expandW_x3_packed<<<dim3(8, 72), blk, 0, stream>>>(ca_vWr, ca_vWi, cav_r, cav_i, FF, 24);

    // ---- self-attention block
    cln_kernel<<<NTOK, blk, 0, stream>>>(x_r, x_i, ln1_g, hr, hi);
    expandA_x3<<<dim3(2, NTOK), blk, 0, stream>>>(hr, hi, A1r, A1i, FF);
    cgemm_mfma<false,false,false,false,false><<<dim3(64, 8), blk, 0, stream>>>(
        A1r, A1i, 1536, saq_r, saq_i, 0, 32, sa_qbr, sa_qbi, 0, nullptr,
        nullptr, nullptr, qr, qi, FF, 1536, nullptr, nullptr);
    cgemm_mfma<false,false,false,false,false><<<dim3(64, 8), blk, 0, stream>>>(
        A1r, A1i, 1536, sak_r, sak_i, 0, 32, sa_kbr, sa_kbi, 0, nullptr,
        nullptr, nullptr, kr, ki, FF, 1536, nullptr, nullptr);
    cgemm_mfma<false,false,false,false,false><<<dim3(64, 8), blk, 0, stream>>>(
        A1r, A1i, 1536, sav_r, sav_i, 0, 32, sa_vbr, sa_vbi, 0, nullptr,
        nullptr, nullptr, vr, vi, FF, 1536, nullptr, nullptr);
    cattn_kernel<<<dim3(32, 8, 4), blk, 0, stream>>>(qr, qi, kr, ki, vr, vi,
                                                     mr, mi, 1024, 1024);
    expandA_x3<<<dim3(2, NTOK), blk, 0, stream>>>(mr, mi, A1r, A1i, FF);
    cgemm_mfma<false,false,false,true,false><<<dim3(64, 8), blk, 0, stream>>>(
        A1r, A1i, 1536, sao_r, sao_i, 0, 32, sa_obr, sa_obi, 0, nullptr,
        x_r, x_i, xr, xi, FF, 1536, nullptr, nullptr);

    // ---- cross-attention block
    cln_kernel<<<NTOK, blk, 0, stream>>>(xr, xi, ln2_g, hr, hi);
    expandA_x3<<<dim3(2, NTOK), blk, 0, stream>>>(hr, hi, A1r, A1i, FF);
    cgemm_mfma<false,false,false,false,false><<<dim3(64, 8), blk, 0, stream>>>(
        A1r, A1i, 1536, caq_r, caq_i, 0, 32, ca_qbr, ca_qbi, 0, nullptr,
        nullptr, nullptr, qr, qi, FF, 1536, nullptr, nullptr);
    expandA_x3<<<dim3(3, 1024), blk, 0, stream>>>(ctx_r, ctx_i, A2r, A2i, CDIM);
    cgemm_mfma<false,false,false,false,false><<<dim3(16, 8), blk, 0, stream>>>(
        A2r, A2i, 2304, cak_r, cak_i, 0, 32, ca_kbr, ca_kbi, 0, nullptr,
        nullptr, nullptr, kr, ki, FF, 2304, nullptr, nullptr);
    cgemm_mfma<false,false,false,false,false><<<dim3(16, 8), blk, 0, stream>>>(
        A2r, A2i, 2304, cav_r, cav_i, 0, 32, ca_vbr, ca_vbi, 0, nullptr,
        nullptr, nullptr, vr, vi, FF, 2304, nullptr, nullptr);
    cattn_kernel<<<dim3(32, 8, 4), blk, 0, stream>>>(qr, qi, kr, ki, vr, vi,
                                                     mr, mi, 1024, 256);
    expandA_x3<<<dim3(2, NTOK), blk, 0, stream>>>(mr, mi, A1r, A1i, FF);
    cgemm_mfma<false,false,false,true,false><<<dim3(64, 8), blk, 0, stream>>>(
        A1r, A1i, 1536, cao_r, cao_i, 0, 32, ca_obr, ca_obi, 0, nullptr,
        xr, xi, xr, xi, FF, 1536, nullptr, nullptr);

    // ---- phase-routed MoE
    cln_kernel<<<NTOK, blk, 0, stream>>>(xr, xi, ln3_g, hr, hi);
    route_kernel<<<NTOK, blk, 0, stream>>>(hr, hi, eidx);
    moe_build_kernel<<<1, blk, 0, stream>>>(eidx, order, tileExpert);
    convA_plain<<<dim3(2, NTOK), blk, 0, stream>>>(hr, hi, h3r, h3i, FF);
    // layer 1: u = modReLU(h @ W1 + b1), bf16 out
    convW_packed<<<dim3(32, 16, 8), blk, 0, stream>>>(moe_W1r, moe_W1i, Wm_r, Wm_i, HID, W1S);
    cgemm_mfma<true,true,true,false,true><<<dim3(TMAX, 32), blk, 0, stream>>>(
        h3r, h3i, FF, Wm_r, Wm_i, W1S, 128, moe_b1r, moe_b1i, HID, moe_mb,
        nullptr, nullptr, u_r, u_i, HID, FF, order, tileExpert);
    // layer 2: y = u @ W2 + b2, fp32 out
    convW_packed<<<dim3(8, 64, 8), blk, 0, stream>>>(moe_W2r, moe_W2i, Wm_r, Wm_i, FF, W1S);
    cgemm_mfma<true,false,false,false,false><<<dim3(TMAX, 8), blk, 0, stream>>>(
        u_r, u_i, HID, Wm_r, Wm_i, W1S, 32, moe_b2r, moe_b2i, FF, nullptr,
        nullptr, nullptr, y_r, y_i, FF, HID, order, tileExpert);
    combine_kernel<<<NPAD, blk, 0, stream>>>(order, xr, xi, y_r, y_i, out);
}

// Round 3
// 1030.718 us; speedup vs baseline: 7.0556x; 1.3685x over previous
//
#include <hip/hip_runtime.h>
#include <hip/hip_bf16.h>
#include <math.h>

// ComplexTransformerBlock: B=4 S=1024 L=256 F=512 CD=768 NH=8 (d=64) E=8 HID=2048
// Round 3: attention -> bf16x3 MFMA (scores and PV fp32-accurate via hi/lo split).
// GEMMs unchanged from round 2 (bf16x3 MFMA for routing-critical, bf16 for MoE).

#define NTOK 4096
#define FF   512
#define CDIM 768
#define NEXP 8
#define HID  2048
#define TMAX 72
#define NPAD (TMAX * 64)

typedef __hip_bfloat16 bf16;
typedef short bf16x8 __attribute__((ext_vector_type(8)));
typedef float f32x4  __attribute__((ext_vector_type(4)));

__device__ __forceinline__ short f2bf(float x) {
    unsigned u = __float_as_uint(x);
    unsigned r = (u + 0x7fff + ((u >> 16) & 1)) >> 16;
    return (short)r;
}
__device__ __forceinline__ float bf2f(short s) {
    return __uint_as_float(((unsigned)(unsigned short)s) << 16);
}

// ---------------------------------------------------------------- complex LN
__global__ __launch_bounds__(256)
void cln_kernel(const float* __restrict__ xr, const float* __restrict__ xi,
                const float* __restrict__ g,
                float* __restrict__ hr, float* __restrict__ hi)
{
    const int F = FF;
    long base = (long)blockIdx.x * F;
    int t = threadIdx.x;
    int j0 = t, j1 = t + 256;
    float xr0 = xr[base + j0], xi0 = xi[base + j0];
    float xr1 = xr[base + j1], xi1 = xi[base + j1];
    float a0 = sqrtf(xr0 * xr0 + xi0 * xi0 + 1e-6f);
    float a1 = sqrtf(xr1 * xr1 + xi1 * xi1 + 1e-6f);
    float s = a0 + a1;
#pragma unroll
    for (int off = 32; off >= 1; off >>= 1) s += __shfl_xor(s, off);
    __shared__ float wsum[4];
    if ((t & 63) == 0) wsum[t >> 6] = s;
    __syncthreads();
    float mean = (wsum[0] + wsum[1] + wsum[2] + wsum[3]) * (1.0f / 512.0f);
    float d0 = g[j0] * (a0 / (mean + 1e-6f)) / (a0 + 1e-6f);
    float d1 = g[j1] * (a1 / (mean + 1e-6f)) / (a1 + 1e-6f);
    hr[base + j0] = xr0 * d0;  hi[base + j0] = xi0 * d0;
    hr[base + j1] = xr1 * d1;  hi[base + j1] = xi1 * d1;
}

// --------------------------------------------------- fp32 -> bf16x3 A expand
__global__ __launch_bounds__(256)
void expandA_x3(const float* __restrict__ sR, const float* __restrict__ sI,
                bf16* __restrict__ dR, bf16* __restrict__ dI, int K)
{
    int k = blockIdx.x * 256 + threadIdx.x;
    int m = blockIdx.y;
    long s = (long)m * K + k;
    long d = (long)m * 3 * K + k;
    float a = sR[s];
    bf16 ah = __float2bfloat16(a);
    bf16 al = __float2bfloat16(a - __bfloat162float(ah));
    dR[d] = ah; dR[d + K] = al; dR[d + 2 * K] = ah;
    float b = sI[s];
    bf16 bh = __float2bfloat16(b);
    bf16 bl = __float2bfloat16(b - __bfloat162float(bh));
    dI[d] = bh; dI[d + K] = bl; dI[d + 2 * K] = bh;
}

__global__ __launch_bounds__(256)
void convA_plain(const float* __restrict__ sR, const float* __restrict__ sI,
                 bf16* __restrict__ dR, bf16* __restrict__ dI, int K)
{
    int k = blockIdx.x * 256 + threadIdx.x;
    long s = (long)blockIdx.y * K + k;
    dR[s] = __float2bfloat16(sR[s]);
    dI[s] = __float2bfloat16(sI[s]);
}

// ---------------------------------- W -> packed MFMA-fragment layout, bf16x3
__global__ __launch_bounds__(256)
void expandW_x3_packed(const float* __restrict__ sR, const float* __restrict__ sI,
                       bf16* __restrict__ dR, bf16* __restrict__ dI,
                       int N, int kdiv /*K/32*/)
{
    int g = blockIdx.x * 256 + threadIdx.x;
    int nt = g >> 6, l = g & 63;
    int kc = blockIdx.y;
    int t3 = (kc >= kdiv) + (kc >= 2 * kdiv);
    int kb = (kc - t3 * kdiv) * 32 + (l >> 4) * 8;
    int n  = nt * 16 + (l & 15);
    long dbase = ((long)kc * (N >> 4) + nt) * 512 + l * 8;
#pragma unroll
    for (int j = 0; j < 8; j++) {
        float a = sR[(long)(kb + j) * N + n];
        bf16 ah = __float2bfloat16(a);
        dR[dbase + j] = (t3 < 2) ? ah : __float2bfloat16(a - __bfloat162float(ah));
        float b = sI[(long)(kb + j) * N + n];
        bf16 bh = __float2bfloat16(b);
        dI[dbase + j] = (t3 < 2) ? bh : __float2bfloat16(b - __bfloat162float(bh));
    }
}

__global__ __launch_bounds__(256)
void convW_packed(const float* __restrict__ sR, const float* __restrict__ sI,
                  bf16* __restrict__ dR, bf16* __restrict__ dI,
                  int N, long estride)
{
    int g = blockIdx.x * 256 + threadIdx.x;
    int nt = g >> 6, l = g & 63;
    int kc = blockIdx.y;
    int e  = blockIdx.z;
    const float* srcR = sR + (long)e * estride;
    const float* srcI = sI + (long)e * estride;
    bf16* dstR = dR + (long)e * estride;
    bf16* dstI = dI + (long)e * estride;
    int kb = kc * 32 + (l >> 4) * 8;
    int n  = nt * 16 + (l & 15);
    long dbase = ((long)kc * (N >> 4) + nt) * 512 + l * 8;
#pragma unroll
    for (int j = 0; j < 8; j++) {
        dstR[dbase + j] = __float2bfloat16(srcR[(long)(kb + j) * N + n]);
        dstI[dbase + j] = __float2bfloat16(srcI[(long)(kb + j) * N + n]);
    }
}

// -------------------------------------------------- complex MFMA GEMM 64x64
template<bool EXPERT, bool GATHER, bool MODRELU, bool RESID, bool OUTBF16>
__global__ __launch_bounds__(256)
void cgemm_mfma(const bf16* __restrict__ Ar, const bf16* __restrict__ Ai, int lda,
                const bf16* __restrict__ Wr, const bf16* __restrict__ Wi,
                long wstride, int ntTot,
                const float* __restrict__ br, const float* __restrict__ bi, int bstride,
                const float* __restrict__ mb,
                const float* __restrict__ Rr, const float* __restrict__ Ri,
                void* __restrict__ Crv, void* __restrict__ Civ, int ldc, int Kp,
                const int* __restrict__ order, const int* __restrict__ tileExpert)
{
    __shared__ short sA[8192];
    __shared__ short sW[8192];
    int tm = blockIdx.x, tn = blockIdx.y;
    if (EXPERT) {
        int e = tileExpert[tm];
        if (e < 0) return;
        Wr += (long)e * wstride;  Wi += (long)e * wstride;
        br += (long)e * bstride;  bi += (long)e * bstride;
        if (MODRELU) mb += (long)e * bstride;
    }
    int t = threadIdx.x;
    int m = t & 63, jj = t >> 6;
    int aldsLane = (jj << 4) + (m & 15);
    int mt = m >> 4;
    long abase; bool aok = true;
    {
        int arow = tm * 64 + m;
        if (GATHER) { int g = order[arow]; aok = (g >= 0); abase = (long)(aok ? g : 0) * lda; }
        else abase = (long)arow * lda;
    }
    int wl = t & 63, wb = t >> 6;
    int l = t & 63, w = t >> 6;
    int wm = w & 1, wn = w >> 1;

    f32x4 z = {0.f, 0.f, 0.f, 0.f};
    f32x4 accR[2][2], accI[2][2];
#pragma unroll
    for (int a = 0; a < 2; a++)
#pragma unroll
        for (int b = 0; b < 2; b++) { accR[a][b] = z; accI[a][b] = z; }

    const bf16x8 sgn = {(short)0x8000,(short)0x8000,(short)0x8000,(short)0x8000,
                        (short)0x8000,(short)0x8000,(short)0x8000,(short)0x8000};

    for (int k0 = 0; k0 < Kp; k0 += 64) {
        __syncthreads();
#pragma unroll
        for (int ri = 0; ri < 2; ri++) {
            const bf16* src = ri ? Ai : Ar;
#pragma unroll
            for (int kc = 0; kc < 2; kc++) {
                bf16x8 v = {};
                if (!GATHER || aok)
                    v = *(const bf16x8*)&src[abase + k0 + kc * 32 + jj * 8];
                *(bf16x8*)&sA[((((ri * 2 + kc) << 2) + mt) << 9) + aldsLane * 8] = v;
            }
        }
        int kc0 = k0 >> 5;
#pragma unroll
        for (int it = 0; it < 4; it++) {
            int b  = (it << 2) + wb;
            int ri = b >> 3, kc = (b >> 2) & 1, ntl = b & 3;
            const bf16* src = ri ? Wi : Wr;
            bf16x8 v = *(const bf16x8*)&src[(((long)(kc0 + kc) * ntTot + tn * 4 + ntl) << 9) + wl * 8];
            *(bf16x8*)&sW[((((ri * 2 + kc) << 2) + ntl) << 9) + wl * 8] = v;
        }
        __syncthreads();
#pragma unroll
        for (int kc = 0; kc < 2; kc++) {
            bf16x8 arf[2], aif[2], naf[2], wrf[2], wif[2];
#pragma unroll
            for (int s = 0; s < 2; s++) {
                arf[s] = *(const bf16x8*)&sA[(((kc << 2) + wm * 2 + s) << 9) + l * 8];
                aif[s] = *(const bf16x8*)&sA[((((2 + kc) << 2) + wm * 2 + s) << 9) + l * 8];
                naf[s] = aif[s] ^ sgn;
                wrf[s] = *(const bf16x8*)&sW[(((kc << 2) + wn * 2 + s) << 9) + l * 8];
                wif[s] = *(const bf16x8*)&sW[((((2 + kc) << 2) + wn * 2 + s) << 9) + l * 8];
            }
#pragma unroll
            for (int sm = 0; sm < 2; sm++)
#pragma unroll
                for (int sn = 0; sn < 2; sn++) {
                    accR[sm][sn] = __builtin_amdgcn_mfma_f32_16x16x32_bf16(arf[sm], wrf[sn], accR[sm][sn], 0, 0, 0);
                    accR[sm][sn] = __builtin_amdgcn_mfma_f32_16x16x32_bf16(naf[sm], wif[sn], accR[sm][sn], 0, 0, 0);
                    accI[sm][sn] = __builtin_amdgcn_mfma_f32_16x16x32_bf16(arf[sm], wif[sn], accI[sm][sn], 0, 0, 0);
                    accI[sm][sn] = __builtin_amdgcn_mfma_f32_16x16x32_bf16(aif[sm], wrf[sn], accI[sm][sn], 0, 0, 0);
                }
        }
    }
#pragma unroll
    for (int sm = 0; sm < 2; sm++)
#pragma unroll
        for (int sn = 0; sn < 2; sn++) {
            int row0 = tm * 64 + (wm * 2 + sm) * 16 + (l >> 4) * 4;
            int col  = tn * 64 + (wn * 2 + sn) * 16 + (l & 15);
            float bre = br[col], bie = bi[col];
            float mbe = MODRELU ? mb[col] : 0.f;
#pragma unroll
            for (int v = 0; v < 4; v++) {
                int row = row0 + v;
                float vr = accR[sm][sn][v] + bre;
                float vi = accI[sm][sn][v] + bie;
                if (MODRELU) {
                    float amp = sqrtf(vr * vr + vi * vi + 1e-10f);
                    float sc = fmaxf(amp + mbe, 0.f) / (amp + 1e-10f);
                    vr *= sc; vi *= sc;
                }
                long cidx = (long)row * ldc + col;
                if (RESID) { vr += Rr[cidx]; vi += Ri[cidx]; }
                if (OUTBF16) {
                    ((bf16*)Crv)[cidx] = __float2bfloat16(vr);
                    ((bf16*)Civ)[cidx] = __float2bfloat16(vi);
                } else {
                    ((float*)Crv)[cidx] = vr;
                    ((float*)Civ)[cidx] = vi;
                }
            }
        }
}

// ------------------------------- MFMA flash complex attention (bf16x3 exact)
// Block: 64 q-rows x (head, batch); 4 waves, 16 q-rows each. K-tiles of 32.
// scores = (Qr.Kr^T + Qi.Ki^T)*0.125 via x3 split; online softmax fp32;
// PV via Ph.Vh + Pl.Vh + Ph.Vl (both r and i outputs).
__global__ __launch_bounds__(256)
void cattn_mfma(const float* __restrict__ qr, const float* __restrict__ qi,
                const float* __restrict__ kr, const float* __restrict__ ki,
                const float* __restrict__ vr, const float* __restrict__ vi,
                float* __restrict__ mr, float* __restrict__ mi,
                int S, int Sk)
{
    __shared__ short sK[8192];  // [ri][hl][c][nt2][64][8]
    __shared__ short sV[8192];  // [ri][hl][nt4][64][8]
    __shared__ short sP[5120];  // [w][hl][16][40]
    const int F = FF;
    int qt = blockIdx.x, h = blockIdx.y, b = blockIdx.z;
    int t = threadIdx.x;
    int w = t >> 6, l = t & 63, q = l >> 4, n16 = l & 15;

    // ---- Q fragments in registers (A operand), x3 split
    bf16x8 qh_[2][2], ql_[2][2];   // [ri][chunk]
    {
        long qbase = ((long)(b * S + qt * 64 + w * 16 + n16)) * F + h * 64 + q * 8;
#pragma unroll
        for (int ri = 0; ri < 2; ri++) {
            const float* src = ri ? qi : qr;
#pragma unroll
            for (int c = 0; c < 2; c++) {
#pragma unroll
                for (int j = 0; j < 8; j++) {
                    float x = src[qbase + c * 32 + j];
                    short xh = f2bf(x);
                    qh_[ri][c][j] = xh;
                    ql_[ri][c][j] = f2bf(x - bf2f(xh));
                }
            }
        }
    }

    f32x4 zf = {0.f, 0.f, 0.f, 0.f};
    f32x4 oR[4], oI[4];
#pragma unroll
    for (int nt = 0; nt < 4; nt++) { oR[nt] = zf; oI[nt] = zf; }
    float m_run[4] = {-3.0e38f, -3.0e38f, -3.0e38f, -3.0e38f};
    float l_run[4] = {0.f, 0.f, 0.f, 0.f};

    int nkt = Sk >> 5;
    for (int kt = 0; kt < nkt; kt++) {
        __syncthreads();
        // ---- stage K fragments (B operand for scores: B[k=d'][n=key])
#pragma unroll
        for (int it = 0; it < 2; it++) {
            int s = t + 256 * it;
            int sl = s & 63, g = s >> 6;              // g 0..7
            int ri = g >> 2, c = (g >> 1) & 1, nt = g & 1;
            int sq = sl >> 4, sn = sl & 15;
            const float* src = ri ? ki : kr;
            long base = ((long)(b * Sk + kt * 32 + nt * 16 + sn)) * F + h * 64 + c * 32 + sq * 8;
            int outH = ((((ri * 2 + 0) * 2 + c) * 2 + nt) * 64 + sl) * 8;
            int outL = ((((ri * 2 + 1) * 2 + c) * 2 + nt) * 64 + sl) * 8;
#pragma unroll
            for (int j = 0; j < 8; j++) {
                float x = src[base + j];
                short xh = f2bf(x);
                sK[outH + j] = xh;
                sK[outL + j] = f2bf(x - bf2f(xh));
            }
        }
        // ---- stage V fragments (B operand for PV: B[k=key][n=d])
#pragma unroll
        for (int it = 0; it < 2; it++) {
            int s = t + 256 * it;
            int sl = s & 63, g = s >> 6;
            int ri = g >> 2, nt = g & 3;
            int sq = sl >> 4, sn = sl & 15;
            const float* src = ri ? vi : vr;
            long base = ((long)(b * Sk + kt * 32 + sq * 8)) * F + h * 64 + nt * 16 + sn;
            int outH = (((ri * 2 + 0) * 4 + nt) * 64 + sl) * 8;
            int outL = (((ri * 2 + 1) * 4 + nt) * 64 + sl) * 8;
#pragma unroll
            for (int j = 0; j < 8; j++) {
                float x = src[base + (long)j * F];
                short xh = f2bf(x);
                sV[outH + j] = xh;
                sV[outL + j] = f2bf(x - bf2f(xh));
            }
        }
        __syncthreads();

        // ---- scores (x3: QhKh + QlKh + QhKl, r and i)
        f32x4 sc[2];
        sc[0] = zf; sc[1] = zf;
#pragma unroll
        for (int nt = 0; nt < 2; nt++) {
#pragma unroll
            for (int ri = 0; ri < 2; ri++) {
                bf16x8 kh0 = *(const bf16x8*)&sK[((((ri * 2 + 0) * 2 + 0) * 2 + nt) * 64 + l) * 8];
                bf16x8 kh1 = *(const bf16x8*)&sK[((((ri * 2 + 0) * 2 + 1) * 2 + nt) * 64 + l) * 8];
                bf16x8 kl0 = *(const bf16x8*)&sK[((((ri * 2 + 1) * 2 + 0) * 2 + nt) * 64 + l) * 8];
                bf16x8 kl1 = *(const bf16x8*)&sK[((((ri * 2 + 1) * 2 + 1) * 2 + nt) * 64 + l) * 8];
                sc[nt] = __builtin_amdgcn_mfma_f32_16x16x32_bf16(qh_[ri][0], kh0, sc[nt], 0, 0, 0);
                sc[nt] = __builtin_amdgcn_mfma_f32_16x16x32_bf16(qh_[ri][1], kh1, sc[nt], 0, 0, 0);
                sc[nt] = __builtin_amdgcn_mfma_f32_16x16x32_bf16(ql_[ri][0], kh0, sc[nt], 0, 0, 0);
                sc[nt] = __builtin_amdgcn_mfma_f32_16x16x32_bf16(ql_[ri][1], kh1, sc[nt], 0, 0, 0);
                sc[nt] = __builtin_amdgcn_mfma_f32_16x16x32_bf16(qh_[ri][0], kl0, sc[nt], 0, 0, 0);
                sc[nt] = __builtin_amdgcn_mfma_f32_16x16x32_bf16(qh_[ri][1], kl1, sc[nt], 0, 0, 0);
            }
        }
        // ---- online softmax (row = q*4+v across 16 lanes of quad)
        float alpha[4];
#pragma unroll
        for (int v = 0; v < 4; v++) {
            float s0 = sc[0][v] * 0.125f, s1 = sc[1][v] * 0.125f;
            float mx = fmaxf(s0, s1);
            mx = fmaxf(mx, __shfl_xor(mx, 1));
            mx = fmaxf(mx, __shfl_xor(mx, 2));
            mx = fmaxf(mx, __shfl_xor(mx, 4));
            mx = fmaxf(mx, __shfl_xor(mx, 8));
            float mnew = fmaxf(m_run[v], mx);
            float p0 = expf(s0 - mnew), p1 = expf(s1 - mnew);
            sc[0][v] = p0; sc[1][v] = p1;
            float ps = p0 + p1;
            ps += __shfl_xor(ps, 1);
            ps += __shfl_xor(ps, 2);
            ps += __shfl_xor(ps, 4);
            ps += __shfl_xor(ps, 8);
            alpha[v] = expf(m_run[v] - mnew);
            l_run[v] = l_run[v] * alpha[v] + ps;
            m_run[v] = mnew;
        }
#pragma unroll
        for (int nt = 0; nt < 4; nt++)
#pragma unroll
            for (int v = 0; v < 4; v++) { oR[nt][v] *= alpha[v]; oI[nt][v] *= alpha[v]; }
        // ---- P -> LDS (C layout -> A fragment layout), h/l split
        int pbase = w * 1280;
#pragma unroll
        for (int nt = 0; nt < 2; nt++)
#pragma unroll
            for (int v = 0; v < 4; v++) {
                float p = sc[nt][v];
                short ph = f2bf(p);
                short pl = f2bf(p - bf2f(ph));
                int idx = pbase + (q * 4 + v) * 40 + nt * 16 + n16;
                sP[idx] = ph;
                sP[idx + 640] = pl;
            }
        bf16x8 pH = *(const bf16x8*)&sP[pbase + n16 * 40 + q * 8];
        bf16x8 pL = *(const bf16x8*)&sP[pbase + 640 + n16 * 40 + q * 8];
        // ---- PV (x3: PhVh + PlVh + PhVl)
#pragma unroll
        for (int nt = 0; nt < 4; nt++) {
            bf16x8 vh = *(const bf16x8*)&sV[(((0 * 2 + 0) * 4 + nt) * 64 + l) * 8];
            bf16x8 vl = *(const bf16x8*)&sV[(((0 * 2 + 1) * 4 + nt) * 64 + l) * 8];
            oR[nt] = __builtin_amdgcn_mfma_f32_16x16x32_bf16(pH, vh, oR[nt], 0, 0, 0);
            oR[nt] = __builtin_amdgcn_mfma_f32_16x16x32_bf16(pL, vh, oR[nt], 0, 0, 0);
            oR[nt] = __builtin_amdgcn_mfma_f32_16x16x32_bf16(pH, vl, oR[nt], 0, 0, 0);
            bf16x8 wh = *(const bf16x8*)&sV[(((1 * 2 + 0) * 4 + nt) * 64 + l) * 8];
            bf16x8 wl2 = *(const bf16x8*)&sV[(((1 * 2 + 1) * 4 + nt) * 64 + l) * 8];
            oI[nt] = __builtin_amdgcn_mfma_f32_16x16x32_bf16(pH, wh, oI[nt], 0, 0, 0);
            oI[nt] = __builtin_amdgcn_mfma_f32_16x16x32_bf16(pL, wh, oI[nt], 0, 0, 0);
            oI[nt] = __builtin_amdgcn_mfma_f32_16x16x32_bf16(pH, wl2, oI[nt], 0, 0, 0);
        }
    }
    // ---- epilogue
#pragma unroll
    for (int v = 0; v < 4; v++) {
        float inv = 1.0f / l_run[v];
        long obase = ((long)(b * S + qt * 64 + w * 16 + q * 4 + v)) * F + h * 64 + n16;
#pragma unroll
        for (int nt = 0; nt < 4; nt++) {
            mr[obase + nt * 16] = oR[nt][v] * inv;
            mi[obase + nt * 16] = oI[nt][v] * inv;
        }
    }
}

// ----------------------------------------------------------------- routing
__global__ __launch_bounds__(256)
void route_kernel(const float* __restrict__ hr, const float* __restrict__ hi,
                  int* __restrict__ eidx)
{
    const int F = FF;
    long base = (long)blockIdx.x * F;
    int t = threadIdx.x;
    double ss = 0.0, cc = 0.0;
#pragma unroll
    for (int u = 0; u < 2; u++) {
        int j = t + u * 256;
        float ph = atan2f(hi[base + j], hr[base + j]);
        ss += (double)sinf(ph);
        cc += (double)cosf(ph);
    }
#pragma unroll
    for (int off = 32; off >= 1; off >>= 1) {
        ss += __shfl_xor(ss, off);
        cc += __shfl_xor(cc, off);
    }
    __shared__ double wss[4], wcc[4];
    if ((t & 63) == 0) { wss[t >> 6] = ss; wcc[t >> 6] = cc; }
    __syncthreads();
    if (t == 0) {
        float msin = (float)((wss[0] + wss[1] + wss[2] + wss[3]) * (1.0 / 512.0));
        float mcos = (float)((wcc[0] + wcc[1] + wcc[2] + wcc[3]) * (1.0 / 512.0));
        float tp = atan2f(msin, mcos);
        float a = (tp + 3.14159274101257324f) / 6.28318548202514648f * 8.0f;
        int k = (int)floorf(a);
        k = min(max(k, 0), NEXP - 1);
        eidx[blockIdx.x] = k;
    }
}

__global__ __launch_bounds__(256)
void moe_build_kernel(const int* __restrict__ eidx, int* __restrict__ order,
                      int* __restrict__ tileExpert)
{
    __shared__ int cnt[NEXP], segbase[NEXP], cursor[NEXP], tbase[NEXP];
    int t = threadIdx.x;
    if (t < NEXP) { cnt[t] = 0; cursor[t] = 0; }
    __syncthreads();
    for (int i = t; i < NTOK; i += 256) atomicAdd(&cnt[eidx[i]], 1);
    __syncthreads();
    if (t == 0) {
        int ob = 0, tb = 0;
        for (int e = 0; e < NEXP; e++) {
            segbase[e] = ob; tbase[e] = tb;
            int tiles = (cnt[e] + 63) >> 6;
            ob += tiles << 6; tb += tiles;
        }
    }
    __syncthreads();
    for (int i = t; i < NPAD; i += 256) order[i] = -1;
    if (t < TMAX) {
        int ex = -1;
        for (int e = 0; e < NEXP; e++) {
            int tiles = (cnt[e] + 63) >> 6;
            if (t >= tbase[e] && t < tbase[e] + tiles) ex = e;
        }
        tileExpert[t] = ex;
    }
    __syncthreads();
    for (int i = t; i < NTOK; i += 256) {
        int e = eidx[i];
        int pos = atomicAdd(&cursor[e], 1);
        order[segbase[e] + pos] = i;
    }
}

__global__ __launch_bounds__(256)
void combine_kernel(const int* __restrict__ order,
                    const float* __restrict__ xr, const float* __restrict__ xi,
                    const float* __restrict__ yr, const float* __restrict__ yi,
                    float* __restrict__ out)
{
    const int F = FF;
    int p = blockIdx.x;
    int tok = order[p];
    if (tok < 0) return;
    int t = threadIdx.x;
    float* outr = out;
    float* outi = out + (long)NTOK * FF;
#pragma unroll
    for (int u = 0; u < 2; u++) {
        int j = t + u * 256;
        long src = (long)p * F + j;
        long dst = (long)tok * F + j;
        outr[dst] = xr[dst] + yr[src];
        outi[dst] = xi[dst] + yi[src];
    }
}

// ------------------------------------------------------------------- launch
extern "C" void kernel_launch(void* const* d_in, const int* in_sizes, int n_in,
                              void* d_out, int out_size, void* d_ws, size_t ws_size,
                              hipStream_t stream)
{
    (void)in_sizes; (void)n_in; (void)out_size; (void)ws_size;
    const float* x_r   = (const float*)d_in[0];
    const float* x_i   = (const float*)d_in[1];
    const float* ctx_r = (const float*)d_in[2];
    const float* ctx_i = (const float*)d_in[3];
    const float* ln1_g = (const float*)d_in[4];
    const float* ln2_g = (const float*)d_in[5];
    const float* ln3_g = (const float*)d_in[6];
    const float* sa_qWr = (const float*)d_in[7];   const float* sa_qWi = (const float*)d_in[8];
    const float* sa_qbr = (const float*)d_in[9];   const float* sa_qbi = (const float*)d_in[10];
    const float* sa_kWr = (const float*)d_in[11];  const float* sa_kWi = (const float*)d_in[12];
    const float* sa_kbr = (const float*)d_in[13];  const float* sa_kbi = (const float*)d_in[14];
    const float* sa_vWr = (const float*)d_in[15];  const float* sa_vWi = (const float*)d_in[16];
    const float* sa_vbr = (const float*)d_in[17];  const float* sa_vbi = (const float*)d_in[18];
    const float* sa_oWr = (const float*)d_in[19];  const float* sa_oWi = (const float*)d_in[20];
    const float* sa_obr = (const float*)d_in[21];  const float* sa_obi = (const float*)d_in[22];
    const float* ca_qWr = (const float*)d_in[23];  const float* ca_qWi = (const float*)d_in[24];
    const float* ca_qbr = (const float*)d_in[25];  const float* ca_qbi = (const float*)d_in[26];
    const float* ca_kWr = (const float*)d_in[27];  const float* ca_kWi = (const float*)d_in[28];
    const float* ca_kbr = (const float*)d_in[29];  const float* ca_kbi = (const float*)d_in[30];
    const float* ca_vWr = (const float*)d_in[31];  const float* ca_vWi = (const float*)d_in[32];
    const float* ca_vbr = (const float*)d_in[33];  const float* ca_vbi = (const float*)d_in[34];
    const float* ca_oWr = (const float*)d_in[35];  const float* ca_oWi = (const float*)d_in[36];
    const float* ca_obr = (const float*)d_in[37];  const float* ca_obi = (const float*)d_in[38];
    const float* moe_W1r = (const float*)d_in[39]; const float* moe_W1i = (const float*)d_in[40];
    const float* moe_b1r = (const float*)d_in[41]; const float* moe_b1i = (const float*)d_in[42];
    const float* moe_mb  = (const float*)d_in[43];
    const float* moe_W2r = (const float*)d_in[44]; const float* moe_W2i = (const float*)d_in[45];
    const float* moe_b2r = (const float*)d_in[46]; const float* moe_b2i = (const float*)d_in[47];
    float* out = (float*)d_out;

    char* W = (char*)d_ws;
    const long NF = (long)NTOK * FF;
    float* xr = (float*)(W + 0 * NF * 4);
    float* xi = (float*)(W + 1 * NF * 4);
    float* hr = (float*)(W + 2 * NF * 4);
    float* hi = (float*)(W + 3 * NF * 4);
    char* poolB = W + 4 * NF * 4;
    float* qr = (float*)poolB;                float* qi = (float*)(poolB + NF * 4);
    float* kr = (float*)(poolB + 2 * NF * 4); float* ki = (float*)(poolB + 3 * NF * 4);
    float* vr = (float*)(poolB + 4 * NF * 4); float* vi = (float*)(poolB + 5 * NF * 4);
    float* mr = (float*)(poolB + 6 * NF * 4); float* mi = (float*)(poolB + 7 * NF * 4);
    bf16* u_r = (bf16*)poolB;
    bf16* u_i = (bf16*)(poolB + 18874368);
    float* y_r = (float*)(poolB + 37748736);
    float* y_i = (float*)(poolB + 37748736 + 9437184);
    bf16* h3r = (bf16*)(poolB + 56623104);
    bf16* h3i = (bf16*)(poolB + 56623104 + 4194304);
    char* Q = W + 12 * NF * 4;
    bf16* A1r = (bf16*)Q;                   bf16* A1i = (bf16*)(Q + 12582912);
    bf16* A2r = (bf16*)(Q + 25165824);      bf16* A2i = (bf16*)(Q + 25165824 + 4718592);
    char* WQ = Q + 34603008;
    bf16* saq_r = (bf16*)(WQ + 0 * 1572864);  bf16* saq_i = (bf16*)(WQ + 1 * 1572864);
    bf16* sak_r = (bf16*)(WQ + 2 * 1572864);  bf16* sak_i = (bf16*)(WQ + 3 * 1572864);
    bf16* sav_r = (bf16*)(WQ + 4 * 1572864);  bf16* sav_i = (bf16*)(WQ + 5 * 1572864);
    bf16* sao_r = (bf16*)(WQ + 6 * 1572864);  bf16* sao_i = (bf16*)(WQ + 7 * 1572864);
    bf16* caq_r = (bf16*)(WQ + 8 * 1572864);  bf16* caq_i = (bf16*)(WQ + 9 * 1572864);
    bf16* cao_r = (bf16*)(WQ + 10 * 1572864); bf16* cao_i = (bf16*)(WQ + 11 * 1572864);
    bf16* cak_r = (bf16*)(WQ + 12 * 1572864);
    bf16* cak_i = (bf16*)(WQ + 12 * 1572864 + 2359296);
    bf16* cav_r = (bf16*)(WQ + 12 * 1572864 + 2 * 2359296);
    bf16* cav_i = (bf16*)(WQ + 12 * 1572864 + 3 * 2359296);
    bf16* Wm_r = (bf16*)Q;
    bf16* Wm_i = (bf16*)(Q + 16777216);
    int* eidx       = (int*)(W + 12 * NF * 4 + 62914560);
    int* order      = eidx + NTOK;
    int* tileExpert = order + NPAD;

    dim3 blk(256);
    const long W1S = (long)FF * HID;

    expandW_x3_packed<<<dim3(8, 48), blk, 0, stream>>>(sa_qWr, sa_qWi, saq_r, saq_i, FF, 16);
    expandW_x3_packed<<<dim3(8, 48), blk, 0, stream>>>(sa_kWr, sa_kWi, sak_r, sak_i, FF, 16);
    expandW_x3_packed<<<dim3(8, 48), blk, 0, stream>>>(sa_vWr, sa_vWi, sav_r, sav_i, FF, 16);
    expandW_x3_packed<<<dim3(8, 48), blk, 0, stream>>>(sa_oWr, sa_oWi, sao_r, sao_i, FF, 16);
    expandW_x3_packed<<<dim3(8, 48), blk, 0, stream>>>(ca_qWr, ca_qWi, caq_r, caq_i, FF, 16);
    expandW_x3_packed<<<dim3(8, 48), blk, 0, stream>>>(ca_oWr, ca_oWi, cao_r, cao_i, FF, 16);
    expandW_x3_packed<<<dim3(8, 72), blk, 0, stream>>>(ca_kWr, ca_kWi, cak_r, cak_i, FF, 24);
    expandW_x3_packed<<<dim3(8, 72), blk, 0, stream>>>(ca_vWr, ca_vWi, cav_r, cav_i, FF, 24);

    // ---- self-attention block
    cln_kernel<<<NTOK, blk, 0, stream>>>(x_r, x_i, ln1_g, hr, hi);
    expandA_x3<<<dim3(2, NTOK), blk, 0, stream>>>(hr, hi, A1r, A1i, FF);
    cgemm_mfma<false,false,false,false,false><<<dim3(64, 8), blk, 0, stream>>>(
        A1r, A1i, 1536, saq_r, saq_i, 0, 32, sa_qbr, sa_qbi, 0, nullptr,
        nullptr, nullptr, qr, qi, FF, 1536, nullptr, nullptr);
    cgemm_mfma<false,false,false,false,false><<<dim3(64, 8), blk, 0, stream>>>(
        A1r, A1i, 1536, sak_r, sak_i, 0, 32, sa_kbr, sa_kbi, 0, nullptr,
        nullptr, nullptr, kr, ki, FF, 1536, nullptr, nullptr);
    cgemm_mfma<false,false,false,false,false><<<dim3(64, 8), blk, 0, stream>>>(
        A1r, A1i, 1536, sav_r, sav_i, 0, 32, sa_vbr, sa_vbi, 0, nullptr,
        nullptr, nullptr, vr, vi, FF, 1536, nullptr, nullptr);
    cattn_mfma<<<dim3(16, 8, 4), blk, 0, stream>>>(qr, qi, kr, ki, vr, vi,
                                                   mr, mi, 1024, 1024);
    expandA_x3<<<dim3(2, NTOK), blk, 0, stream>>>(mr, mi, A1r, A1i, FF);
    cgemm_mfma<false,false,false,true,false><<<dim3(64, 8), blk, 0, stream>>>(
        A1r, A1i, 1536, sao_r, sao_i, 0, 32, sa_obr, sa_obi, 0, nullptr,
        x_r, x_i, xr, xi, FF, 1536, nullptr, nullptr);

    // ---- cross-attention block
    cln_kernel<<<NTOK, blk, 0, stream>>>(xr, xi, ln2_g, hr, hi);
    expandA_x3<<<dim3(2, NTOK), blk, 0, stream>>>(hr, hi, A1r, A1i, FF);
    cgemm_mfma<false,false,false,false,false><<<dim3(64, 8), blk, 0, stream>>>(
        A1r, A1i, 1536, caq_r, caq_i, 0, 32, ca_qbr, ca_qbi, 0, nullptr,
        nullptr, nullptr, qr, qi, FF, 1536, nullptr, nullptr);
    expandA_x3<<<dim3(3, 1024), blk, 0, stream>>>(ctx_r, ctx_i, A2r, A2i, CDIM);
    cgemm_mfma<false,false,false,false,false><<<dim3(16, 8), blk, 0, stream>>>(
        A2r, A2i, 2304, cak_r, cak_i, 0, 32, ca_kbr, ca_kbi, 0, nullptr,
        nullptr, nullptr, kr, ki, FF, 2304, nullptr, nullptr);
    cgemm_mfma<false,false,false,false,false><<<dim3(16, 8), blk, 0, stream>>>(
        A2r, A2i, 2304, cav_r, cav_i, 0, 32, ca_vbr, ca_vbi, 0, nullptr,
        nullptr, nullptr, vr, vi, FF, 2304, nullptr, nullptr);
    cattn_mfma<<<dim3(16, 8, 4), blk, 0, stream>>>(qr, qi, kr, ki, vr, vi,
                                                   mr, mi, 1024, 256);
    expandA_x3<<<dim3(2, NTOK), blk, 0, stream>>>(mr, mi, A1r, A1i, FF);
    cgemm_mfma<false,false,false,true,false><<<dim3(64, 8), blk, 0, stream>>>(
        A1r, A1i, 1536, cao_r, cao_i, 0, 32, ca_obr, ca_obi, 0, nullptr,
        xr, xi, xr, xi, FF, 1536, nullptr, nullptr);

    // ---- phase-routed MoE
    cln_kernel<<<NTOK, blk, 0, stream>>>(xr, xi, ln3_g, hr, hi);
    route_kernel<<<NTOK, blk, 0, stream>>>(hr, hi, eidx);
    moe_build_kernel<<<1, blk, 0, stream>>>(eidx, order, tileExpert);
    convA_plain<<<dim3(2, NTOK), blk, 0, stream>>>(hr, hi, h3r, h3i, FF);
    convW_packed<<<dim3(32, 16, 8), blk, 0, stream>>>(moe_W1r, moe_W1i, Wm_r, Wm_i, HID, W1S);
    cgemm_mfma<true,true,true,false,true><<<dim3(TMAX, 32), blk, 0, stream>>>(
        h3r, h3i, FF, Wm_r, Wm_i, W1S, 128, moe_b1r, moe_b1i, HID, moe_mb,
        nullptr, nullptr, u_r, u_i, HID, FF, order, tileExpert);
    convW_packed<<<dim3(8, 64, 8), blk, 0, stream>>>(moe_W2r, moe_W2i, Wm_r, Wm_i, FF, W1S);
    cgemm_mfma<true,false,false,false,false><<<dim3(TMAX, 8), blk, 0, stream>>>(
        u_r, u_i, HID, Wm_r, Wm_i, W1S, 32, moe_b2r, moe_b2i, FF, nullptr,
        nullptr, nullptr, y_r, y_i, FF, HID, order, tileExpert);
    combine_kernel<<<NPAD, blk, 0, stream>>>(order, xr, xi, y_r, y_i, out);
}

// Round 4
// 894.545 us; speedup vs baseline: 8.1296x; 1.1522x over previous
//
#include <hip/hip_runtime.h>
#include <hip/hip_bf16.h>
#include <math.h>

// ComplexTransformerBlock: B=4 S=1024 L=256 F=512 CD=768 NH=8 (d=64) E=8 HID=2048
// Round 4: global_load_lds staging in GEMM+attention; K/V pre-packed to fragment
// image; fused QKV / cross-KV dispatches; dedup x3 storage ([Ah|Al], [Wh;Wl] with
// logical-K wrap). Numerics unchanged (bf16x3 routing-critical, bf16 MoE).

#define NTOK 4096
#define FF   512
#define CDIM 768
#define NEXP 8
#define HID  2048
#define TMAX 72
#define NPAD (TMAX * 64)

typedef __hip_bfloat16 bf16;
typedef short bf16x8 __attribute__((ext_vector_type(8)));
typedef float f32x4  __attribute__((ext_vector_type(4)));

struct Ptr6 { const float* p[6]; };

__device__ __forceinline__ short f2bf(float x) {
    unsigned u = __float_as_uint(x);
    unsigned r = (u + 0x7fff + ((u >> 16) & 1)) >> 16;
    return (short)r;
}
__device__ __forceinline__ float bf2f(short s) {
    return __uint_as_float(((unsigned)(unsigned short)s) << 16);
}
__device__ __forceinline__ void gload16(const void* g, void* l) {
    __builtin_amdgcn_global_load_lds(
        (const __attribute__((address_space(1))) unsigned int*)g,
        (__attribute__((address_space(3))) unsigned int*)l, 16, 0, 0);
}

// ---------------------------------------------------------------- complex LN
__global__ __launch_bounds__(256)
void cln_kernel(const float* __restrict__ xr, const float* __restrict__ xi,
                const float* __restrict__ g,
                float* __restrict__ hr, float* __restrict__ hi)
{
    const int F = FF;
    long base = (long)blockIdx.x * F;
    int t = threadIdx.x;
    int j0 = t, j1 = t + 256;
    float xr0 = xr[base + j0], xi0 = xi[base + j0];
    float xr1 = xr[base + j1], xi1 = xi[base + j1];
    float a0 = sqrtf(xr0 * xr0 + xi0 * xi0 + 1e-6f);
    float a1 = sqrtf(xr1 * xr1 + xi1 * xi1 + 1e-6f);
    float s = a0 + a1;
#pragma unroll
    for (int off = 32; off >= 1; off >>= 1) s += __shfl_xor(s, off);
    __shared__ float wsum[4];
    if ((t & 63) == 0) wsum[t >> 6] = s;
    __syncthreads();
    float mean = (wsum[0] + wsum[1] + wsum[2] + wsum[3]) * (1.0f / 512.0f);
    float d0 = g[j0] * (a0 / (mean + 1e-6f)) / (a0 + 1e-6f);
    float d1 = g[j1] * (a1 / (mean + 1e-6f)) / (a1 + 1e-6f);
    hr[base + j0] = xr0 * d0;  hi[base + j0] = xi0 * d0;
    hr[base + j1] = xr1 * d1;  hi[base + j1] = xi1 * d1;
}

// ------------------------------------------------- fp32 -> [Ah|Al] (M x 2K)
__global__ __launch_bounds__(256)
void expandA_x2(const float* __restrict__ sR, const float* __restrict__ sI,
                bf16* __restrict__ dR, bf16* __restrict__ dI, int K)
{
    int k = blockIdx.x * 256 + threadIdx.x;
    int m = blockIdx.y;
    long s = (long)m * K + k;
    long d = (long)m * 2 * K + k;
    float a = sR[s];
    bf16 ah = __float2bfloat16(a);
    dR[d] = ah; dR[d + K] = __float2bfloat16(a - __bfloat162float(ah));
    float b = sI[s];
    bf16 bh = __float2bfloat16(b);
    dI[d] = bh; dI[d + K] = __float2bfloat16(b - __bfloat162float(bh));
}

__global__ __launch_bounds__(256)
void convA_plain(const float* __restrict__ sR, const float* __restrict__ sI,
                 bf16* __restrict__ dR, bf16* __restrict__ dI, int K)
{
    int k = blockIdx.x * 256 + threadIdx.x;
    long s = (long)blockIdx.y * K + k;
    dR[s] = __float2bfloat16(sR[s]);
    dI[s] = __float2bfloat16(sI[s]);
}

// --------------------------- W -> packed fragment layout, phys [Wh ; Wl]
// dst: [kc (2*kdiv)][nt (N/16)][lane 64][8]; lane=q*16+nn holds
// W[kseg*32 + q*8 + j][nt*16+nn], seg0=hi, seg1=lo.
__global__ __launch_bounds__(256)
void expandW_x2_packed(const float* __restrict__ sR, const float* __restrict__ sI,
                       bf16* __restrict__ dR, bf16* __restrict__ dI,
                       int N, int kdiv)
{
    int g = blockIdx.x * 256 + threadIdx.x;
    int nt = g >> 6, l = g & 63;
    int kc = blockIdx.y;                 // 0 .. 2*kdiv-1
    int lo = (kc >= kdiv);
    int kb = (kc - (lo ? kdiv : 0)) * 32 + (l >> 4) * 8;
    int n  = nt * 16 + (l & 15);
    long dbase = ((long)kc * (N >> 4) + nt) * 512 + l * 8;
#pragma unroll
    for (int j = 0; j < 8; j++) {
        float a = sR[(long)(kb + j) * N + n];
        bf16 ah = __float2bfloat16(a);
        dR[dbase + j] = lo ? __float2bfloat16(a - __bfloat162float(ah)) : ah;
        float b = sI[(long)(kb + j) * N + n];
        bf16 bh = __float2bfloat16(b);
        dI[dbase + j] = lo ? __float2bfloat16(b - __bfloat162float(bh)) : bh;
    }
}

// W -> packed plain bf16, expert-strided (MoE weights)
__global__ __launch_bounds__(256)
void convW_packed(const float* __restrict__ sR, const float* __restrict__ sI,
                  bf16* __restrict__ dR, bf16* __restrict__ dI,
                  int N, long estride)
{
    int g = blockIdx.x * 256 + threadIdx.x;
    int nt = g >> 6, l = g & 63;
    int kc = blockIdx.y;
    int e  = blockIdx.z;
    const float* srcR = sR + (long)e * estride;
    const float* srcI = sI + (long)e * estride;
    bf16* dstR = dR + (long)e * estride;
    bf16* dstI = dI + (long)e * estride;
    int kb = kc * 32 + (l >> 4) * 8;
    int n  = nt * 16 + (l & 15);
    long dbase = ((long)kc * (N >> 4) + nt) * 512 + l * 8;
#pragma unroll
    for (int j = 0; j < 8; j++) {
        dstR[dbase + j] = __float2bfloat16(srcR[(long)(kb + j) * N + n]);
        dstI[dbase + j] = __float2bfloat16(srcI[(long)(kb + j) * N + n]);
    }
}

// -------------------------------------------------- complex MFMA GEMM 64x64
// global_load_lds staging (LDS layouts are fragment/lane-linear). blockIdx.z
// selects fused weight/bias/output set. X3: logical Kp = 3*Kreal with A phys
// [Ah|Al] (wrap k>=2K) and W phys [Wh;Wl] (wrap kc>=kdiv).
template<bool X3, bool EXPERT, bool GATHER, bool MODRELU, bool RESID, bool OUTBF16>
__global__ __launch_bounds__(256)
void cgemm_mfma(const bf16* __restrict__ Ar, const bf16* __restrict__ Ai,
                int lda, int Kreal,
                const bf16* __restrict__ Wr0, const bf16* __restrict__ Wi0,
                long wz, long westride, int ntTot, int kdiv,
                Ptr6 bias, int bstride, const float* __restrict__ mb,
                const float* __restrict__ Rr, const float* __restrict__ Ri,
                void* __restrict__ Cr0, void* __restrict__ Ci0, long cz,
                int ldc, int Kp,
                const int* __restrict__ order, const int* __restrict__ tileExpert)
{
    __shared__ short sA[8192];   // [(ri*2+kc)*4 + mt][lane64*8]   16 KB
    __shared__ short sW[8192];   // [(ri*2+kc)*4 + ntl][lane64*8]  16 KB
    int tm = blockIdx.x, tn = blockIdx.y, z = blockIdx.z;
    const bf16* Wr = Wr0 + (long)z * wz;
    const bf16* Wi = Wi0 + (long)z * wz;
    const float* br = bias.p[2 * z];
    const float* bi = bias.p[2 * z + 1];
    void* Crv = (char*)Cr0 + (long)z * cz;
    void* Civ = (char*)Ci0 + (long)z * cz;
    if (EXPERT) {
        int e = tileExpert[tm];
        if (e < 0) return;
        Wr += (long)e * westride;  Wi += (long)e * westride;
        br += (long)e * bstride;   bi += (long)e * bstride;
        if (MODRELU) mb += (long)e * bstride;
    }
    int t = threadIdx.x;
    int l = t & 63, jj = t >> 6;
    int riS = jj >> 1, kcS = jj & 1;          // this wave's staging slice
    const bf16* Asrc = riS ? Ai : Ar;
    const bf16* Wsrc = riS ? Wi : Wr;
    int kq8 = (l >> 4) * 8;
    long arb[4];
#pragma unroll
    for (int mt = 0; mt < 4; mt++) {
        int grow = tm * 64 + mt * 16 + (l & 15);
        int tok = grow;
        if (GATHER) { int gg = order[grow]; tok = (gg < 0) ? 0 : gg; }
        arb[mt] = (long)tok * lda;
    }
    int wm = jj & 1, wn = jj >> 1;            // compute coords

    f32x4 zf = {0.f, 0.f, 0.f, 0.f};
    f32x4 accR[2][2], accI[2][2];
#pragma unroll
    for (int a = 0; a < 2; a++)
#pragma unroll
        for (int b = 0; b < 2; b++) { accR[a][b] = zf; accI[a][b] = zf; }

    const bf16x8 sgn = {(short)0x8000,(short)0x8000,(short)0x8000,(short)0x8000,
                        (short)0x8000,(short)0x8000,(short)0x8000,(short)0x8000};

    for (int k0 = 0; k0 < Kp; k0 += 64) {
        __syncthreads();
        // ---- stage A: 4 blocks (this wave's (riS,kcS), mt 0..3)
        int lc = k0 + kcS * 32;
        int acol = (X3 && lc >= 2 * Kreal) ? lc - 2 * Kreal : lc;
#pragma unroll
        for (int mt = 0; mt < 4; mt++)
            gload16(Asrc + arb[mt] + acol + kq8,
                    &sA[(((riS * 2 + kcS) << 2) + mt) << 9]);
        // ---- stage W: 4 blocks (contiguous 1KB each in the pack)
        int kcl = (k0 >> 5) + kcS;
        int pkc = (X3 && kcl >= kdiv) ? kcl - kdiv : kcl;
        const bf16* wbase = Wsrc + (((long)pkc * ntTot + tn * 4) << 9) + l * 8;
#pragma unroll
        for (int ntl = 0; ntl < 4; ntl++)
            gload16(wbase + (ntl << 9),
                    &sW[(((riS * 2 + kcS) << 2) + ntl) << 9]);
        __syncthreads();
        // ---- compute
#pragma unroll
        for (int kc = 0; kc < 2; kc++) {
            bf16x8 arf[2], aif[2], naf[2], wrf[2], wif[2];
#pragma unroll
            for (int s = 0; s < 2; s++) {
                arf[s] = *(const bf16x8*)&sA[(((kc << 2) + wm * 2 + s) << 9) + l * 8];
                aif[s] = *(const bf16x8*)&sA[((((2 + kc) << 2) + wm * 2 + s) << 9) + l * 8];
                naf[s] = aif[s] ^ sgn;
                wrf[s] = *(const bf16x8*)&sW[(((kc << 2) + wn * 2 + s) << 9) + l * 8];
                wif[s] = *(const bf16x8*)&sW[((((2 + kc) << 2) + wn * 2 + s) << 9) + l * 8];
            }
#pragma unroll
            for (int sm = 0; sm < 2; sm++)
#pragma unroll
                for (int sn = 0; sn < 2; sn++) {
                    accR[sm][sn] = __builtin_amdgcn_mfma_f32_16x16x32_bf16(arf[sm], wrf[sn], accR[sm][sn], 0, 0, 0);
                    accR[sm][sn] = __builtin_amdgcn_mfma_f32_16x16x32_bf16(naf[sm], wif[sn], accR[sm][sn], 0, 0, 0);
                    accI[sm][sn] = __builtin_amdgcn_mfma_f32_16x16x32_bf16(arf[sm], wif[sn], accI[sm][sn], 0, 0, 0);
                    accI[sm][sn] = __builtin_amdgcn_mfma_f32_16x16x32_bf16(aif[sm], wrf[sn], accI[sm][sn], 0, 0, 0);
                }
        }
    }
    // ---- epilogue: C/D layout col=lane&15, row=(lane>>4)*4+reg
#pragma unroll
    for (int sm = 0; sm < 2; sm++)
#pragma unroll
        for (int sn = 0; sn < 2; sn++) {
            int row0 = tm * 64 + (wm * 2 + sm) * 16 + (l >> 4) * 4;
            int col  = tn * 64 + (wn * 2 + sn) * 16 + (l & 15);
            float bre = br[col], bie = bi[col];
            float mbe = MODRELU ? mb[col] : 0.f;
#pragma unroll
            for (int v = 0; v < 4; v++) {
                int row = row0 + v;
                float vr = accR[sm][sn][v] + bre;
                float vi = accI[sm][sn][v] + bie;
                if (MODRELU) {
                    float amp = sqrtf(vr * vr + vi * vi + 1e-10f);
                    float sc = fmaxf(amp + mbe, 0.f) / (amp + 1e-10f);
                    vr *= sc; vi *= sc;
                }
                long cidx = (long)row * ldc + col;
                if (RESID) { vr += Rr[cidx]; vi += Ri[cidx]; }
                if (OUTBF16) {
                    ((bf16*)Crv)[cidx] = __float2bfloat16(vr);
                    ((bf16*)Civ)[cidx] = __float2bfloat16(vi);
                } else {
                    ((float*)Crv)[cidx] = vr;
                    ((float*)Civ)[cidx] = vi;
                }
            }
        }
}

// ------------------- pack K/V into attention LDS fragment image (bf16 hi/lo)
// pK/pV: per (b,h,kt): 8192 shorts each, mirroring cattn's sK/sV exactly.
__global__ __launch_bounds__(256)
void pack_kv(const float* __restrict__ kr, const float* __restrict__ ki,
             const float* __restrict__ vr, const float* __restrict__ vi,
             short* __restrict__ pK, short* __restrict__ pV, int Sk)
{
    const int F = FF;
    int kt = blockIdx.x, h = blockIdx.y, b = blockIdx.z;
    int nkt = gridDim.x;
    long blkbase = ((long)((b * 8 + h) * nkt) + kt) * 8192;
    int t = threadIdx.x;
#pragma unroll
    for (int it = 0; it < 2; it++) {
        int s = t + 256 * it;
        int sl = s & 63, g = s >> 6;
        int ri = g >> 2, c = (g >> 1) & 1, nt = g & 1;
        int sq = sl >> 4, sn = sl & 15;
        const float* src = ri ? ki : kr;
        long base = ((long)(b * Sk + kt * 32 + nt * 16 + sn)) * F + h * 64 + c * 32 + sq * 8;
        long outH = blkbase + ((((ri * 2 + 0) * 2 + c) * 2 + nt) * 64 + sl) * 8;
        long outL = blkbase + ((((ri * 2 + 1) * 2 + c) * 2 + nt) * 64 + sl) * 8;
#pragma unroll
        for (int j = 0; j < 8; j++) {
            float x = src[base + j];
            short xh = f2bf(x);
            pK[outH + j] = xh;
            pK[outL + j] = f2bf(x - bf2f(xh));
        }
    }
#pragma unroll
    for (int it = 0; it < 2; it++) {
        int s = t + 256 * it;
        int sl = s & 63, g = s >> 6;
        int ri = g >> 2, nt = g & 3;
        int sq = sl >> 4, sn = sl & 15;
        const float* src = ri ? vi : vr;
        long base = ((long)(b * Sk + kt * 32 + sq * 8)) * F + h * 64 + nt * 16 + sn;
        long outH = blkbase + (((ri * 2 + 0) * 4 + nt) * 64 + sl) * 8;
        long outL = blkbase + (((ri * 2 + 1) * 4 + nt) * 64 + sl) * 8;
#pragma unroll
        for (int j = 0; j < 8; j++) {
            float x = src[base + (long)j * F];
            short xh = f2bf(x);
            pV[outH + j] = xh;
            pV[outL + j] = f2bf(x - bf2f(xh));
        }
    }
}

// ------------------------------- MFMA flash complex attention (bf16x3 exact)
__global__ __launch_bounds__(256)
void cattn_mfma(const float* __restrict__ qr, const float* __restrict__ qi,
                const short* __restrict__ pK, const short* __restrict__ pV,
                float* __restrict__ mr, float* __restrict__ mi,
                int S, int Sk)
{
    __shared__ short sK[8192];  // [ri][hl][c][nt2][64][8]
    __shared__ short sV[8192];  // [ri][hl][nt4][64][8]
    __shared__ short sP[5120];  // [w][hl][16][40]
    const int F = FF;
    int qt = blockIdx.x, h = blockIdx.y, b = blockIdx.z;
    int t = threadIdx.x;
    int w = t >> 6, l = t & 63, q = l >> 4, n16 = l & 15;

    // ---- Q fragments in registers (A operand), x3 split
    bf16x8 qh_[2][2], ql_[2][2];
    {
        long qbase = ((long)(b * S + qt * 64 + w * 16 + n16)) * F + h * 64 + q * 8;
#pragma unroll
        for (int ri = 0; ri < 2; ri++) {
            const float* src = ri ? qi : qr;
#pragma unroll
            for (int c = 0; c < 2; c++) {
                float vv[8];
                *(float4*)&vv[0] = *(const float4*)&src[qbase + c * 32];
                *(float4*)&vv[4] = *(const float4*)&src[qbase + c * 32 + 4];
#pragma unroll
                for (int j = 0; j < 8; j++) {
                    short xh = f2bf(vv[j]);
                    qh_[ri][c][j] = xh;
                    ql_[ri][c][j] = f2bf(vv[j] - bf2f(xh));
                }
            }
        }
    }

    f32x4 zf = {0.f, 0.f, 0.f, 0.f};
    f32x4 oR[4], oI[4];
#pragma unroll
    for (int nt = 0; nt < 4; nt++) { oR[nt] = zf; oI[nt] = zf; }
    float m_run[4] = {-3.0e38f, -3.0e38f, -3.0e38f, -3.0e38f};
    float l_run[4] = {0.f, 0.f, 0.f, 0.f};

    int nkt = Sk >> 5;
    long pbh = (long)((b * 8 + h) * nkt) * 8192;
    for (int kt = 0; kt < nkt; kt++) {
        __syncthreads();
        long pb = pbh + (long)kt * 8192;
#pragma unroll
        for (int i = 0; i < 4; i++) {
            int bk = w * 4 + i;
            gload16(pK + pb + (bk << 9) + l * 8, &sK[bk << 9]);
            gload16(pV + pb + (bk << 9) + l * 8, &sV[bk << 9]);
        }
        __syncthreads();

        // ---- scores (x3: QhKh + QlKh + QhKl, r and i)
        f32x4 sc[2];
        sc[0] = zf; sc[1] = zf;
#pragma unroll
        for (int nt = 0; nt < 2; nt++) {
#pragma unroll
            for (int ri = 0; ri < 2; ri++) {
                bf16x8 kh0 = *(const bf16x8*)&sK[((((ri * 2 + 0) * 2 + 0) * 2 + nt) * 64 + l) * 8];
                bf16x8 kh1 = *(const bf16x8*)&sK[((((ri * 2 + 0) * 2 + 1) * 2 + nt) * 64 + l) * 8];
                bf16x8 kl0 = *(const bf16x8*)&sK[((((ri * 2 + 1) * 2 + 0) * 2 + nt) * 64 + l) * 8];
                bf16x8 kl1 = *(const bf16x8*)&sK[((((ri * 2 + 1) * 2 + 1) * 2 + nt) * 64 + l) * 8];
                sc[nt] = __builtin_amdgcn_mfma_f32_16x16x32_bf16(qh_[ri][0], kh0, sc[nt], 0, 0, 0);
                sc[nt] = __builtin_amdgcn_mfma_f32_16x16x32_bf16(qh_[ri][1], kh1, sc[nt], 0, 0, 0);
                sc[nt] = __builtin_amdgcn_mfma_f32_16x16x32_bf16(ql_[ri][0], kh0, sc[nt], 0, 0, 0);
                sc[nt] = __builtin_amdgcn_mfma_f32_16x16x32_bf16(ql_[ri][1], kh1, sc[nt], 0, 0, 0);
                sc[nt] = __builtin_amdgcn_mfma_f32_16x16x32_bf16(qh_[ri][0], kl0, sc[nt], 0, 0, 0);
                sc[nt] = __builtin_amdgcn_mfma_f32_16x16x32_bf16(qh_[ri][1], kl1, sc[nt], 0, 0, 0);
            }
        }
        // ---- online softmax
        float alpha[4];
#pragma unroll
        for (int v = 0; v < 4; v++) {
            float s0 = sc[0][v] * 0.125f, s1 = sc[1][v] * 0.125f;
            float mx = fmaxf(s0, s1);
            mx = fmaxf(mx, __shfl_xor(mx, 1));
            mx = fmaxf(mx, __shfl_xor(mx, 2));
            mx = fmaxf(mx, __shfl_xor(mx, 4));
            mx = fmaxf(mx, __shfl_xor(mx, 8));
            float mnew = fmaxf(m_run[v], mx);
            float p0 = __expf(s0 - mnew), p1 = __expf(s1 - mnew);
            sc[0][v] = p0; sc[1][v] = p1;
            float ps = p0 + p1;
            ps += __shfl_xor(ps, 1);
            ps += __shfl_xor(ps, 2);
            ps += __shfl_xor(ps, 4);
            ps += __shfl_xor(ps, 8);
            alpha[v] = __expf(m_run[v] - mnew);
            l_run[v] = l_run[v] * alpha[v] + ps;
            m_run[v] = mnew;
        }
#pragma unroll
        for (int nt = 0; nt < 4; nt++)
#pragma unroll
            for (int v = 0; v < 4; v++) { oR[nt][v] *= alpha[v]; oI[nt][v] *= alpha[v]; }
        // ---- P -> LDS (C layout -> A fragment layout), h/l split
        int pbase = w * 1280;
#pragma unroll
        for (int nt = 0; nt < 2; nt++)
#pragma unroll
            for (int v = 0; v < 4; v++) {
                float p = sc[nt][v];
                short ph = f2bf(p);
                short pl = f2bf(p - bf2f(ph));
                int idx = pbase + (q * 4 + v) * 40 + nt * 16 + n16;
                sP[idx] = ph;
                sP[idx + 640] = pl;
            }
        bf16x8 pH = *(const bf16x8*)&sP[pbase + n16 * 40 + q * 8];
        bf16x8 pL = *(const bf16x8*)&sP[pbase + 640 + n16 * 40 + q * 8];
        // ---- PV (x3: PhVh + PlVh + PhVl)
#pragma unroll
        for (int nt = 0; nt < 4; nt++) {
            bf16x8 vh = *(const bf16x8*)&sV[(((0 * 2 + 0) * 4 + nt) * 64 + l) * 8];
            bf16x8 vl = *(const bf16x8*)&sV[(((0 * 2 + 1) * 4 + nt) * 64 + l) * 8];
            oR[nt] = __builtin_amdgcn_mfma_f32_16x16x32_bf16(pH, vh, oR[nt], 0, 0, 0);
            oR[nt] = __builtin_amdgcn_mfma_f32_16x16x32_bf16(pL, vh, oR[nt], 0, 0, 0);
            oR[nt] = __builtin_amdgcn_mfma_f32_16x16x32_bf16(pH, vl, oR[nt], 0, 0, 0);
            bf16x8 wh = *(const bf16x8*)&sV[(((1 * 2 + 0) * 4 + nt) * 64 + l) * 8];
            bf16x8 wl2 = *(const bf16x8*)&sV[(((1 * 2 + 1) * 4 + nt) * 64 + l) * 8];
            oI[nt] = __builtin_amdgcn_mfma_f32_16x16x32_bf16(pH, wh, oI[nt], 0, 0, 0);
            oI[nt] = __builtin_amdgcn_mfma_f32_16x16x32_bf16(pL, wh, oI[nt], 0, 0, 0);
            oI[nt] = __builtin_amdgcn_mfma_f32_16x16x32_bf16(pH, wl2, oI[nt], 0, 0, 0);
        }
    }
#pragma unroll
    for (int v = 0; v < 4; v++) {
        float inv = 1.0f / l_run[v];
        long obase = ((long)(b * S + qt * 64 + w * 16 + q * 4 + v)) * F + h * 64 + n16;
#pragma unroll
        for (int nt = 0; nt < 4; nt++) {
            mr[obase + nt * 16] = oR[nt][v] * inv;
            mi[obase + nt * 16] = oI[nt][v] * inv;
        }
    }
}

// ----------------------------------------------------------------- routing
__global__ __launch_bounds__(256)
void route_kernel(const float* __restrict__ hr, const float* __restrict__ hi,
                  int* __restrict__ eidx)
{
    const int F = FF;
    long base = (long)blockIdx.x * F;
    int t = threadIdx.x;
    double ss = 0.0, cc = 0.0;
#pragma unroll
    for (int u = 0; u < 2; u++) {
        int j = t + u * 256;
        float ph = atan2f(hi[base + j], hr[base + j]);
        ss += (double)sinf(ph);
        cc += (double)cosf(ph);
    }
#pragma unroll
    for (int off = 32; off >= 1; off >>= 1) {
        ss += __shfl_xor(ss, off);
        cc += __shfl_xor(cc, off);
    }
    __shared__ double wss[4], wcc[4];
    if ((t & 63) == 0) { wss[t >> 6] = ss; wcc[t >> 6] = cc; }
    __syncthreads();
    if (t == 0) {
        float msin = (float)((wss[0] + wss[1] + wss[2] + wss[3]) * (1.0 / 512.0));
        float mcos = (float)((wcc[0] + wcc[1] + wcc[2] + wcc[3]) * (1.0 / 512.0));
        float tp = atan2f(msin, mcos);
        float a = (tp + 3.14159274101257324f) / 6.28318548202514648f * 8.0f;
        int k = (int)floorf(a);
        k = min(max(k, 0), NEXP - 1);
        eidx[blockIdx.x] = k;
    }
}

__global__ __launch_bounds__(256)
void moe_build_kernel(const int* __restrict__ eidx, int* __restrict__ order,
                      int* __restrict__ tileExpert)
{
    __shared__ int cnt[NEXP], segbase[NEXP], cursor[NEXP], tbase[NEXP];
    int t = threadIdx.x;
    if (t < NEXP) { cnt[t] = 0; cursor[t] = 0; }
    __syncthreads();
    for (int i = t; i < NTOK; i += 256) atomicAdd(&cnt[eidx[i]], 1);
    __syncthreads();
    if (t == 0) {
        int ob = 0, tb = 0;
        for (int e = 0; e < NEXP; e++) {
            segbase[e] = ob; tbase[e] = tb;
            int tiles = (cnt[e] + 63) >> 6;
            ob += tiles << 6; tb += tiles;
        }
    }
    __syncthreads();
    for (int i = t; i < NPAD; i += 256) order[i] = -1;
    if (t < TMAX) {
        int ex = -1;
        for (int e = 0; e < NEXP; e++) {
            int tiles = (cnt[e] + 63) >> 6;
            if (t >= tbase[e] && t < tbase[e] + tiles) ex = e;
        }
        tileExpert[t] = ex;
    }
    __syncthreads();
    for (int i = t; i < NTOK; i += 256) {
        int e = eidx[i];
        int pos = atomicAdd(&cursor[e], 1);
        order[segbase[e] + pos] = i;
    }
}

__global__ __launch_bounds__(256)
void combine_kernel(const int* __restrict__ order,
                    const float* __restrict__ xr, const float* __restrict__ xi,
                    const float* __restrict__ yr, const float* __restrict__ yi,
                    float* __restrict__ out)
{
    const int F = FF;
    int p = blockIdx.x;
    int tok = order[p];
    if (tok < 0) return;
    int t = threadIdx.x;
    float* outr = out;
    float* outi = out + (long)NTOK * FF;
#pragma unroll
    for (int u = 0; u < 2; u++) {
        int j = t + u * 256;
        long src = (long)p * F + j;
        long dst = (long)tok * F + j;
        outr[dst] = xr[dst] + yr[src];
        outi[dst] = xi[dst] + yi[src];
    }
}

// ------------------------------------------------------------------- launch
extern "C" void kernel_launch(void* const* d_in, const int* in_sizes, int n_in,
                              void* d_out, int out_size, void* d_ws, size_t ws_size,
                              hipStream_t stream)
{
    (void)in_sizes; (void)n_in; (void)out_size; (void)ws_size;
    const float* x_r   = (const float*)d_in[0];
    const float* x_i   = (const float*)d_in[1];
    const float* ctx_r = (const float*)d_in[2];
    const float* ctx_i = (const float*)d_in[3];
    const float* ln1_g = (const float*)d_in[4];
    const float* ln2_g = (const float*)d_in[5];
    const float* ln3_g = (const float*)d_in[6];
    const float* sa_qWr = (const float*)d_in[7];   const float* sa_qWi = (const float*)d_in[8];
    const float* sa_qbr = (const float*)d_in[9];   const float* sa_qbi = (const float*)d_in[10];
    const float* sa_kWr = (const float*)d_in[11];  const float* sa_kWi = (const float*)d_in[12];
    const float* sa_kbr = (const float*)d_in[13];  const float* sa_kbi = (const float*)d_in[14];
    const float* sa_vWr = (const float*)d_in[15];  const float* sa_vWi = (const float*)d_in[16];
    const float* sa_vbr = (const float*)d_in[17];  const float* sa_vbi = (const float*)d_in[18];
    const float* sa_oWr = (const float*)d_in[19];  const float* sa_oWi = (const float*)d_in[20];
    const float* sa_obr = (const float*)d_in[21];  const float* sa_obi = (const float*)d_in[22];
    const float* ca_qWr = (const float*)d_in[23];  const float* ca_qWi = (const float*)d_in[24];
    const float* ca_qbr = (const float*)d_in[25];  const float* ca_qbi = (const float*)d_in[26];
    const float* ca_kWr = (const float*)d_in[27];  const float* ca_kWi = (const float*)d_in[28];
    const float* ca_kbr = (const float*)d_in[29];  const float* ca_kbi = (const float*)d_in[30];
    const float* ca_vWr = (const float*)d_in[31];  const float* ca_vWi = (const float*)d_in[32];
    const float* ca_vbr = (const float*)d_in[33];  const float* ca_vbi = (const float*)d_in[34];
    const float* ca_oWr = (const float*)d_in[35];  const float* ca_oWi = (const float*)d_in[36];
    const float* ca_obr = (const float*)d_in[37];  const float* ca_obi = (const float*)d_in[38];
    const float* moe_W1r = (const float*)d_in[39]; const float* moe_W1i = (const float*)d_in[40];
    const float* moe_b1r = (const float*)d_in[41]; const float* moe_b1i = (const float*)d_in[42];
    const float* moe_mb  = (const float*)d_in[43];
    const float* moe_W2r = (const float*)d_in[44]; const float* moe_W2i = (const float*)d_in[45];
    const float* moe_b2r = (const float*)d_in[46]; const float* moe_b2i = (const float*)d_in[47];
    float* out = (float*)d_out;

    char* W = (char*)d_ws;
    const long NF = (long)NTOK * FF;          // 2,097,152 elements
    float* xr = (float*)(W + 0 * NF * 4);
    float* xi = (float*)(W + 1 * NF * 4);
    float* hr = (float*)(W + 2 * NF * 4);
    float* hi = (float*)(W + 3 * NF * 4);
    char* poolB = W + 4 * NF * 4;             // 64 MB pool
    float* qr = (float*)poolB;                float* qi = (float*)(poolB + NF * 4);
    float* kr = (float*)(poolB + 2 * NF * 4); float* ki = (float*)(poolB + 3 * NF * 4);
    float* vr = (float*)(poolB + 4 * NF * 4); float* vi = (float*)(poolB + 5 * NF * 4);
    float* mr = (float*)(poolB + 6 * NF * 4); float* mi = (float*)(poolB + 7 * NF * 4);
    bf16* u_r = (bf16*)poolB;                                   // MoE overlay
    bf16* u_i = (bf16*)(poolB + 18874368);
    float* y_r = (float*)(poolB + 37748736);
    float* y_i = (float*)(poolB + 37748736 + 9437184);
    bf16* h3r = (bf16*)(poolB + 56623104);
    bf16* h3i = (bf16*)(poolB + 56623104 + 4194304);
    // region Q
    char* Q = W + 12 * NF * 4;
    bf16* A1r = (bf16*)Q;                        // 4096x1024 = 8 MB
    bf16* A1i = (bf16*)(Q + 8388608);
    bf16* A2r = (bf16*)(Q + 16777216);           // 1024x1536 = 3 MB
    bf16* A2i = (bf16*)(Q + 19922944);
    char* WQ = Q + 23068672;
    const long PS1 = 524288;                      // 1024x512 elements
    const long PS2 = 786432;                      // 1536x512 elements
    bf16* saq_r = (bf16*)(WQ);                   bf16* saq_i = saq_r + PS1;
    bf16* sak_r = saq_r + 2 * PS1;               bf16* sak_i = saq_r + 3 * PS1;
    bf16* sav_r = saq_r + 4 * PS1;               bf16* sav_i = saq_r + 5 * PS1;
    bf16* sao_r = saq_r + 6 * PS1;               bf16* sao_i = saq_r + 7 * PS1;
    bf16* caq_r = saq_r + 8 * PS1;               bf16* caq_i = saq_r + 9 * PS1;
    bf16* cao_r = saq_r + 10 * PS1;              bf16* cao_i = saq_r + 11 * PS1;
    bf16* cak_r = saq_r + 12 * PS1;              bf16* cak_i = cak_r + PS2;
    bf16* cav_r = cak_r + 2 * PS2;               bf16* cav_i = cak_r + 3 * PS2;
    // KV fragment packs (overlay dead regions)
    short* pKbuf = (short*)hr;                    // hr+hi = 16 MB, exact for self
    short* pVbuf = (short*)Q;                     // A1 region, 16 MB
    // MoE weight overlay (A1/A2/W-pack region, dead by MoE time)
    bf16* Wm_r = (bf16*)Q;
    bf16* Wm_i = (bf16*)(Q + 16777216);
    int* eidx       = (int*)(W + 12 * NF * 4 + 62914560);
    int* order      = eidx + NTOK;
    int* tileExpert = order + NPAD;

    dim3 blk(256);
    const long W1S = (long)FF * HID;
    const long CZ = 2 * NF * 4;                   // bytes between fused outputs
    Ptr6 bQKV = {{sa_qbr, sa_qbi, sa_kbr, sa_kbi, sa_vbr, sa_vbi}};
    Ptr6 bSAO = {{sa_obr, sa_obi, 0, 0, 0, 0}};
    Ptr6 bCAQ = {{ca_qbr, ca_qbi, 0, 0, 0, 0}};
    Ptr6 bCKV = {{ca_kbr, ca_kbi, ca_vbr, ca_vbi, 0, 0}};
    Ptr6 bCAO = {{ca_obr, ca_obi, 0, 0, 0, 0}};
    Ptr6 bM1  = {{moe_b1r, moe_b1i, 0, 0, 0, 0}};
    Ptr6 bM2  = {{moe_b2r, moe_b2i, 0, 0, 0, 0}};

    // ---- weight packs (phys [Wh;Wl])
    expandW_x2_packed<<<dim3(8, 32), blk, 0, stream>>>(sa_qWr, sa_qWi, saq_r, saq_i, FF, 16);
    expandW_x2_packed<<<dim3(8, 32), blk, 0, stream>>>(sa_kWr, sa_kWi, sak_r, sak_i, FF, 16);
    expandW_x2_packed<<<dim3(8, 32), blk, 0, stream>>>(sa_vWr, sa_vWi, sav_r, sav_i, FF, 16);
    expandW_x2_packed<<<dim3(8, 32), blk, 0, stream>>>(sa_oWr, sa_oWi, sao_r, sao_i, FF, 16);
    expandW_x2_packed<<<dim3(8, 32), blk, 0, stream>>>(ca_qWr, ca_qWi, caq_r, caq_i, FF, 16);
    expandW_x2_packed<<<dim3(8, 32), blk, 0, stream>>>(ca_oWr, ca_oWi, cao_r, cao_i, FF, 16);
    expandW_x2_packed<<<dim3(8, 48), blk, 0, stream>>>(ca_kWr, ca_kWi, cak_r, cak_i, FF, 24);
    expandW_x2_packed<<<dim3(8, 48), blk, 0, stream>>>(ca_vWr, ca_vWi, cav_r, cav_i, FF, 24);

    // ---- self-attention block
    cln_kernel<<<NTOK, blk, 0, stream>>>(x_r, x_i, ln1_g, hr, hi);
    expandA_x2<<<dim3(2, NTOK), blk, 0, stream>>>(hr, hi, A1r, A1i, FF);
    cgemm_mfma<true,false,false,false,false,false><<<dim3(64, 8, 3), blk, 0, stream>>>(
        A1r, A1i, 1024, 512, saq_r, saq_i, 2 * PS1, 0, 32, 16,
        bQKV, 0, nullptr, nullptr, nullptr, qr, qi, CZ, FF, 1536, nullptr, nullptr);
    pack_kv<<<dim3(32, 8, 4), blk, 0, stream>>>(kr, ki, vr, vi, pKbuf, pVbuf, 1024);
    cattn_mfma<<<dim3(16, 8, 4), blk, 0, stream>>>(qr, qi, pKbuf, pVbuf, mr, mi, 1024, 1024);
    expandA_x2<<<dim3(2, NTOK), blk, 0, stream>>>(mr, mi, A1r, A1i, FF);
    cgemm_mfma<true,false,false,false,true,false><<<dim3(64, 8, 1), blk, 0, stream>>>(
        A1r, A1i, 1024, 512, sao_r, sao_i, 0, 0, 32, 16,
        bSAO, 0, nullptr, x_r, x_i, xr, xi, 0, FF, 1536, nullptr, nullptr);

    // ---- cross-attention block
    cln_kernel<<<NTOK, blk, 0, stream>>>(xr, xi, ln2_g, hr, hi);
    expandA_x2<<<dim3(2, NTOK), blk, 0, stream>>>(hr, hi, A1r, A1i, FF);
    cgemm_mfma<true,false,false,false,false,false><<<dim3(64, 8, 1), blk, 0, stream>>>(
        A1r, A1i, 1024, 512, caq_r, caq_i, 0, 0, 32, 16,
        bCAQ, 0, nullptr, nullptr, nullptr, qr, qi, 0, FF, 1536, nullptr, nullptr);
    expandA_x2<<<dim3(3, 1024), blk, 0, stream>>>(ctx_r, ctx_i, A2r, A2i, CDIM);
    cgemm_mfma<true,false,false,false,false,false><<<dim3(16, 8, 2), blk, 0, stream>>>(
        A2r, A2i, 1536, 768, cak_r, cak_i, 2 * PS2, 0, 32, 24,
        bCKV, 0, nullptr, nullptr, nullptr, kr, ki, CZ, FF, 2304, nullptr, nullptr);
    pack_kv<<<dim3(8, 8, 4), blk, 0, stream>>>(kr, ki, vr, vi, pKbuf, pVbuf, 256);
    cattn_mfma<<<dim3(16, 8, 4), blk, 0, stream>>>(qr, qi, pKbuf, pVbuf, mr, mi, 1024, 256);
    expandA_x2<<<dim3(2, NTOK), blk, 0, stream>>>(mr, mi, A1r, A1i, FF);
    cgemm_mfma<true,false,false,false,true,false><<<dim3(64, 8, 1), blk, 0, stream>>>(
        A1r, A1i, 1024, 512, cao_r, cao_i, 0, 0, 32, 16,
        bCAO, 0, nullptr, xr, xi, xr, xi, 0, FF, 1536, nullptr, nullptr);

    // ---- phase-routed MoE
    cln_kernel<<<NTOK, blk, 0, stream>>>(xr, xi, ln3_g, hr, hi);
    route_kernel<<<NTOK, blk, 0, stream>>>(hr, hi, eidx);
    moe_build_kernel<<<1, blk, 0, stream>>>(eidx, order, tileExpert);
    convA_plain<<<dim3(2, NTOK), blk, 0, stream>>>(hr, hi, h3r, h3i, FF);
    convW_packed<<<dim3(32, 16, 8), blk, 0, stream>>>(moe_W1r, moe_W1i, Wm_r, Wm_i, HID, W1S);
    cgemm_mfma<false,true,true,true,false,true><<<dim3(TMAX, 32, 1), blk, 0, stream>>>(
        h3r, h3i, 512, 512, Wm_r, Wm_i, 0, W1S, 128, 0,
        bM1, HID, moe_mb, nullptr, nullptr, u_r, u_i, 0, HID, 512, order, tileExpert);
    convW_packed<<<dim3(8, 64, 8), blk, 0, stream>>>(moe_W2r, moe_W2i, Wm_r, Wm_i, FF, W1S);
    cgemm_mfma<false,true,false,false,false,false><<<dim3(TMAX, 8, 1), blk, 0, stream>>>(
        u_r, u_i, 2048, 2048, Wm_r, Wm_i, 0, W1S, 32, 0,
        bM2, FF, nullptr, nullptr, nullptr, y_r, y_i, 0, FF, 2048, nullptr, tileExpert);
    combine_kernel<<<NPAD, blk, 0, stream>>>(order, xr, xi, y_r, y_i, out);
}

// Round 6
// 866.536 us; speedup vs baseline: 8.3924x; 1.0323x over previous
//
#include <hip/hip_runtime.h>
#include <hip/hip_bf16.h>
#include <math.h>

// ComplexTransformerBlock: B=4 S=1024 L=256 F=512 CD=768 NH=8 (d=64) E=8 HID=2048
// Round 6: round-5 structure (128x128 MFMA tiles for QKV+MoE-L1, fused LN/expand/
// route, cattn writes A1 [Ah|Al] directly, single W-pack dispatch) with the
// cattn epilogue bug fixed: short(bf16 bits) was implicitly NUMERICALLY converted
// to __hip_bfloat16; now uses __float2bfloat16 value conversion.

#define NTOK 4096
#define FF   512
#define CDIM 768
#define NEXP 8
#define HID  2048
#define TMAX128 40
#define NPAD128 (TMAX128 * 128)   // 5120

typedef __hip_bfloat16 bf16;
typedef short bf16x8 __attribute__((ext_vector_type(8)));
typedef float f32x4  __attribute__((ext_vector_type(4)));

struct Ptr6 { const float* p[6]; };
struct WPackAll {
    const float* sR[8]; const float* sI[8];
    bf16* dR[8]; bf16* dI[8];
    int kdiv[8];
};

__device__ __forceinline__ short f2bf(float x) {          // raw bf16 bits (for short* bufs)
    unsigned u = __float_as_uint(x);
    unsigned r = (u + 0x7fff + ((u >> 16) & 1)) >> 16;
    return (short)r;
}
__device__ __forceinline__ float bf2f(short s) {
    return __uint_as_float(((unsigned)(unsigned short)s) << 16);
}
__device__ __forceinline__ void gload16(const void* g, void* l) {
    __builtin_amdgcn_global_load_lds(
        (const __attribute__((address_space(1))) unsigned int*)g,
        (__attribute__((address_space(3))) unsigned int*)l, 16, 0, 0);
}

// --------------------------- fused complex LN -> A1 [Ah|Al] (M x 1024 bf16)
__global__ __launch_bounds__(256)
void cln_expand(const float* __restrict__ xr, const float* __restrict__ xi,
                const float* __restrict__ g,
                bf16* __restrict__ dR, bf16* __restrict__ dI)
{
    long base = (long)blockIdx.x * FF;
    int t = threadIdx.x;
    int j0 = t, j1 = t + 256;
    float xr0 = xr[base + j0], xi0 = xi[base + j0];
    float xr1 = xr[base + j1], xi1 = xi[base + j1];
    float a0 = sqrtf(xr0 * xr0 + xi0 * xi0 + 1e-6f);
    float a1 = sqrtf(xr1 * xr1 + xi1 * xi1 + 1e-6f);
    float s = a0 + a1;
#pragma unroll
    for (int off = 32; off >= 1; off >>= 1) s += __shfl_xor(s, off);
    __shared__ float wsum[4];
    if ((t & 63) == 0) wsum[t >> 6] = s;
    __syncthreads();
    float mean = (wsum[0] + wsum[1] + wsum[2] + wsum[3]) * (1.0f / 512.0f);
    float d0 = g[j0] * (a0 / (mean + 1e-6f)) / (a0 + 1e-6f);
    float d1 = g[j1] * (a1 / (mean + 1e-6f)) / (a1 + 1e-6f);
    long d = (long)blockIdx.x * 1024;
    float h; bf16 hh;
    h = xr0 * d0; hh = __float2bfloat16(h);
    dR[d + j0] = hh; dR[d + 512 + j0] = __float2bfloat16(h - __bfloat162float(hh));
    h = xi0 * d0; hh = __float2bfloat16(h);
    dI[d + j0] = hh; dI[d + 512 + j0] = __float2bfloat16(h - __bfloat162float(hh));
    h = xr1 * d1; hh = __float2bfloat16(h);
    dR[d + j1] = hh; dR[d + 512 + j1] = __float2bfloat16(h - __bfloat162float(hh));
    h = xi1 * d1; hh = __float2bfloat16(h);
    dI[d + j1] = hh; dI[d + 512 + j1] = __float2bfloat16(h - __bfloat162float(hh));
}

// --------------------- fused complex LN -> h3 (bf16) + phase routing (eidx)
__global__ __launch_bounds__(256)
void cln_route(const float* __restrict__ xr, const float* __restrict__ xi,
               const float* __restrict__ g,
               bf16* __restrict__ h3r, bf16* __restrict__ h3i,
               int* __restrict__ eidx)
{
    long base = (long)blockIdx.x * FF;
    int t = threadIdx.x;
    int j0 = t, j1 = t + 256;
    float xr0 = xr[base + j0], xi0 = xi[base + j0];
    float xr1 = xr[base + j1], xi1 = xi[base + j1];
    float a0 = sqrtf(xr0 * xr0 + xi0 * xi0 + 1e-6f);
    float a1 = sqrtf(xr1 * xr1 + xi1 * xi1 + 1e-6f);
    float s = a0 + a1;
#pragma unroll
    for (int off = 32; off >= 1; off >>= 1) s += __shfl_xor(s, off);
    __shared__ float wsum[4];
    __shared__ double wss[4], wcc[4];
    if ((t & 63) == 0) wsum[t >> 6] = s;
    __syncthreads();
    float mean = (wsum[0] + wsum[1] + wsum[2] + wsum[3]) * (1.0f / 512.0f);
    float d0 = g[j0] * (a0 / (mean + 1e-6f)) / (a0 + 1e-6f);
    float d1 = g[j1] * (a1 / (mean + 1e-6f)) / (a1 + 1e-6f);
    float h0r = xr0 * d0, h0i = xi0 * d0;
    float h1r = xr1 * d1, h1i = xi1 * d1;
    h3r[base + j0] = __float2bfloat16(h0r);
    h3i[base + j0] = __float2bfloat16(h0i);
    h3r[base + j1] = __float2bfloat16(h1r);
    h3i[base + j1] = __float2bfloat16(h1i);
    float ph0 = atan2f(h0i, h0r), ph1 = atan2f(h1i, h1r);
    double ss = (double)sinf(ph0) + (double)sinf(ph1);
    double cc = (double)cosf(ph0) + (double)cosf(ph1);
#pragma unroll
    for (int off = 32; off >= 1; off >>= 1) {
        ss += __shfl_xor(ss, off);
        cc += __shfl_xor(cc, off);
    }
    if ((t & 63) == 0) { wss[t >> 6] = ss; wcc[t >> 6] = cc; }
    __syncthreads();
    if (t == 0) {
        float msin = (float)((wss[0] + wss[1] + wss[2] + wss[3]) * (1.0 / 512.0));
        float mcos = (float)((wcc[0] + wcc[1] + wcc[2] + wcc[3]) * (1.0 / 512.0));
        float tp = atan2f(msin, mcos);
        float a = (tp + 3.14159274101257324f) / 6.28318548202514648f * 8.0f;
        int k = (int)floorf(a);
        k = min(max(k, 0), NEXP - 1);
        eidx[blockIdx.x] = k;
    }
}

// ------------------------------------------------- fp32 -> [Ah|Al] (ctx only)
__global__ __launch_bounds__(256)
void expandA_x2(const float* __restrict__ sR, const float* __restrict__ sI,
                bf16* __restrict__ dR, bf16* __restrict__ dI, int K)
{
    int k = blockIdx.x * 256 + threadIdx.x;
    int m = blockIdx.y;
    long s = (long)m * K + k;
    long d = (long)m * 2 * K + k;
    float a = sR[s];
    bf16 ah = __float2bfloat16(a);
    dR[d] = ah; dR[d + K] = __float2bfloat16(a - __bfloat162float(ah));
    float b = sI[s];
    bf16 bh = __float2bfloat16(b);
    dI[d] = bh; dI[d + K] = __float2bfloat16(b - __bfloat162float(bh));
}

// --------------------------- all 8 attention W packs in one dispatch (x2 phys)
__global__ __launch_bounds__(256)
void expandW_all(WPackAll p)
{
    int z = blockIdx.z;
    int kdiv = p.kdiv[z];
    int kc = blockIdx.y;
    if (kc >= 2 * kdiv) return;
    const int N = FF;
    int g = blockIdx.x * 256 + threadIdx.x;
    int nt = g >> 6, l = g & 63;
    int lo = (kc >= kdiv);
    int kb = (kc - (lo ? kdiv : 0)) * 32 + (l >> 4) * 8;
    int n  = nt * 16 + (l & 15);
    long dbase = ((long)kc * (N >> 4) + nt) * 512 + l * 8;
    const float* sR = p.sR[z]; const float* sI = p.sI[z];
    bf16* dR = p.dR[z]; bf16* dI = p.dI[z];
#pragma unroll
    for (int j = 0; j < 8; j++) {
        float a = sR[(long)(kb + j) * N + n];
        bf16 ah = __float2bfloat16(a);
        dR[dbase + j] = lo ? __float2bfloat16(a - __bfloat162float(ah)) : ah;
        float b = sI[(long)(kb + j) * N + n];
        bf16 bh = __float2bfloat16(b);
        dI[dbase + j] = lo ? __float2bfloat16(b - __bfloat162float(bh)) : bh;
    }
}

// W -> packed plain bf16, expert-strided (MoE weights)
__global__ __launch_bounds__(256)
void convW_packed(const float* __restrict__ sR, const float* __restrict__ sI,
                  bf16* __restrict__ dR, bf16* __restrict__ dI,
                  int N, long estride)
{
    int g = blockIdx.x * 256 + threadIdx.x;
    int nt = g >> 6, l = g & 63;
    int kc = blockIdx.y;
    int e  = blockIdx.z;
    const float* srcR = sR + (long)e * estride;
    const float* srcI = sI + (long)e * estride;
    bf16* dstR = dR + (long)e * estride;
    bf16* dstI = dI + (long)e * estride;
    int kb = kc * 32 + (l >> 4) * 8;
    int n  = nt * 16 + (l & 15);
    long dbase = ((long)kc * (N >> 4) + nt) * 512 + l * 8;
#pragma unroll
    for (int j = 0; j < 8; j++) {
        dstR[dbase + j] = __float2bfloat16(srcR[(long)(kb + j) * N + n]);
        dstI[dbase + j] = __float2bfloat16(srcI[(long)(kb + j) * N + n]);
    }
}

// ---------------------------------------------- complex MFMA GEMM 128x128
// 4 waves in 2x2; each wave 64x64 quadrant = 4x4 16x16 subtiles (x r,i).
// 64 KB LDS, BK=64. 4 MFMA per ds_read_b128.
template<bool X3, bool EXPERT, bool GATHER, bool MODRELU, bool OUTBF16>
__global__ __launch_bounds__(256, 2)
void cgemm128(const bf16* __restrict__ Ar, const bf16* __restrict__ Ai,
              int lda, int Kreal,
              const bf16* __restrict__ Wr0, const bf16* __restrict__ Wi0,
              long wz, long westride, int ntTot, int kdiv,
              Ptr6 bias, int bstride, const float* __restrict__ mb,
              void* __restrict__ Cr0, void* __restrict__ Ci0, long cz,
              int ldc, int Kp,
              const int* __restrict__ order, const int* __restrict__ tileExpert)
{
    __shared__ short sA[16384];   // 32 KB: [(ri*2+kc)*8 + mt][lane64][8]
    __shared__ short sW[16384];   // 32 KB: [(ri*2+kc)*8 + nt][lane64][8]
    int tm = blockIdx.x, tn = blockIdx.y, z = blockIdx.z;
    const bf16* Wr = Wr0 + (long)z * wz;
    const bf16* Wi = Wi0 + (long)z * wz;
    const float* br = bias.p[2 * z];
    const float* bi = bias.p[2 * z + 1];
    void* Crv = (char*)Cr0 + (long)z * cz;
    void* Civ = (char*)Ci0 + (long)z * cz;
    if (EXPERT) {
        int e = tileExpert[tm];
        if (e < 0) return;
        Wr += (long)e * westride;  Wi += (long)e * westride;
        br += (long)e * bstride;   bi += (long)e * bstride;
        if (MODRELU) mb += (long)e * bstride;
    }
    int t = threadIdx.x;
    int l = t & 63, w = t >> 6;
    int riS = w >> 1, kcS = w & 1;
    const bf16* Asrc = riS ? Ai : Ar;
    const bf16* Wsrc = riS ? Wi : Wr;
    int kq8 = (l >> 4) * 8;
    long arb[8];
#pragma unroll
    for (int mt = 0; mt < 8; mt++) {
        int grow = tm * 128 + mt * 16 + (l & 15);
        int tok = grow;
        if (GATHER) { int gg = order[grow]; tok = (gg < 0) ? 0 : gg; }
        arb[mt] = (long)tok * lda;
    }
    int wm = w & 1, wn = w >> 1;

    f32x4 zf = {0.f, 0.f, 0.f, 0.f};
    f32x4 accR[4][4], accI[4][4];
#pragma unroll
    for (int a = 0; a < 4; a++)
#pragma unroll
        for (int b = 0; b < 4; b++) { accR[a][b] = zf; accI[a][b] = zf; }

    const bf16x8 sgn = {(short)0x8000,(short)0x8000,(short)0x8000,(short)0x8000,
                        (short)0x8000,(short)0x8000,(short)0x8000,(short)0x8000};

    for (int k0 = 0; k0 < Kp; k0 += 64) {
        __syncthreads();
        int lc = k0 + kcS * 32;
        int acol = (X3 && lc >= 2 * Kreal) ? lc - 2 * Kreal : lc;
#pragma unroll
        for (int mt = 0; mt < 8; mt++)
            gload16(Asrc + arb[mt] + acol + kq8,
                    &sA[(((riS * 2 + kcS) * 8 + mt) << 9)]);
        int kcl = (k0 >> 5) + kcS;
        int pkc = (X3 && kcl >= kdiv) ? kcl - kdiv : kcl;
        const bf16* wb = Wsrc + (((long)pkc * ntTot + tn * 8) << 9) + l * 8;
#pragma unroll
        for (int ntl = 0; ntl < 8; ntl++)
            gload16(wb + (ntl << 9),
                    &sW[(((riS * 2 + kcS) * 8 + ntl) << 9)]);
        __syncthreads();
#pragma unroll
        for (int kc = 0; kc < 2; kc++) {
            bf16x8 wrf[4], wif[4];
#pragma unroll
            for (int sn = 0; sn < 4; sn++) {
                wrf[sn] = *(const bf16x8*)&sW[(((kc * 8) + wn * 4 + sn) << 9) + l * 8];
                wif[sn] = *(const bf16x8*)&sW[((((2 + kc) * 8) + wn * 4 + sn) << 9) + l * 8];
            }
#pragma unroll
            for (int sm = 0; sm < 4; sm++) {
                bf16x8 ar = *(const bf16x8*)&sA[(((kc * 8) + wm * 4 + sm) << 9) + l * 8];
                bf16x8 ai = *(const bf16x8*)&sA[((((2 + kc) * 8) + wm * 4 + sm) << 9) + l * 8];
                bf16x8 na = ai ^ sgn;
#pragma unroll
                for (int sn = 0; sn < 4; sn++) {
                    accR[sm][sn] = __builtin_amdgcn_mfma_f32_16x16x32_bf16(ar, wrf[sn], accR[sm][sn], 0, 0, 0);
                    accR[sm][sn] = __builtin_amdgcn_mfma_f32_16x16x32_bf16(na, wif[sn], accR[sm][sn], 0, 0, 0);
                    accI[sm][sn] = __builtin_amdgcn_mfma_f32_16x16x32_bf16(ar, wif[sn], accI[sm][sn], 0, 0, 0);
                    accI[sm][sn] = __builtin_amdgcn_mfma_f32_16x16x32_bf16(ai, wrf[sn], accI[sm][sn], 0, 0, 0);
                }
            }
        }
    }
#pragma unroll
    for (int sm = 0; sm < 4; sm++)
#pragma unroll
        for (int sn = 0; sn < 4; sn++) {
            int row0 = tm * 128 + wm * 64 + sm * 16 + (l >> 4) * 4;
            int col  = tn * 128 + wn * 64 + sn * 16 + (l & 15);
            float bre = br[col], bie = bi[col];
            float mbe = MODRELU ? mb[col] : 0.f;
#pragma unroll
            for (int v = 0; v < 4; v++) {
                int row = row0 + v;
                float vr = accR[sm][sn][v] + bre;
                float vi = accI[sm][sn][v] + bie;
                if (MODRELU) {
                    float amp = sqrtf(vr * vr + vi * vi + 1e-10f);
                    float sc = fmaxf(amp + mbe, 0.f) / (amp + 1e-10f);
                    vr *= sc; vi *= sc;
                }
                long cidx = (long)row * ldc + col;
                if (OUTBF16) {
                    ((bf16*)Crv)[cidx] = __float2bfloat16(vr);
                    ((bf16*)Civ)[cidx] = __float2bfloat16(vi);
                } else {
                    ((float*)Crv)[cidx] = vr;
                    ((float*)Civ)[cidx] = vi;
                }
            }
        }
}

// -------------------------------------------------- complex MFMA GEMM 64x64
template<bool X3, bool EXPERT, bool GATHER, bool MODRELU, bool RESID, bool OUTBF16>
__global__ __launch_bounds__(256)
void cgemm_mfma(const bf16* __restrict__ Ar, const bf16* __restrict__ Ai,
                int lda, int Kreal,
                const bf16* __restrict__ Wr0, const bf16* __restrict__ Wi0,
                long wz, long westride, int ntTot, int kdiv,
                Ptr6 bias, int bstride, const float* __restrict__ mb,
                const float* __restrict__ Rr, const float* __restrict__ Ri,
                void* __restrict__ Cr0, void* __restrict__ Ci0, long cz,
                int ldc, int Kp,
                const int* __restrict__ order, const int* __restrict__ tileExpert)
{
    __shared__ short sA[8192];
    __shared__ short sW[8192];
    int tm = blockIdx.x, tn = blockIdx.y, z = blockIdx.z;
    const bf16* Wr = Wr0 + (long)z * wz;
    const bf16* Wi = Wi0 + (long)z * wz;
    const float* br = bias.p[2 * z];
    const float* bi = bias.p[2 * z + 1];
    void* Crv = (char*)Cr0 + (long)z * cz;
    void* Civ = (char*)Ci0 + (long)z * cz;
    if (EXPERT) {
        int e = tileExpert[tm];
        if (e < 0) return;
        Wr += (long)e * westride;  Wi += (long)e * westride;
        br += (long)e * bstride;   bi += (long)e * bstride;
        if (MODRELU) mb += (long)e * bstride;
    }
    int t = threadIdx.x;
    int l = t & 63, jj = t >> 6;
    int riS = jj >> 1, kcS = jj & 1;
    const bf16* Asrc = riS ? Ai : Ar;
    const bf16* Wsrc = riS ? Wi : Wr;
    int kq8 = (l >> 4) * 8;
    long arb[4];
#pragma unroll
    for (int mt = 0; mt < 4; mt++) {
        int grow = tm * 64 + mt * 16 + (l & 15);
        int tok = grow;
        if (GATHER) { int gg = order[grow]; tok = (gg < 0) ? 0 : gg; }
        arb[mt] = (long)tok * lda;
    }
    int wm = jj & 1, wn = jj >> 1;

    f32x4 zf = {0.f, 0.f, 0.f, 0.f};
    f32x4 accR[2][2], accI[2][2];
#pragma unroll
    for (int a = 0; a < 2; a++)
#pragma unroll
        for (int b = 0; b < 2; b++) { accR[a][b] = zf; accI[a][b] = zf; }

    const bf16x8 sgn = {(short)0x8000,(short)0x8000,(short)0x8000,(short)0x8000,
                        (short)0x8000,(short)0x8000,(short)0x8000,(short)0x8000};

    for (int k0 = 0; k0 < Kp; k0 += 64) {
        __syncthreads();
        int lc = k0 + kcS * 32;
        int acol = (X3 && lc >= 2 * Kreal) ? lc - 2 * Kreal : lc;
#pragma unroll
        for (int mt = 0; mt < 4; mt++)
            gload16(Asrc + arb[mt] + acol + kq8,
                    &sA[(((riS * 2 + kcS) << 2) + mt) << 9]);
        int kcl = (k0 >> 5) + kcS;
        int pkc = (X3 && kcl >= kdiv) ? kcl - kdiv : kcl;
        const bf16* wbase = Wsrc + (((long)pkc * ntTot + tn * 4) << 9) + l * 8;
#pragma unroll
        for (int ntl = 0; ntl < 4; ntl++)
            gload16(wbase + (ntl << 9),
                    &sW[(((riS * 2 + kcS) << 2) + ntl) << 9]);
        __syncthreads();
#pragma unroll
        for (int kc = 0; kc < 2; kc++) {
            bf16x8 arf[2], aif[2], naf[2], wrf[2], wif[2];
#pragma unroll
            for (int s = 0; s < 2; s++) {
                arf[s] = *(const bf16x8*)&sA[(((kc << 2) + wm * 2 + s) << 9) + l * 8];
                aif[s] = *(const bf16x8*)&sA[((((2 + kc) << 2) + wm * 2 + s) << 9) + l * 8];
                naf[s] = aif[s] ^ sgn;
                wrf[s] = *(const bf16x8*)&sW[(((kc << 2) + wn * 2 + s) << 9) + l * 8];
                wif[s] = *(const bf16x8*)&sW[((((2 + kc) << 2) + wn * 2 + s) << 9) + l * 8];
            }
#pragma unroll
            for (int sm = 0; sm < 2; sm++)
#pragma unroll
                for (int sn = 0; sn < 2; sn++) {
                    accR[sm][sn] = __builtin_amdgcn_mfma_f32_16x16x32_bf16(arf[sm], wrf[sn], accR[sm][sn], 0, 0, 0);
                    accR[sm][sn] = __builtin_amdgcn_mfma_f32_16x16x32_bf16(naf[sm], wif[sn], accR[sm][sn], 0, 0, 0);
                    accI[sm][sn] = __builtin_amdgcn_mfma_f32_16x16x32_bf16(arf[sm], wif[sn], accI[sm][sn], 0, 0, 0);
                    accI[sm][sn] = __builtin_amdgcn_mfma_f32_16x16x32_bf16(aif[sm], wrf[sn], accI[sm][sn], 0, 0, 0);
                }
        }
    }
#pragma unroll
    for (int sm = 0; sm < 2; sm++)
#pragma unroll
        for (int sn = 0; sn < 2; sn++) {
            int row0 = tm * 64 + (wm * 2 + sm) * 16 + (l >> 4) * 4;
            int col  = tn * 64 + (wn * 2 + sn) * 16 + (l & 15);
            float bre = br[col], bie = bi[col];
            float mbe = MODRELU ? mb[col] : 0.f;
#pragma unroll
            for (int v = 0; v < 4; v++) {
                int row = row0 + v;
                float vr = accR[sm][sn][v] + bre;
                float vi = accI[sm][sn][v] + bie;
                if (MODRELU) {
                    float amp = sqrtf(vr * vr + vi * vi + 1e-10f);
                    float sc = fmaxf(amp + mbe, 0.f) / (amp + 1e-10f);
                    vr *= sc; vi *= sc;
                }
                long cidx = (long)row * ldc + col;
                if (RESID) { vr += Rr[cidx]; vi += Ri[cidx]; }
                if (OUTBF16) {
                    ((bf16*)Crv)[cidx] = __float2bfloat16(vr);
                    ((bf16*)Civ)[cidx] = __float2bfloat16(vi);
                } else {
                    ((float*)Crv)[cidx] = vr;
                    ((float*)Civ)[cidx] = vi;
                }
            }
        }
}

// ------------------- pack K/V into attention LDS fragment image (bf16 hi/lo)
__global__ __launch_bounds__(256)
void pack_kv(const float* __restrict__ kr, const float* __restrict__ ki,
             const float* __restrict__ vr, const float* __restrict__ vi,
             short* __restrict__ pK, short* __restrict__ pV, int Sk)
{
    const int F = FF;
    int kt = blockIdx.x, h = blockIdx.y, b = blockIdx.z;
    int nkt = gridDim.x;
    long blkbase = ((long)((b * 8 + h) * nkt) + kt) * 8192;
    int t = threadIdx.x;
#pragma unroll
    for (int it = 0; it < 2; it++) {
        int s = t + 256 * it;
        int sl = s & 63, g = s >> 6;
        int ri = g >> 2, c = (g >> 1) & 1, nt = g & 1;
        int sq = sl >> 4, sn = sl & 15;
        const float* src = ri ? ki : kr;
        long base = ((long)(b * Sk + kt * 32 + nt * 16 + sn)) * F + h * 64 + c * 32 + sq * 8;
        long outH = blkbase + ((((ri * 2 + 0) * 2 + c) * 2 + nt) * 64 + sl) * 8;
        long outL = blkbase + ((((ri * 2 + 1) * 2 + c) * 2 + nt) * 64 + sl) * 8;
#pragma unroll
        for (int j = 0; j < 8; j++) {
            float x = src[base + j];
            short xh = f2bf(x);
            pK[outH + j] = xh;
            pK[outL + j] = f2bf(x - bf2f(xh));
        }
    }
#pragma unroll
    for (int it = 0; it < 2; it++) {
        int s = t + 256 * it;
        int sl = s & 63, g = s >> 6;
        int ri = g >> 2, nt = g & 3;
        int sq = sl >> 4, sn = sl & 15;
        const float* src = ri ? vi : vr;
        long base = ((long)(b * Sk + kt * 32 + sq * 8)) * F + h * 64 + nt * 16 + sn;
        long outH = blkbase + (((ri * 2 + 0) * 4 + nt) * 64 + sl) * 8;
        long outL = blkbase + (((ri * 2 + 1) * 4 + nt) * 64 + sl) * 8;
#pragma unroll
        for (int j = 0; j < 8; j++) {
            float x = src[base + (long)j * F];
            short xh = f2bf(x);
            pV[outH + j] = xh;
            pV[outL + j] = f2bf(x - bf2f(xh));
        }
    }
}

// ------------------------------- MFMA flash complex attention (bf16x3 exact)
// Epilogue writes output directly into A1 [Ah|Al] layout (proper bf16 convert).
__global__ __launch_bounds__(256)
void cattn_mfma(const float* __restrict__ qr, const float* __restrict__ qi,
                const short* __restrict__ pK, const short* __restrict__ pV,
                bf16* __restrict__ dR, bf16* __restrict__ dI,
                int S, int Sk)
{
    __shared__ short sK[8192];
    __shared__ short sV[8192];
    __shared__ short sP[5120];
    const int F = FF;
    int qt = blockIdx.x, h = blockIdx.y, b = blockIdx.z;
    int t = threadIdx.x;
    int w = t >> 6, l = t & 63, q = l >> 4, n16 = l & 15;

    bf16x8 qh_[2][2], ql_[2][2];
    {
        long qbase = ((long)(b * S + qt * 64 + w * 16 + n16)) * F + h * 64 + q * 8;
#pragma unroll
        for (int ri = 0; ri < 2; ri++) {
            const float* src = ri ? qi : qr;
#pragma unroll
            for (int c = 0; c < 2; c++) {
                float vv[8];
                *(float4*)&vv[0] = *(const float4*)&src[qbase + c * 32];
                *(float4*)&vv[4] = *(const float4*)&src[qbase + c * 32 + 4];
#pragma unroll
                for (int j = 0; j < 8; j++) {
                    short xh = f2bf(vv[j]);
                    qh_[ri][c][j] = xh;
                    ql_[ri][c][j] = f2bf(vv[j] - bf2f(xh));
                }
            }
        }
    }

    f32x4 zf = {0.f, 0.f, 0.f, 0.f};
    f32x4 oR[4], oI[4];
#pragma unroll
    for (int nt = 0; nt < 4; nt++) { oR[nt] = zf; oI[nt] = zf; }
    float m_run[4] = {-3.0e38f, -3.0e38f, -3.0e38f, -3.0e38f};
    float l_run[4] = {0.f, 0.f, 0.f, 0.f};

    int nkt = Sk >> 5;
    long pbh = (long)((b * 8 + h) * nkt) * 8192;
    for (int kt = 0; kt < nkt; kt++) {
        __syncthreads();
        long pb = pbh + (long)kt * 8192;
#pragma unroll
        for (int i = 0; i < 4; i++) {
            int bk = w * 4 + i;
            gload16(pK + pb + (bk << 9) + l * 8, &sK[bk << 9]);
            gload16(pV + pb + (bk << 9) + l * 8, &sV[bk << 9]);
        }
        __syncthreads();

        f32x4 sc[2];
        sc[0] = zf; sc[1] = zf;
#pragma unroll
        for (int nt = 0; nt < 2; nt++) {
#pragma unroll
            for (int ri = 0; ri < 2; ri++) {
                bf16x8 kh0 = *(const bf16x8*)&sK[((((ri * 2 + 0) * 2 + 0) * 2 + nt) * 64 + l) * 8];
                bf16x8 kh1 = *(const bf16x8*)&sK[((((ri * 2 + 0) * 2 + 1) * 2 + nt) * 64 + l) * 8];
                bf16x8 kl0 = *(const bf16x8*)&sK[((((ri * 2 + 1) * 2 + 0) * 2 + nt) * 64 + l) * 8];
                bf16x8 kl1 = *(const bf16x8*)&sK[((((ri * 2 + 1) * 2 + 1) * 2 + nt) * 64 + l) * 8];
                sc[nt] = __builtin_amdgcn_mfma_f32_16x16x32_bf16(qh_[ri][0], kh0, sc[nt], 0, 0, 0);
                sc[nt] = __builtin_amdgcn_mfma_f32_16x16x32_bf16(qh_[ri][1], kh1, sc[nt], 0, 0, 0);
                sc[nt] = __builtin_amdgcn_mfma_f32_16x16x32_bf16(ql_[ri][0], kh0, sc[nt], 0, 0, 0);
                sc[nt] = __builtin_amdgcn_mfma_f32_16x16x32_bf16(ql_[ri][1], kh1, sc[nt], 0, 0, 0);
                sc[nt] = __builtin_amdgcn_mfma_f32_16x16x32_bf16(qh_[ri][0], kl0, sc[nt], 0, 0, 0);
                sc[nt] = __builtin_amdgcn_mfma_f32_16x16x32_bf16(qh_[ri][1], kl1, sc[nt], 0, 0, 0);
            }
        }
        float alpha[4];
#pragma unroll
        for (int v = 0; v < 4; v++) {
            float s0 = sc[0][v] * 0.125f, s1 = sc[1][v] * 0.125f;
            float mx = fmaxf(s0, s1);
            mx = fmaxf(mx, __shfl_xor(mx, 1));
            mx = fmaxf(mx, __shfl_xor(mx, 2));
            mx = fmaxf(mx, __shfl_xor(mx, 4));
            mx = fmaxf(mx, __shfl_xor(mx, 8));
            float mnew = fmaxf(m_run[v], mx);
            float p0 = __expf(s0 - mnew), p1 = __expf(s1 - mnew);
            sc[0][v] = p0; sc[1][v] = p1;
            float ps = p0 + p1;
            ps += __shfl_xor(ps, 1);
            ps += __shfl_xor(ps, 2);
            ps += __shfl_xor(ps, 4);
            ps += __shfl_xor(ps, 8);
            alpha[v] = __expf(m_run[v] - mnew);
            l_run[v] = l_run[v] * alpha[v] + ps;
            m_run[v] = mnew;
        }
#pragma unroll
        for (int nt = 0; nt < 4; nt++)
#pragma unroll
            for (int v = 0; v < 4; v++) { oR[nt][v] *= alpha[v]; oI[nt][v] *= alpha[v]; }
        int pbase = w * 1280;
#pragma unroll
        for (int nt = 0; nt < 2; nt++)
#pragma unroll
            for (int v = 0; v < 4; v++) {
                float p = sc[nt][v];
                short ph = f2bf(p);
                short pl = f2bf(p - bf2f(ph));
                int idx = pbase + (q * 4 + v) * 40 + nt * 16 + n16;
                sP[idx] = ph;
                sP[idx + 640] = pl;
            }
        bf16x8 pH = *(const bf16x8*)&sP[pbase + n16 * 40 + q * 8];
        bf16x8 pL = *(const bf16x8*)&sP[pbase + 640 + n16 * 40 + q * 8];
#pragma unroll
        for (int nt = 0; nt < 4; nt++) {
            bf16x8 vh = *(const bf16x8*)&sV[(((0 * 2 + 0) * 4 + nt) * 64 + l) * 8];
            bf16x8 vl = *(const bf16x8*)&sV[(((0 * 2 + 1) * 4 + nt) * 64 + l) * 8];
            oR[nt] = __builtin_amdgcn_mfma_f32_16x16x32_bf16(pH, vh, oR[nt], 0, 0, 0);
            oR[nt] = __builtin_amdgcn_mfma_f32_16x16x32_bf16(pL, vh, oR[nt], 0, 0, 0);
            oR[nt] = __builtin_amdgcn_mfma_f32_16x16x32_bf16(pH, vl, oR[nt], 0, 0, 0);
            bf16x8 wh = *(const bf16x8*)&sV[(((1 * 2 + 0) * 4 + nt) * 64 + l) * 8];
            bf16x8 wl2 = *(const bf16x8*)&sV[(((1 * 2 + 1) * 4 + nt) * 64 + l) * 8];
            oI[nt] = __builtin_amdgcn_mfma_f32_16x16x32_bf16(pH, wh, oI[nt], 0, 0, 0);
            oI[nt] = __builtin_amdgcn_mfma_f32_16x16x32_bf16(pL, wh, oI[nt], 0, 0, 0);
            oI[nt] = __builtin_amdgcn_mfma_f32_16x16x32_bf16(pH, wl2, oI[nt], 0, 0, 0);
        }
    }
    // ---- epilogue: write [Ah|Al] expanded rows of A1 directly (FIXED: proper
    // __float2bfloat16 value conversion, NOT raw-bit short -> bf16 assignment)
#pragma unroll
    for (int v = 0; v < 4; v++) {
        float inv = 1.0f / l_run[v];
        long rbase = ((long)(b * S + qt * 64 + w * 16 + q * 4 + v)) * 1024;
#pragma unroll
        for (int nt = 0; nt < 4; nt++) {
            int col = h * 64 + nt * 16 + n16;
            float vr = oR[nt][v] * inv;
            bf16 hh = __float2bfloat16(vr);
            dR[rbase + col] = hh;
            dR[rbase + 512 + col] = __float2bfloat16(vr - __bfloat162float(hh));
            float vi = oI[nt][v] * inv;
            bf16 hi2 = __float2bfloat16(vi);
            dI[rbase + col] = hi2;
            dI[rbase + 512 + col] = __float2bfloat16(vi - __bfloat162float(hi2));
        }
    }
}

// ---------------------------------------------------- MoE routing tables
__global__ __launch_bounds__(256)
void moe_build_kernel(const int* __restrict__ eidx, int* __restrict__ order,
                      int* __restrict__ te128, int* __restrict__ te64)
{
    __shared__ int cnt[NEXP], segbase[NEXP], cursor[NEXP], tb128[NEXP], n128[NEXP];
    int t = threadIdx.x;
    if (t < NEXP) { cnt[t] = 0; cursor[t] = 0; }
    __syncthreads();
    for (int i = t; i < NTOK; i += 256) atomicAdd(&cnt[eidx[i]], 1);
    __syncthreads();
    if (t == 0) {
        int ob = 0, tb = 0;
        for (int e = 0; e < NEXP; e++) {
            segbase[e] = ob; tb128[e] = tb;
            int tiles = (cnt[e] + 127) >> 7;
            n128[e] = tiles;
            ob += tiles << 7; tb += tiles;
        }
    }
    __syncthreads();
    for (int i = t; i < NPAD128; i += 256) order[i] = -1;
    if (t < TMAX128) {
        int ex = -1;
        for (int e = 0; e < NEXP; e++)
            if (t >= tb128[e] && t < tb128[e] + n128[e]) ex = e;
        te128[t] = ex;
    }
    if (t >= 64 && t < 64 + 2 * TMAX128) {
        int tt = t - 64;
        int ex = -1;
        for (int e = 0; e < NEXP; e++)
            if (tt >= tb128[e] * 2 && tt < (tb128[e] + n128[e]) * 2) ex = e;
        te64[tt] = ex;
    }
    __syncthreads();
    for (int i = t; i < NTOK; i += 256) {
        int e = eidx[i];
        int pos = atomicAdd(&cursor[e], 1);
        order[segbase[e] + pos] = i;
    }
}

__global__ __launch_bounds__(256)
void combine_kernel(const int* __restrict__ order,
                    const float* __restrict__ xr, const float* __restrict__ xi,
                    const float* __restrict__ yr, const float* __restrict__ yi,
                    float* __restrict__ out)
{
    const int F = FF;
    int p = blockIdx.x;
    int tok = order[p];
    if (tok < 0) return;
    int t = threadIdx.x;
    float* outr = out;
    float* outi = out + (long)NTOK * FF;
#pragma unroll
    for (int u = 0; u < 2; u++) {
        int j = t + u * 256;
        long src = (long)p * F + j;
        long dst = (long)tok * F + j;
        outr[dst] = xr[dst] + yr[src];
        outi[dst] = xi[dst] + yi[src];
    }
}

// ------------------------------------------------------------------- launch
extern "C" void kernel_launch(void* const* d_in, const int* in_sizes, int n_in,
                              void* d_out, int out_size, void* d_ws, size_t ws_size,
                              hipStream_t stream)
{
    (void)in_sizes; (void)n_in; (void)out_size; (void)ws_size;
    const float* x_r   = (const float*)d_in[0];
    const float* x_i   = (const float*)d_in[1];
    const float* ctx_r = (const float*)d_in[2];
    const float* ctx_i = (const float*)d_in[3];
    const float* ln1_g = (const float*)d_in[4];
    const float* ln2_g = (const float*)d_in[5];
    const float* ln3_g = (const float*)d_in[6];
    const float* sa_qWr = (const float*)d_in[7];   const float* sa_qWi = (const float*)d_in[8];
    const float* sa_qbr = (const float*)d_in[9];   const float* sa_qbi = (const float*)d_in[10];
    const float* sa_kWr = (const float*)d_in[11];  const float* sa_kWi = (const float*)d_in[12];
    const float* sa_kbr = (const float*)d_in[13];  const float* sa_kbi = (const float*)d_in[14];
    const float* sa_vWr = (const float*)d_in[15];  const float* sa_vWi = (const float*)d_in[16];
    const float* sa_vbr = (const float*)d_in[17];  const float* sa_vbi = (const float*)d_in[18];
    const float* sa_oWr = (const float*)d_in[19];  const float* sa_oWi = (const float*)d_in[20];
    const float* sa_obr = (const float*)d_in[21];  const float* sa_obi = (const float*)d_in[22];
    const float* ca_qWr = (const float*)d_in[23];  const float* ca_qWi = (const float*)d_in[24];
    const float* ca_qbr = (const float*)d_in[25];  const float* ca_qbi = (const float*)d_in[26];
    const float* ca_kWr = (const float*)d_in[27];  const float* ca_kWi = (const float*)d_in[28];
    const float* ca_kbr = (const float*)d_in[29];  const float* ca_kbi = (const float*)d_in[30];
    const float* ca_vWr = (const float*)d_in[31];  const float* ca_vWi = (const float*)d_in[32];
    const float* ca_vbr = (const float*)d_in[33];  const float* ca_vbi = (const float*)d_in[34];
    const float* ca_oWr = (const float*)d_in[35];  const float* ca_oWi = (const float*)d_in[36];
    const float* ca_obr = (const float*)d_in[37];  const float* ca_obi = (const float*)d_in[38];
    const float* moe_W1r = (const float*)d_in[39]; const float* moe_W1i = (const float*)d_in[40];
    const float* moe_b1r = (const float*)d_in[41]; const float* moe_b1i = (const float*)d_in[42];
    const float* moe_mb  = (const float*)d_in[43];
    const float* moe_W2r = (const float*)d_in[44]; const float* moe_W2i = (const float*)d_in[45];
    const float* moe_b2r = (const float*)d_in[46]; const float* moe_b2i = (const float*)d_in[47];
    float* out = (float*)d_out;

    char* W = (char*)d_ws;
    const long NF = (long)NTOK * FF;
    const long NF4 = NF * 4;                      // 8 MB
    float* xr = (float*)(W + 0 * NF4);
    float* xi = (float*)(W + 1 * NF4);
    char* base2 = W + 2 * NF4;                    // 16.8 MB region
    short* pKbuf = (short*)base2;                 // attention phase
    bf16* h3r = (bf16*)base2;                     // MoE phase
    bf16* h3i = (bf16*)(base2 + 4194304);
    char* poolB = W + 4 * NF4;                    // 67.1 MB pool
    float* qr = (float*)poolB;                float* qi = (float*)(poolB + NF4);
    float* kr = (float*)(poolB + 2 * NF4);    float* ki = (float*)(poolB + 3 * NF4);
    float* vr = (float*)(poolB + 4 * NF4);    float* vi = (float*)(poolB + 5 * NF4);
    short* pVbuf = (short*)(poolB + 6 * NF4);     // attention phase (16 MB)
    bf16* u_r = (bf16*)poolB;                     // MoE overlay: 5120x2048
    bf16* u_i = (bf16*)(poolB + 20971520);
    float* y_r = (float*)(poolB + 41943040);      // 5120x512 f32
    float* y_i = (float*)(poolB + 52428800);
    char* Q = W + 12 * NF4;
    bf16* A1r = (bf16*)Q;                         // 4096x1024
    bf16* A1i = (bf16*)(Q + 8388608);
    bf16* A2r = (bf16*)(Q + 16777216);            // 1024x1536
    bf16* A2i = (bf16*)(Q + 19922944);
    char* WQ = Q + 23068672;
    const long PS1 = 524288;
    const long PS2 = 786432;
    bf16* saq_r = (bf16*)(WQ);                   bf16* saq_i = saq_r + PS1;
    bf16* sak_r = saq_r + 2 * PS1;               bf16* sak_i = saq_r + 3 * PS1;
    bf16* sav_r = saq_r + 4 * PS1;               bf16* sav_i = saq_r + 5 * PS1;
    bf16* sao_r = saq_r + 6 * PS1;               bf16* sao_i = saq_r + 7 * PS1;
    bf16* caq_r = saq_r + 8 * PS1;               bf16* caq_i = saq_r + 9 * PS1;
    bf16* cao_r = saq_r + 10 * PS1;              bf16* cao_i = saq_r + 11 * PS1;
    bf16* cak_r = saq_r + 12 * PS1;              bf16* cak_i = cak_r + PS2;
    bf16* cav_r = cak_r + 2 * PS2;               bf16* cav_i = cak_r + 3 * PS2;
    bf16* Wm_r = (bf16*)Q;                        // MoE weight overlay
    bf16* Wm_i = (bf16*)(Q + 16777216);
    char* ints = W + 12 * NF4 + 41943040 + 524288;   // past WQ end, padded
    int* eidx  = (int*)ints;
    int* order = eidx + NTOK;
    int* te128 = order + NPAD128;
    int* te64  = te128 + 64;

    dim3 blk(256);
    const long W1S = (long)FF * HID;
    const long CZ = 2 * NF4;
    Ptr6 bQKV = {{sa_qbr, sa_qbi, sa_kbr, sa_kbi, sa_vbr, sa_vbi}};
    Ptr6 bSAO = {{sa_obr, sa_obi, 0, 0, 0, 0}};
    Ptr6 bCAQ = {{ca_qbr, ca_qbi, 0, 0, 0, 0}};
    Ptr6 bCKV = {{ca_kbr, ca_kbi, ca_vbr, ca_vbi, 0, 0}};
    Ptr6 bCAO = {{ca_obr, ca_obi, 0, 0, 0, 0}};
    Ptr6 bM1  = {{moe_b1r, moe_b1i, 0, 0, 0, 0}};
    Ptr6 bM2  = {{moe_b2r, moe_b2i, 0, 0, 0, 0}};

    // ---- all 8 attention weight packs in one dispatch
    WPackAll wp;
    wp.sR[0]=sa_qWr; wp.sI[0]=sa_qWi; wp.dR[0]=saq_r; wp.dI[0]=saq_i; wp.kdiv[0]=16;
    wp.sR[1]=sa_kWr; wp.sI[1]=sa_kWi; wp.dR[1]=sak_r; wp.dI[1]=sak_i; wp.kdiv[1]=16;
    wp.sR[2]=sa_vWr; wp.sI[2]=sa_vWi; wp.dR[2]=sav_r; wp.dI[2]=sav_i; wp.kdiv[2]=16;
    wp.sR[3]=sa_oWr; wp.sI[3]=sa_oWi; wp.dR[3]=sao_r; wp.dI[3]=sao_i; wp.kdiv[3]=16;
    wp.sR[4]=ca_qWr; wp.sI[4]=ca_qWi; wp.dR[4]=caq_r; wp.dI[4]=caq_i; wp.kdiv[4]=16;
    wp.sR[5]=ca_oWr; wp.sI[5]=ca_oWi; wp.dR[5]=cao_r; wp.dI[5]=cao_i; wp.kdiv[5]=16;
    wp.sR[6]=ca_kWr; wp.sI[6]=ca_kWi; wp.dR[6]=cak_r; wp.dI[6]=cak_i; wp.kdiv[6]=24;
    wp.sR[7]=ca_vWr; wp.sI[7]=ca_vWi; wp.dR[7]=cav_r; wp.dI[7]=cav_i; wp.kdiv[7]=24;
    expandW_all<<<dim3(8, 48, 8), blk, 0, stream>>>(wp);

    // ---- self-attention block
    cln_expand<<<NTOK, blk, 0, stream>>>(x_r, x_i, ln1_g, A1r, A1i);
    cgemm128<true,false,false,false,false><<<dim3(32, 4, 3), blk, 0, stream>>>(
        A1r, A1i, 1024, 512, saq_r, saq_i, 2 * PS1, 0, 32, 16,
        bQKV, 0, nullptr, qr, qi, CZ, FF, 1536, nullptr, nullptr);
    pack_kv<<<dim3(32, 8, 4), blk, 0, stream>>>(kr, ki, vr, vi, pKbuf, pVbuf, 1024);
    cattn_mfma<<<dim3(16, 8, 4), blk, 0, stream>>>(qr, qi, pKbuf, pVbuf, A1r, A1i, 1024, 1024);
    cgemm_mfma<true,false,false,false,true,false><<<dim3(64, 8, 1), blk, 0, stream>>>(
        A1r, A1i, 1024, 512, sao_r, sao_i, 0, 0, 32, 16,
        bSAO, 0, nullptr, x_r, x_i, xr, xi, 0, FF, 1536, nullptr, nullptr);

    // ---- cross-attention block
    cln_expand<<<NTOK, blk, 0, stream>>>(xr, xi, ln2_g, A1r, A1i);
    cgemm_mfma<true,false,false,false,false,false><<<dim3(64, 8, 1), blk, 0, stream>>>(
        A1r, A1i, 1024, 512, caq_r, caq_i, 0, 0, 32, 16,
        bCAQ, 0, nullptr, nullptr, nullptr, qr, qi, 0, FF, 1536, nullptr, nullptr);
    expandA_x2<<<dim3(3, 1024), blk, 0, stream>>>(ctx_r, ctx_i, A2r, A2i, CDIM);
    cgemm_mfma<true,false,false,false,false,false><<<dim3(16, 8, 2), blk, 0, stream>>>(
        A2r, A2i, 1536, 768, cak_r, cak_i, 2 * PS2, 0, 32, 24,
        bCKV, 0, nullptr, nullptr, nullptr, kr, ki, CZ, FF, 2304, nullptr, nullptr);
    pack_kv<<<dim3(8, 8, 4), blk, 0, stream>>>(kr, ki, vr, vi, pKbuf, pVbuf, 256);
    cattn_mfma<<<dim3(16, 8, 4), blk, 0, stream>>>(qr, qi, pKbuf, pVbuf, A1r, A1i, 1024, 256);
    cgemm_mfma<true,false,false,false,true,false><<<dim3(64, 8, 1), blk, 0, stream>>>(
        A1r, A1i, 1024, 512, cao_r, cao_i, 0, 0, 32, 16,
        bCAO, 0, nullptr, xr, xi, xr, xi, 0, FF, 1536, nullptr, nullptr);

    // ---- phase-routed MoE
    cln_route<<<NTOK, blk, 0, stream>>>(xr, xi, ln3_g, h3r, h3i, eidx);
    moe_build_kernel<<<1, blk, 0, stream>>>(eidx, order, te128, te64);
    convW_packed<<<dim3(32, 16, 8), blk, 0, stream>>>(moe_W1r, moe_W1i, Wm_r, Wm_i, HID, W1S);
    cgemm128<false,true,true,true,true><<<dim3(TMAX128, 16, 1), blk, 0, stream>>>(
        h3r, h3i, 512, 512, Wm_r, Wm_i, 0, W1S, 128, 0,
        bM1, HID, moe_mb, u_r, u_i, 0, HID, 512, order, te128);
    convW_packed<<<dim3(8, 64, 8), blk, 0, stream>>>(moe_W2r, moe_W2i, Wm_r, Wm_i, FF, W1S);
    cgemm_mfma<false,true,false,false,false,false><<<dim3(2 * TMAX128, 8, 1), blk, 0, stream>>>(
        u_r, u_i, 2048, 2048, Wm_r, Wm_i, 0, W1S, 32, 0,
        bM2, FF, nullptr, nullptr, nullptr, y_r, y_i, 0, FF, 2048, nullptr, te64);
    combine_kernel<<<NPAD128, blk, 0, stream>>>(order, xr, xi, y_r, y_i, out);
}

// Round 7
// 866.391 us; speedup vs baseline: 8.3938x; 1.0002x over previous
//
#include <hip/hip_runtime.h>
#include <hip/hip_bf16.h>
#include <math.h>

// ComplexTransformerBlock: B=4 S=1024 L=256 F=512 CD=768 NH=8 (d=64) E=8 HID=2048
// Round 7: XCD-locality banding (1D grids decoded so linear%8 ~ XCD selects a
// band): cattn gets 4 (b,h) per XCD (K/V pack fits 4MB L2); MoE L1/L2 banded by
// tile-row so each XCD streams ~1 expert's weights. MoE L2 moved to 128x128 tile.

#define NTOK 4096
#define FF   512
#define CDIM 768
#define NEXP 8
#define HID  2048
#define TMAX128 40
#define NPAD128 (TMAX128 * 128)   // 5120

typedef __hip_bfloat16 bf16;
typedef short bf16x8 __attribute__((ext_vector_type(8)));
typedef float f32x4  __attribute__((ext_vector_type(4)));

struct Ptr6 { const float* p[6]; };
struct WPackAll {
    const float* sR[8]; const float* sI[8];
    bf16* dR[8]; bf16* dI[8];
    int kdiv[8];
};

__device__ __forceinline__ short f2bf(float x) {          // raw bf16 bits (for short* bufs)
    unsigned u = __float_as_uint(x);
    unsigned r = (u + 0x7fff + ((u >> 16) & 1)) >> 16;
    return (short)r;
}
__device__ __forceinline__ float bf2f(short s) {
    return __uint_as_float(((unsigned)(unsigned short)s) << 16);
}
__device__ __forceinline__ void gload16(const void* g, void* l) {
    __builtin_amdgcn_global_load_lds(
        (const __attribute__((address_space(1))) unsigned int*)g,
        (__attribute__((address_space(3))) unsigned int*)l, 16, 0, 0);
}

// --------------------------- fused complex LN -> A1 [Ah|Al] (M x 1024 bf16)
__global__ __launch_bounds__(256)
void cln_expand(const float* __restrict__ xr, const float* __restrict__ xi,
                const float* __restrict__ g,
                bf16* __restrict__ dR, bf16* __restrict__ dI)
{
    long base = (long)blockIdx.x * FF;
    int t = threadIdx.x;
    int j0 = t, j1 = t + 256;
    float xr0 = xr[base + j0], xi0 = xi[base + j0];
    float xr1 = xr[base + j1], xi1 = xi[base + j1];
    float a0 = sqrtf(xr0 * xr0 + xi0 * xi0 + 1e-6f);
    float a1 = sqrtf(xr1 * xr1 + xi1 * xi1 + 1e-6f);
    float s = a0 + a1;
#pragma unroll
    for (int off = 32; off >= 1; off >>= 1) s += __shfl_xor(s, off);
    __shared__ float wsum[4];
    if ((t & 63) == 0) wsum[t >> 6] = s;
    __syncthreads();
    float mean = (wsum[0] + wsum[1] + wsum[2] + wsum[3]) * (1.0f / 512.0f);
    float d0 = g[j0] * (a0 / (mean + 1e-6f)) / (a0 + 1e-6f);
    float d1 = g[j1] * (a1 / (mean + 1e-6f)) / (a1 + 1e-6f);
    long d = (long)blockIdx.x * 1024;
    float h; bf16 hh;
    h = xr0 * d0; hh = __float2bfloat16(h);
    dR[d + j0] = hh; dR[d + 512 + j0] = __float2bfloat16(h - __bfloat162float(hh));
    h = xi0 * d0; hh = __float2bfloat16(h);
    dI[d + j0] = hh; dI[d + 512 + j0] = __float2bfloat16(h - __bfloat162float(hh));
    h = xr1 * d1; hh = __float2bfloat16(h);
    dR[d + j1] = hh; dR[d + 512 + j1] = __float2bfloat16(h - __bfloat162float(hh));
    h = xi1 * d1; hh = __float2bfloat16(h);
    dI[d + j1] = hh; dI[d + 512 + j1] = __float2bfloat16(h - __bfloat162float(hh));
}

// --------------------- fused complex LN -> h3 (bf16) + phase routing (eidx)
__global__ __launch_bounds__(256)
void cln_route(const float* __restrict__ xr, const float* __restrict__ xi,
               const float* __restrict__ g,
               bf16* __restrict__ h3r, bf16* __restrict__ h3i,
               int* __restrict__ eidx)
{
    long base = (long)blockIdx.x * FF;
    int t = threadIdx.x;
    int j0 = t, j1 = t + 256;
    float xr0 = xr[base + j0], xi0 = xi[base + j0];
    float xr1 = xr[base + j1], xi1 = xi[base + j1];
    float a0 = sqrtf(xr0 * xr0 + xi0 * xi0 + 1e-6f);
    float a1 = sqrtf(xr1 * xr1 + xi1 * xi1 + 1e-6f);
    float s = a0 + a1;
#pragma unroll
    for (int off = 32; off >= 1; off >>= 1) s += __shfl_xor(s, off);
    __shared__ float wsum[4];
    __shared__ double wss[4], wcc[4];
    if ((t & 63) == 0) wsum[t >> 6] = s;
    __syncthreads();
    float mean = (wsum[0] + wsum[1] + wsum[2] + wsum[3]) * (1.0f / 512.0f);
    float d0 = g[j0] * (a0 / (mean + 1e-6f)) / (a0 + 1e-6f);
    float d1 = g[j1] * (a1 / (mean + 1e-6f)) / (a1 + 1e-6f);
    float h0r = xr0 * d0, h0i = xi0 * d0;
    float h1r = xr1 * d1, h1i = xi1 * d1;
    h3r[base + j0] = __float2bfloat16(h0r);
    h3i[base + j0] = __float2bfloat16(h0i);
    h3r[base + j1] = __float2bfloat16(h1r);
    h3i[base + j1] = __float2bfloat16(h1i);
    float ph0 = atan2f(h0i, h0r), ph1 = atan2f(h1i, h1r);
    double ss = (double)sinf(ph0) + (double)sinf(ph1);
    double cc = (double)cosf(ph0) + (double)cosf(ph1);
#pragma unroll
    for (int off = 32; off >= 1; off >>= 1) {
        ss += __shfl_xor(ss, off);
        cc += __shfl_xor(cc, off);
    }
    if ((t & 63) == 0) { wss[t >> 6] = ss; wcc[t >> 6] = cc; }
    __syncthreads();
    if (t == 0) {
        float msin = (float)((wss[0] + wss[1] + wss[2] + wss[3]) * (1.0 / 512.0));
        float mcos = (float)((wcc[0] + wcc[1] + wcc[2] + wcc[3]) * (1.0 / 512.0));
        float tp = atan2f(msin, mcos);
        float a = (tp + 3.14159274101257324f) / 6.28318548202514648f * 8.0f;
        int k = (int)floorf(a);
        k = min(max(k, 0), NEXP - 1);
        eidx[blockIdx.x] = k;
    }
}

// ------------------------------------------------- fp32 -> [Ah|Al] (ctx only)
__global__ __launch_bounds__(256)
void expandA_x2(const float* __restrict__ sR, const float* __restrict__ sI,
                bf16* __restrict__ dR, bf16* __restrict__ dI, int K)
{
    int k = blockIdx.x * 256 + threadIdx.x;
    int m = blockIdx.y;
    long s = (long)m * K + k;
    long d = (long)m * 2 * K + k;
    float a = sR[s];
    bf16 ah = __float2bfloat16(a);
    dR[d] = ah; dR[d + K] = __float2bfloat16(a - __bfloat162float(ah));
    float b = sI[s];
    bf16 bh = __float2bfloat16(b);
    dI[d] = bh; dI[d + K] = __float2bfloat16(b - __bfloat162float(bh));
}

// --------------------------- all 8 attention W packs in one dispatch (x2 phys)
__global__ __launch_bounds__(256)
void expandW_all(WPackAll p)
{
    int z = blockIdx.z;
    int kdiv = p.kdiv[z];
    int kc = blockIdx.y;
    if (kc >= 2 * kdiv) return;
    const int N = FF;
    int g = blockIdx.x * 256 + threadIdx.x;
    int nt = g >> 6, l = g & 63;
    int lo = (kc >= kdiv);
    int kb = (kc - (lo ? kdiv : 0)) * 32 + (l >> 4) * 8;
    int n  = nt * 16 + (l & 15);
    long dbase = ((long)kc * (N >> 4) + nt) * 512 + l * 8;
    const float* sR = p.sR[z]; const float* sI = p.sI[z];
    bf16* dR = p.dR[z]; bf16* dI = p.dI[z];
#pragma unroll
    for (int j = 0; j < 8; j++) {
        float a = sR[(long)(kb + j) * N + n];
        bf16 ah = __float2bfloat16(a);
        dR[dbase + j] = lo ? __float2bfloat16(a - __bfloat162float(ah)) : ah;
        float b = sI[(long)(kb + j) * N + n];
        bf16 bh = __float2bfloat16(b);
        dI[dbase + j] = lo ? __float2bfloat16(b - __bfloat162float(bh)) : bh;
    }
}

// W -> packed plain bf16, expert-strided (MoE weights)
__global__ __launch_bounds__(256)
void convW_packed(const float* __restrict__ sR, const float* __restrict__ sI,
                  bf16* __restrict__ dR, bf16* __restrict__ dI,
                  int N, long estride)
{
    int g = blockIdx.x * 256 + threadIdx.x;
    int nt = g >> 6, l = g & 63;
    int kc = blockIdx.y;
    int e  = blockIdx.z;
    const float* srcR = sR + (long)e * estride;
    const float* srcI = sI + (long)e * estride;
    bf16* dstR = dR + (long)e * estride;
    bf16* dstI = dI + (long)e * estride;
    int kb = kc * 32 + (l >> 4) * 8;
    int n  = nt * 16 + (l & 15);
    long dbase = ((long)kc * (N >> 4) + nt) * 512 + l * 8;
#pragma unroll
    for (int j = 0; j < 8; j++) {
        dstR[dbase + j] = __float2bfloat16(srcR[(long)(kb + j) * N + n]);
        dstI[dbase + j] = __float2bfloat16(srcI[(long)(kb + j) * N + n]);
    }
}

// ---------------------------------------------- complex MFMA GEMM 128x128
// 4 waves in 2x2; each wave 64x64 quadrant = 4x4 16x16 subtiles (x r,i).
// 64 KB LDS, BK=64. bandM>0: 1D grid, linear%8 (~XCD) selects a tile-row band
// of bandM rows so each XCD's L2 holds one weight slice.
template<bool X3, bool EXPERT, bool GATHER, bool MODRELU, bool OUTBF16>
__global__ __launch_bounds__(256, 2)
void cgemm128(const bf16* __restrict__ Ar, const bf16* __restrict__ Ai,
              int lda, int Kreal,
              const bf16* __restrict__ Wr0, const bf16* __restrict__ Wi0,
              long wz, long westride, int ntTot, int kdiv,
              Ptr6 bias, int bstride, const float* __restrict__ mb,
              void* __restrict__ Cr0, void* __restrict__ Ci0, long cz,
              int ldc, int Kp, int bandM,
              const int* __restrict__ order, const int* __restrict__ tileExpert)
{
    __shared__ short sA[16384];   // 32 KB: [(ri*2+kc)*8 + mt][lane64][8]
    __shared__ short sW[16384];   // 32 KB: [(ri*2+kc)*8 + nt][lane64][8]
    int tm, tn, z;
    if (bandM > 0) {
        int L = blockIdx.x;
        int xcd = L & 7, idx = L >> 3;
        tm = xcd * bandM + idx % bandM;
        tn = idx / bandM;
        z = 0;
    } else {
        tm = blockIdx.x; tn = blockIdx.y; z = blockIdx.z;
    }
    const bf16* Wr = Wr0 + (long)z * wz;
    const bf16* Wi = Wi0 + (long)z * wz;
    const float* br = bias.p[2 * z];
    const float* bi = bias.p[2 * z + 1];
    void* Crv = (char*)Cr0 + (long)z * cz;
    void* Civ = (char*)Ci0 + (long)z * cz;
    if (EXPERT) {
        int e = tileExpert[tm];
        if (e < 0) return;
        Wr += (long)e * westride;  Wi += (long)e * westride;
        br += (long)e * bstride;   bi += (long)e * bstride;
        if (MODRELU) mb += (long)e * bstride;
    }
    int t = threadIdx.x;
    int l = t & 63, w = t >> 6;
    int riS = w >> 1, kcS = w & 1;
    const bf16* Asrc = riS ? Ai : Ar;
    const bf16* Wsrc = riS ? Wi : Wr;
    int kq8 = (l >> 4) * 8;
    long arb[8];
#pragma unroll
    for (int mt = 0; mt < 8; mt++) {
        int grow = tm * 128 + mt * 16 + (l & 15);
        int tok = grow;
        if (GATHER) { int gg = order[grow]; tok = (gg < 0) ? 0 : gg; }
        arb[mt] = (long)tok * lda;
    }
    int wm = w & 1, wn = w >> 1;

    f32x4 zf = {0.f, 0.f, 0.f, 0.f};
    f32x4 accR[4][4], accI[4][4];
#pragma unroll
    for (int a = 0; a < 4; a++)
#pragma unroll
        for (int b = 0; b < 4; b++) { accR[a][b] = zf; accI[a][b] = zf; }

    const bf16x8 sgn = {(short)0x8000,(short)0x8000,(short)0x8000,(short)0x8000,
                        (short)0x8000,(short)0x8000,(short)0x8000,(short)0x8000};

    for (int k0 = 0; k0 < Kp; k0 += 64) {
        __syncthreads();
        int lc = k0 + kcS * 32;
        int acol = (X3 && lc >= 2 * Kreal) ? lc - 2 * Kreal : lc;
#pragma unroll
        for (int mt = 0; mt < 8; mt++)
            gload16(Asrc + arb[mt] + acol + kq8,
                    &sA[(((riS * 2 + kcS) * 8 + mt) << 9)]);
        int kcl = (k0 >> 5) + kcS;
        int pkc = (X3 && kcl >= kdiv) ? kcl - kdiv : kcl;
        const bf16* wb = Wsrc + (((long)pkc * ntTot + tn * 8) << 9) + l * 8;
#pragma unroll
        for (int ntl = 0; ntl < 8; ntl++)
            gload16(wb + (ntl << 9),
                    &sW[(((riS * 2 + kcS) * 8 + ntl) << 9)]);
        __syncthreads();
#pragma unroll
        for (int kc = 0; kc < 2; kc++) {
            bf16x8 wrf[4], wif[4];
#pragma unroll
            for (int sn = 0; sn < 4; sn++) {
                wrf[sn] = *(const bf16x8*)&sW[(((kc * 8) + wn * 4 + sn) << 9) + l * 8];
                wif[sn] = *(const bf16x8*)&sW[((((2 + kc) * 8) + wn * 4 + sn) << 9) + l * 8];
            }
#pragma unroll
            for (int sm = 0; sm < 4; sm++) {
                bf16x8 ar = *(const bf16x8*)&sA[(((kc * 8) + wm * 4 + sm) << 9) + l * 8];
                bf16x8 ai = *(const bf16x8*)&sA[((((2 + kc) * 8) + wm * 4 + sm) << 9) + l * 8];
                bf16x8 na = ai ^ sgn;
#pragma unroll
                for (int sn = 0; sn < 4; sn++) {
                    accR[sm][sn] = __builtin_amdgcn_mfma_f32_16x16x32_bf16(ar, wrf[sn], accR[sm][sn], 0, 0, 0);
                    accR[sm][sn] = __builtin_amdgcn_mfma_f32_16x16x32_bf16(na, wif[sn], accR[sm][sn], 0, 0, 0);
                    accI[sm][sn] = __builtin_amdgcn_mfma_f32_16x16x32_bf16(ar, wif[sn], accI[sm][sn], 0, 0, 0);
                    accI[sm][sn] = __builtin_amdgcn_mfma_f32_16x16x32_bf16(ai, wrf[sn], accI[sm][sn], 0, 0, 0);
                }
            }
        }
    }
#pragma unroll
    for (int sm = 0; sm < 4; sm++)
#pragma unroll
        for (int sn = 0; sn < 4; sn++) {
            int row0 = tm * 128 + wm * 64 + sm * 16 + (l >> 4) * 4;
            int col  = tn * 128 + wn * 64 + sn * 16 + (l & 15);
            float bre = br[col], bie = bi[col];
            float mbe = MODRELU ? mb[col] : 0.f;
#pragma unroll
            for (int v = 0; v < 4; v++) {
                int row = row0 + v;
                float vr = accR[sm][sn][v] + bre;
                float vi = accI[sm][sn][v] + bie;
                if (MODRELU) {
                    float amp = sqrtf(vr * vr + vi * vi + 1e-10f);
                    float sc = fmaxf(amp + mbe, 0.f) / (amp + 1e-10f);
                    vr *= sc; vi *= sc;
                }
                long cidx = (long)row * ldc + col;
                if (OUTBF16) {
                    ((bf16*)Crv)[cidx] = __float2bfloat16(vr);
                    ((bf16*)Civ)[cidx] = __float2bfloat16(vi);
                } else {
                    ((float*)Crv)[cidx] = vr;
                    ((float*)Civ)[cidx] = vi;
                }
            }
        }
}

// -------------------------------------------------- complex MFMA GEMM 64x64
template<bool X3, bool EXPERT, bool GATHER, bool MODRELU, bool RESID, bool OUTBF16>
__global__ __launch_bounds__(256)
void cgemm_mfma(const bf16* __restrict__ Ar, const bf16* __restrict__ Ai,
                int lda, int Kreal,
                const bf16* __restrict__ Wr0, const bf16* __restrict__ Wi0,
                long wz, long westride, int ntTot, int kdiv,
                Ptr6 bias, int bstride, const float* __restrict__ mb,
                const float* __restrict__ Rr, const float* __restrict__ Ri,
                void* __restrict__ Cr0, void* __restrict__ Ci0, long cz,
                int ldc, int Kp,
                const int* __restrict__ order, const int* __restrict__ tileExpert)
{
    __shared__ short sA[8192];
    __shared__ short sW[8192];
    int tm = blockIdx.x, tn = blockIdx.y, z = blockIdx.z;
    const bf16* Wr = Wr0 + (long)z * wz;
    const bf16* Wi = Wi0 + (long)z * wz;
    const float* br = bias.p[2 * z];
    const float* bi = bias.p[2 * z + 1];
    void* Crv = (char*)Cr0 + (long)z * cz;
    void* Civ = (char*)Ci0 + (long)z * cz;
    if (EXPERT) {
        int e = tileExpert[tm];
        if (e < 0) return;
        Wr += (long)e * westride;  Wi += (long)e * westride;
        br += (long)e * bstride;   bi += (long)e * bstride;
        if (MODRELU) mb += (long)e * bstride;
    }
    int t = threadIdx.x;
    int l = t & 63, jj = t >> 6;
    int riS = jj >> 1, kcS = jj & 1;
    const bf16* Asrc = riS ? Ai : Ar;
    const bf16* Wsrc = riS ? Wi : Wr;
    int kq8 = (l >> 4) * 8;
    long arb[4];
#pragma unroll
    for (int mt = 0; mt < 4; mt++) {
        int grow = tm * 64 + mt * 16 + (l & 15);
        int tok = grow;
        if (GATHER) { int gg = order[grow]; tok = (gg < 0) ? 0 : gg; }
        arb[mt] = (long)tok * lda;
    }
    int wm = jj & 1, wn = jj >> 1;

    f32x4 zf = {0.f, 0.f, 0.f, 0.f};
    f32x4 accR[2][2], accI[2][2];
#pragma unroll
    for (int a = 0; a < 2; a++)
#pragma unroll
        for (int b = 0; b < 2; b++) { accR[a][b] = zf; accI[a][b] = zf; }

    const bf16x8 sgn = {(short)0x8000,(short)0x8000,(short)0x8000,(short)0x8000,
                        (short)0x8000,(short)0x8000,(short)0x8000,(short)0x8000};

    for (int k0 = 0; k0 < Kp; k0 += 64) {
        __syncthreads();
        int lc = k0 + kcS * 32;
        int acol = (X3 && lc >= 2 * Kreal) ? lc - 2 * Kreal : lc;
#pragma unroll
        for (int mt = 0; mt < 4; mt++)
            gload16(Asrc + arb[mt] + acol + kq8,
                    &sA[(((riS * 2 + kcS) << 2) + mt) << 9]);
        int kcl = (k0 >> 5) + kcS;
        int pkc = (X3 && kcl >= kdiv) ? kcl - kdiv : kcl;
        const bf16* wbase = Wsrc + (((long)pkc * ntTot + tn * 4) << 9) + l * 8;
#pragma unroll
        for (int ntl = 0; ntl < 4; ntl++)
            gload16(wbase + (ntl << 9),
                    &sW[(((riS * 2 + kcS) << 2) + ntl) << 9]);
        __syncthreads();
#pragma unroll
        for (int kc = 0; kc < 2; kc++) {
            bf16x8 arf[2], aif[2], naf[2], wrf[2], wif[2];
#pragma unroll
            for (int s = 0; s < 2; s++) {
                arf[s] = *(const bf16x8*)&sA[(((kc << 2) + wm * 2 + s) << 9) + l * 8];
                aif[s] = *(const bf16x8*)&sA[((((2 + kc) << 2) + wm * 2 + s) << 9) + l * 8];
                naf[s] = aif[s] ^ sgn;
                wrf[s] = *(const bf16x8*)&sW[(((kc << 2) + wn * 2 + s) << 9) + l * 8];
                wif[s] = *(const bf16x8*)&sW[((((2 + kc) << 2) + wn * 2 + s) << 9) + l * 8];
            }
#pragma unroll
            for (int sm = 0; sm < 2; sm++)
#pragma unroll
                for (int sn = 0; sn < 2; sn++) {
                    accR[sm][sn] = __builtin_amdgcn_mfma_f32_16x16x32_bf16(arf[sm], wrf[sn], accR[sm][sn], 0, 0, 0);
                    accR[sm][sn] = __builtin_amdgcn_mfma_f32_16x16x32_bf16(naf[sm], wif[sn], accR[sm][sn], 0, 0, 0);
                    accI[sm][sn] = __builtin_amdgcn_mfma_f32_16x16x32_bf16(arf[sm], wif[sn], accI[sm][sn], 0, 0, 0);
                    accI[sm][sn] = __builtin_amdgcn_mfma_f32_16x16x32_bf16(aif[sm], wrf[sn], accI[sm][sn], 0, 0, 0);
                }
        }
    }
#pragma unroll
    for (int sm = 0; sm < 2; sm++)
#pragma unroll
        for (int sn = 0; sn < 2; sn++) {
            int row0 = tm * 64 + (wm * 2 + sm) * 16 + (l >> 4) * 4;
            int col  = tn * 64 + (wn * 2 + sn) * 16 + (l & 15);
            float bre = br[col], bie = bi[col];
            float mbe = MODRELU ? mb[col] : 0.f;
#pragma unroll
            for (int v = 0; v < 4; v++) {
                int row = row0 + v;
                float vr = accR[sm][sn][v] + bre;
                float vi = accI[sm][sn][v] + bie;
                if (MODRELU) {
                    float amp = sqrtf(vr * vr + vi * vi + 1e-10f);
                    float sc = fmaxf(amp + mbe, 0.f) / (amp + 1e-10f);
                    vr *= sc; vi *= sc;
                }
                long cidx = (long)row * ldc + col;
                if (RESID) { vr += Rr[cidx]; vi += Ri[cidx]; }
                if (OUTBF16) {
                    ((bf16*)Crv)[cidx] = __float2bfloat16(vr);
                    ((bf16*)Civ)[cidx] = __float2bfloat16(vi);
                } else {
                    ((float*)Crv)[cidx] = vr;
                    ((float*)Civ)[cidx] = vi;
                }
            }
        }
}

// ------------------- pack K/V into attention LDS fragment image (bf16 hi/lo)
__global__ __launch_bounds__(256)
void pack_kv(const float* __restrict__ kr, const float* __restrict__ ki,
             const float* __restrict__ vr, const float* __restrict__ vi,
             short* __restrict__ pK, short* __restrict__ pV, int Sk)
{
    const int F = FF;
    int kt = blockIdx.x, h = blockIdx.y, b = blockIdx.z;
    int nkt = gridDim.x;
    long blkbase = ((long)((b * 8 + h) * nkt) + kt) * 8192;
    int t = threadIdx.x;
#pragma unroll
    for (int it = 0; it < 2; it++) {
        int s = t + 256 * it;
        int sl = s & 63, g = s >> 6;
        int ri = g >> 2, c = (g >> 1) & 1, nt = g & 1;
        int sq = sl >> 4, sn = sl & 15;
        const float* src = ri ? ki : kr;
        long base = ((long)(b * Sk + kt * 32 + nt * 16 + sn)) * F + h * 64 + c * 32 + sq * 8;
        long outH = blkbase + ((((ri * 2 + 0) * 2 + c) * 2 + nt) * 64 + sl) * 8;
        long outL = blkbase + ((((ri * 2 + 1) * 2 + c) * 2 + nt) * 64 + sl) * 8;
#pragma unroll
        for (int j = 0; j < 8; j++) {
            float x = src[base + j];
            short xh = f2bf(x);
            pK[outH + j] = xh;
            pK[outL + j] = f2bf(x - bf2f(xh));
        }
    }
#pragma unroll
    for (int it = 0; it < 2; it++) {
        int s = t + 256 * it;
        int sl = s & 63, g = s >> 6;
        int ri = g >> 2, nt = g & 3;
        int sq = sl >> 4, sn = sl & 15;
        const float* src = ri ? vi : vr;
        long base = ((long)(b * Sk + kt * 32 + sq * 8)) * F + h * 64 + nt * 16 + sn;
        long outH = blkbase + (((ri * 2 + 0) * 4 + nt) * 64 + sl) * 8;
        long outL = blkbase + (((ri * 2 + 1) * 4 + nt) * 64 + sl) * 8;
#pragma unroll
        for (int j = 0; j < 8; j++) {
            float x = src[base + (long)j * F];
            short xh = f2bf(x);
            pV[outH + j] = xh;
            pV[outL + j] = f2bf(x - bf2f(xh));
        }
    }
}

// ------------------------------- MFMA flash complex attention (bf16x3 exact)
// 1D grid 512; linear%8 (~XCD) owns 4 (b,h) pairs -> K/V packs fit 4MB L2.
__global__ __launch_bounds__(256)
void cattn_mfma(const float* __restrict__ qr, const float* __restrict__ qi,
                const short* __restrict__ pK, const short* __restrict__ pV,
                bf16* __restrict__ dR, bf16* __restrict__ dI,
                int S, int Sk)
{
    __shared__ short sK[8192];
    __shared__ short sV[8192];
    __shared__ short sP[5120];
    const int F = FF;
    int L = blockIdx.x;
    int xcd = L & 7, idx = L >> 3;
    int bh = xcd * 4 + (idx & 3);
    int qt = idx >> 2;
    int b = bh >> 3, h = bh & 7;
    int t = threadIdx.x;
    int w = t >> 6, l = t & 63, q = l >> 4, n16 = l & 15;

    bf16x8 qh_[2][2], ql_[2][2];
    {
        long qbase = ((long)(b * S + qt * 64 + w * 16 + n16)) * F + h * 64 + q * 8;
#pragma unroll
        for (int ri = 0; ri < 2; ri++) {
            const float* src = ri ? qi : qr;
#pragma unroll
            for (int c = 0; c < 2; c++) {
                float vv[8];
                *(float4*)&vv[0] = *(const float4*)&src[qbase + c * 32];
                *(float4*)&vv[4] = *(const float4*)&src[qbase + c * 32 + 4];
#pragma unroll
                for (int j = 0; j < 8; j++) {
                    short xh = f2bf(vv[j]);
                    qh_[ri][c][j] = xh;
                    ql_[ri][c][j] = f2bf(vv[j] - bf2f(xh));
                }
            }
        }
    }

    f32x4 zf = {0.f, 0.f, 0.f, 0.f};
    f32x4 oR[4], oI[4];
#pragma unroll
    for (int nt = 0; nt < 4; nt++) { oR[nt] = zf; oI[nt] = zf; }
    float m_run[4] = {-3.0e38f, -3.0e38f, -3.0e38f, -3.0e38f};
    float l_run[4] = {0.f, 0.f, 0.f, 0.f};

    int nkt = Sk >> 5;
    long pbh = (long)((b * 8 + h) * nkt) * 8192;
    for (int kt = 0; kt < nkt; kt++) {
        __syncthreads();
        long pb = pbh + (long)kt * 8192;
#pragma unroll
        for (int i = 0; i < 4; i++) {
            int bk = w * 4 + i;
            gload16(pK + pb + (bk << 9) + l * 8, &sK[bk << 9]);
            gload16(pV + pb + (bk << 9) + l * 8, &sV[bk << 9]);
        }
        __syncthreads();

        f32x4 sc[2];
        sc[0] = zf; sc[1] = zf;
#pragma unroll
        for (int nt = 0; nt < 2; nt++) {
#pragma unroll
            for (int ri = 0; ri < 2; ri++) {
                bf16x8 kh0 = *(const bf16x8*)&sK[((((ri * 2 + 0) * 2 + 0) * 2 + nt) * 64 + l) * 8];
                bf16x8 kh1 = *(const bf16x8*)&sK[((((ri * 2 + 0) * 2 + 1) * 2 + nt) * 64 + l) * 8];
                bf16x8 kl0 = *(const bf16x8*)&sK[((((ri * 2 + 1) * 2 + 0) * 2 + nt) * 64 + l) * 8];
                bf16x8 kl1 = *(const bf16x8*)&sK[((((ri * 2 + 1) * 2 + 1) * 2 + nt) * 64 + l) * 8];
                sc[nt] = __builtin_amdgcn_mfma_f32_16x16x32_bf16(qh_[ri][0], kh0, sc[nt], 0, 0, 0);
                sc[nt] = __builtin_amdgcn_mfma_f32_16x16x32_bf16(qh_[ri][1], kh1, sc[nt], 0, 0, 0);
                sc[nt] = __builtin_amdgcn_mfma_f32_16x16x32_bf16(ql_[ri][0], kh0, sc[nt], 0, 0, 0);
                sc[nt] = __builtin_amdgcn_mfma_f32_16x16x32_bf16(ql_[ri][1], kh1, sc[nt], 0, 0, 0);
                sc[nt] = __builtin_amdgcn_mfma_f32_16x16x32_bf16(qh_[ri][0], kl0, sc[nt], 0, 0, 0);
                sc[nt] = __builtin_amdgcn_mfma_f32_16x16x32_bf16(qh_[ri][1], kl1, sc[nt], 0, 0, 0);
            }
        }
        float alpha[4];
#pragma unroll
        for (int v = 0; v < 4; v++) {
            float s0 = sc[0][v] * 0.125f, s1 = sc[1][v] * 0.125f;
            float mx = fmaxf(s0, s1);
            mx = fmaxf(mx, __shfl_xor(mx, 1));
            mx = fmaxf(mx, __shfl_xor(mx, 2));
            mx = fmaxf(mx, __shfl_xor(mx, 4));
            mx = fmaxf(mx, __shfl_xor(mx, 8));
            float mnew = fmaxf(m_run[v], mx);
            float p0 = __expf(s0 - mnew), p1 = __expf(s1 - mnew);
            sc[0][v] = p0; sc[1][v] = p1;
            float ps = p0 + p1;
            ps += __shfl_xor(ps, 1);
            ps += __shfl_xor(ps, 2);
            ps += __shfl_xor(ps, 4);
            ps += __shfl_xor(ps, 8);
            alpha[v] = __expf(m_run[v] - mnew);
            l_run[v] = l_run[v] * alpha[v] + ps;
            m_run[v] = mnew;
        }
#pragma unroll
        for (int nt = 0; nt < 4; nt++)
#pragma unroll
            for (int v = 0; v < 4; v++) { oR[nt][v] *= alpha[v]; oI[nt][v] *= alpha[v]; }
        int pbase = w * 1280;
#pragma unroll
        for (int nt = 0; nt < 2; nt++)
#pragma unroll
            for (int v = 0; v < 4; v++) {
                float p = sc[nt][v];
                short ph = f2bf(p);
                short pl = f2bf(p - bf2f(ph));
                int idxp = pbase + (q * 4 + v) * 40 + nt * 16 + n16;
                sP[idxp] = ph;
                sP[idxp + 640] = pl;
            }
        bf16x8 pH = *(const bf16x8*)&sP[pbase + n16 * 40 + q * 8];
        bf16x8 pL = *(const bf16x8*)&sP[pbase + 640 + n16 * 40 + q * 8];
#pragma unroll
        for (int nt = 0; nt < 4; nt++) {
            bf16x8 vh = *(const bf16x8*)&sV[(((0 * 2 + 0) * 4 + nt) * 64 + l) * 8];
            bf16x8 vl = *(const bf16x8*)&sV[(((0 * 2 + 1) * 4 + nt) * 64 + l) * 8];
            oR[nt] = __builtin_amdgcn_mfma_f32_16x16x32_bf16(pH, vh, oR[nt], 0, 0, 0);
            oR[nt] = __builtin_amdgcn_mfma_f32_16x16x32_bf16(pL, vh, oR[nt], 0, 0, 0);
            oR[nt] = __builtin_amdgcn_mfma_f32_16x16x32_bf16(pH, vl, oR[nt], 0, 0, 0);
            bf16x8 wh = *(const bf16x8*)&sV[(((1 * 2 + 0) * 4 + nt) * 64 + l) * 8];
            bf16x8 wl2 = *(const bf16x8*)&sV[(((1 * 2 + 1) * 4 + nt) * 64 + l) * 8];
            oI[nt] = __builtin_amdgcn_mfma_f32_16x16x32_bf16(pH, wh, oI[nt], 0, 0, 0);
            oI[nt] = __builtin_amdgcn_mfma_f32_16x16x32_bf16(pL, wh, oI[nt], 0, 0, 0);
            oI[nt] = __builtin_amdgcn_mfma_f32_16x16x32_bf16(pH, wl2, oI[nt], 0, 0, 0);
        }
    }
    // ---- epilogue: write [Ah|Al] expanded rows of A1 directly
#pragma unroll
    for (int v = 0; v < 4; v++) {
        float inv = 1.0f / l_run[v];
        long rbase = ((long)(b * S + qt * 64 + w * 16 + q * 4 + v)) * 1024;
#pragma unroll
        for (int nt = 0; nt < 4; nt++) {
            int col = h * 64 + nt * 16 + n16;
            float vr = oR[nt][v] * inv;
            bf16 hh = __float2bfloat16(vr);
            dR[rbase + col] = hh;
            dR[rbase + 512 + col] = __float2bfloat16(vr - __bfloat162float(hh));
            float vi = oI[nt][v] * inv;
            bf16 hi2 = __float2bfloat16(vi);
            dI[rbase + col] = hi2;
            dI[rbase + 512 + col] = __float2bfloat16(vi - __bfloat162float(hi2));
        }
    }
}

// ---------------------------------------------------- MoE routing tables
__global__ __launch_bounds__(256)
void moe_build_kernel(const int* __restrict__ eidx, int* __restrict__ order,
                      int* __restrict__ te128, int* __restrict__ te64)
{
    __shared__ int cnt[NEXP], segbase[NEXP], cursor[NEXP], tb128[NEXP], n128[NEXP];
    int t = threadIdx.x;
    if (t < NEXP) { cnt[t] = 0; cursor[t] = 0; }
    __syncthreads();
    for (int i = t; i < NTOK; i += 256) atomicAdd(&cnt[eidx[i]], 1);
    __syncthreads();
    if (t == 0) {
        int ob = 0, tb = 0;
        for (int e = 0; e < NEXP; e++) {
            segbase[e] = ob; tb128[e] = tb;
            int tiles = (cnt[e] + 127) >> 7;
            n128[e] = tiles;
            ob += tiles << 7; tb += tiles;
        }
    }
    __syncthreads();
    for (int i = t; i < NPAD128; i += 256) order[i] = -1;
    if (t < TMAX128) {
        int ex = -1;
        for (int e = 0; e < NEXP; e++)
            if (t >= tb128[e] && t < tb128[e] + n128[e]) ex = e;
        te128[t] = ex;
    }
    if (t >= 64 && t < 64 + 2 * TMAX128) {
        int tt = t - 64;
        int ex = -1;
        for (int e = 0; e < NEXP; e++)
            if (tt >= tb128[e] * 2 && tt < (tb128[e] + n128[e]) * 2) ex = e;
        te64[tt] = ex;
    }
    __syncthreads();
    for (int i = t; i < NTOK; i += 256) {
        int e = eidx[i];
        int pos = atomicAdd(&cursor[e], 1);
        order[segbase[e] + pos] = i;
    }
}

__global__ __launch_bounds__(256)
void combine_kernel(const int* __restrict__ order,
                    const float* __restrict__ xr, const float* __restrict__ xi,
                    const float* __restrict__ yr, const float* __restrict__ yi,
                    float* __restrict__ out)
{
    const int F = FF;
    int p = blockIdx.x;
    int tok = order[p];
    if (tok < 0) return;
    int t = threadIdx.x;
    float* outr = out;
    float* outi = out + (long)NTOK * FF;
#pragma unroll
    for (int u = 0; u < 2; u++) {
        int j = t + u * 256;
        long src = (long)p * F + j;
        long dst = (long)tok * F + j;
        outr[dst] = xr[dst] + yr[src];
        outi[dst] = xi[dst] + yi[src];
    }
}

// ------------------------------------------------------------------- launch
extern "C" void kernel_launch(void* const* d_in, const int* in_sizes, int n_in,
                              void* d_out, int out_size, void* d_ws, size_t ws_size,
                              hipStream_t stream)
{
    (void)in_sizes; (void)n_in; (void)out_size; (void)ws_size;
    const float* x_r   = (const float*)d_in[0];
    const float* x_i   = (const float*)d_in[1];
    const float* ctx_r = (const float*)d_in[2];
    const float* ctx_i = (const float*)d_in[3];
    const float* ln1_g = (const float*)d_in[4];
    const float* ln2_g = (const float*)d_in[5];
    const float* ln3_g = (const float*)d_in[6];
    const float* sa_qWr = (const float*)d_in[7];   const float* sa_qWi = (const float*)d_in[8];
    const float* sa_qbr = (const float*)d_in[9];   const float* sa_qbi = (const float*)d_in[10];
    const float* sa_kWr = (const float*)d_in[11];  const float* sa_kWi = (const float*)d_in[12];
    const float* sa_kbr = (const float*)d_in[13];  const float* sa_kbi = (const float*)d_in[14];
    const float* sa_vWr = (const float*)d_in[15];  const float* sa_vWi = (const float*)d_in[16];
    const float* sa_vbr = (const float*)d_in[17];  const float* sa_vbi = (const float*)d_in[18];
    const float* sa_oWr = (const float*)d_in[19];  const float* sa_oWi = (const float*)d_in[20];
    const float* sa_obr = (const float*)d_in[21];  const float* sa_obi = (const float*)d_in[22];
    const float* ca_qWr = (const float*)d_in[23];  const float* ca_qWi = (const float*)d_in[24];
    const float* ca_qbr = (const float*)d_in[25];  const float* ca_qbi = (const float*)d_in[26];
    const float* ca_kWr = (const float*)d_in[27];  const float* ca_kWi = (const float*)d_in[28];
    const float* ca_kbr = (const float*)d_in[29];  const float* ca_kbi = (const float*)d_in[30];
    const float* ca_vWr = (const float*)d_in[31];  const float* ca_vWi = (const float*)d_in[32];
    const float* ca_vbr = (const float*)d_in[33];  const float* ca_vbi = (const float*)d_in[34];
    const float* ca_oWr = (const float*)d_in[35];  const float* ca_oWi = (const float*)d_in[36];
    const float* ca_obr = (const float*)d_in[37];  const float* ca_obi = (const float*)d_in[38];
    const float* moe_W1r = (const float*)d_in[39]; const float* moe_W1i = (const float*)d_in[40];
    const float* moe_b1r = (const float*)d_in[41]; const float* moe_b1i = (const float*)d_in[42];
    const float* moe_mb  = (const float*)d_in[43];
    const float* moe_W2r = (const float*)d_in[44]; const float* moe_W2i = (const float*)d_in[45];
    const float* moe_b2r = (const float*)d_in[46]; const float* moe_b2i = (const float*)d_in[47];
    float* out = (float*)d_out;

    char* W = (char*)d_ws;
    const long NF = (long)NTOK * FF;
    const long NF4 = NF * 4;                      // 8 MB
    float* xr = (float*)(W + 0 * NF4);
    float* xi = (float*)(W + 1 * NF4);
    char* base2 = W + 2 * NF4;                    // 16.8 MB region
    short* pKbuf = (short*)base2;                 // attention phase
    bf16* h3r = (bf16*)base2;                     // MoE phase
    bf16* h3i = (bf16*)(base2 + 4194304);
    char* poolB = W + 4 * NF4;                    // 67.1 MB pool
    float* qr = (float*)poolB;                float* qi = (float*)(poolB + NF4);
    float* kr = (float*)(poolB + 2 * NF4);    float* ki = (float*)(poolB + 3 * NF4);
    float* vr = (float*)(poolB + 4 * NF4);    float* vi = (float*)(poolB + 5 * NF4);
    short* pVbuf = (short*)(poolB + 6 * NF4);     // attention phase (16 MB)
    bf16* u_r = (bf16*)poolB;                     // MoE overlay: 5120x2048
    bf16* u_i = (bf16*)(poolB + 20971520);
    float* y_r = (float*)(poolB + 41943040);      // 5120x512 f32
    float* y_i = (float*)(poolB + 52428800);
    char* Q = W + 12 * NF4;
    bf16* A1r = (bf16*)Q;                         // 4096x1024
    bf16* A1i = (bf16*)(Q + 8388608);
    bf16* A2r = (bf16*)(Q + 16777216);            // 1024x1536
    bf16* A2i = (bf16*)(Q + 19922944);
    char* WQ = Q + 23068672;
    const long PS1 = 524288;
    const long PS2 = 786432;
    bf16* saq_r = (bf16*)(WQ);                   bf16* saq_i = saq_r + PS1;
    bf16* sak_r = saq_r + 2 * PS1;               bf16* sak_i = saq_r + 3 * PS1;
    bf16* sav_r = saq_r + 4 * PS1;               bf16* sav_i = saq_r + 5 * PS1;
    bf16* sao_r = saq_r + 6 * PS1;               bf16* sao_i = saq_r + 7 * PS1;
    bf16* caq_r = saq_r + 8 * PS1;               bf16* caq_i = saq_r + 9 * PS1;
    bf16* cao_r = saq_r + 10 * PS1;              bf16* cao_i = saq_r + 11 * PS1;
    bf16* cak_r = saq_r + 12 * PS1;              bf16* cak_i = cak_r + PS2;
    bf16* cav_r = cak_r + 2 * PS2;               bf16* cav_i = cak_r + 3 * PS2;
    bf16* Wm_r = (bf16*)Q;                        // MoE weight overlay
    bf16* Wm_i = (bf16*)(Q + 16777216);
    char* ints = W + 12 * NF4 + 41943040 + 524288;   // past WQ end, padded
    int* eidx  = (int*)ints;
    int* order = eidx + NTOK;
    int* te128 = order + NPAD128;
    int* te64  = te128 + 64;

    dim3 blk(256);
    const long W1S = (long)FF * HID;
    const long CZ = 2 * NF4;
    Ptr6 bQKV = {{sa_qbr, sa_qbi, sa_kbr, sa_kbi, sa_vbr, sa_vbi}};
    Ptr6 bSAO = {{sa_obr, sa_obi, 0, 0, 0, 0}};
    Ptr6 bCAQ = {{ca_qbr, ca_qbi, 0, 0, 0, 0}};
    Ptr6 bCKV = {{ca_kbr, ca_kbi, ca_vbr, ca_vbi, 0, 0}};
    Ptr6 bCAO = {{ca_obr, ca_obi, 0, 0, 0, 0}};
    Ptr6 bM1  = {{moe_b1r, moe_b1i, 0, 0, 0, 0}};
    Ptr6 bM2  = {{moe_b2r, moe_b2i, 0, 0, 0, 0}};

    // ---- all 8 attention weight packs in one dispatch
    WPackAll wp;
    wp.sR[0]=sa_qWr; wp.sI[0]=sa_qWi; wp.dR[0]=saq_r; wp.dI[0]=saq_i; wp.kdiv[0]=16;
    wp.sR[1]=sa_kWr; wp.sI[1]=sa_kWi; wp.dR[1]=sak_r; wp.dI[1]=sak_i; wp.kdiv[1]=16;
    wp.sR[2]=sa_vWr; wp.sI[2]=sa_vWi; wp.dR[2]=sav_r; wp.dI[2]=sav_i; wp.kdiv[2]=16;
    wp.sR[3]=sa_oWr; wp.sI[3]=sa_oWi; wp.dR[3]=sao_r; wp.dI[3]=sao_i; wp.kdiv[3]=16;
    wp.sR[4]=ca_qWr; wp.sI[4]=ca_qWi; wp.dR[4]=caq_r; wp.dI[4]=caq_i; wp.kdiv[4]=16;
    wp.sR[5]=ca_oWr; wp.sI[5]=ca_oWi; wp.dR[5]=cao_r; wp.dI[5]=cao_i; wp.kdiv[5]=16;
    wp.sR[6]=ca_kWr; wp.sI[6]=ca_kWi; wp.dR[6]=cak_r; wp.dI[6]=cak_i; wp.kdiv[6]=24;
    wp.sR[7]=ca_vWr; wp.sI[7]=ca_vWi; wp.dR[7]=cav_r; wp.dI[7]=cav_i; wp.kdiv[7]=24;
    expandW_all<<<dim3(8, 48, 8), blk, 0, stream>>>(wp);

    // ---- self-attention block
    cln_expand<<<NTOK, blk, 0, stream>>>(x_r, x_i, ln1_g, A1r, A1i);
    cgemm128<true,false,false,false,false><<<dim3(32, 4, 3), blk, 0, stream>>>(
        A1r, A1i, 1024, 512, saq_r, saq_i, 2 * PS1, 0, 32, 16,
        bQKV, 0, nullptr, qr, qi, CZ, FF, 1536, 0, nullptr, nullptr);
    pack_kv<<<dim3(32, 8, 4), blk, 0, stream>>>(kr, ki, vr, vi, pKbuf, pVbuf, 1024);
    cattn_mfma<<<512, blk, 0, stream>>>(qr, qi, pKbuf, pVbuf, A1r, A1i, 1024, 1024);
    cgemm_mfma<true,false,false,false,true,false><<<dim3(64, 8, 1), blk, 0, stream>>>(
        A1r, A1i, 1024, 512, sao_r, sao_i, 0, 0, 32, 16,
        bSAO, 0, nullptr, x_r, x_i, xr, xi, 0, FF, 1536, nullptr, nullptr);

    // ---- cross-attention block
    cln_expand<<<NTOK, blk, 0, stream>>>(xr, xi, ln2_g, A1r, A1i);
    cgemm_mfma<true,false,false,false,false,false><<<dim3(64, 8, 1), blk, 0, stream>>>(
        A1r, A1i, 1024, 512, caq_r, caq_i, 0, 0, 32, 16,
        bCAQ, 0, nullptr, nullptr, nullptr, qr, qi, 0, FF, 1536, nullptr, nullptr);
    expandA_x2<<<dim3(3, 1024), blk, 0, stream>>>(ctx_r, ctx_i, A2r, A2i, CDIM);
    cgemm_mfma<true,false,false,false,false,false><<<dim3(16, 8, 2), blk, 0, stream>>>(
        A2r, A2i, 1536, 768, cak_r, cak_i, 2 * PS2, 0, 32, 24,
        bCKV, 0, nullptr, nullptr, nullptr, kr, ki, CZ, FF, 2304, nullptr, nullptr);
    pack_kv<<<dim3(8, 8, 4), blk, 0, stream>>>(kr, ki, vr, vi, pKbuf, pVbuf, 256);
    cattn_mfma<<<512, blk, 0, stream>>>(qr, qi, pKbuf, pVbuf, A1r, A1i, 1024, 256);
    cgemm_mfma<true,false,false,false,true,false><<<dim3(64, 8, 1), blk, 0, stream>>>(
        A1r, A1i, 1024, 512, cao_r, cao_i, 0, 0, 32, 16,
        bCAO, 0, nullptr, xr, xi, xr, xi, 0, FF, 1536, nullptr, nullptr);

    // ---- phase-routed MoE
    cln_route<<<NTOK, blk, 0, stream>>>(xr, xi, ln3_g, h3r, h3i, eidx);
    moe_build_kernel<<<1, blk, 0, stream>>>(eidx, order, te128, te64);
    convW_packed<<<dim3(32, 16, 8), blk, 0, stream>>>(moe_W1r, moe_W1i, Wm_r, Wm_i, HID, W1S);
    // L1: 1D grid 640 = 8 xcd-bands x (5 tm x 16 tn); band=5
    cgemm128<false,true,true,true,true><<<640, blk, 0, stream>>>(
        h3r, h3i, 512, 512, Wm_r, Wm_i, 0, W1S, 128, 0,
        bM1, HID, moe_mb, u_r, u_i, 0, HID, 512, 5, order, te128);
    convW_packed<<<dim3(8, 64, 8), blk, 0, stream>>>(moe_W2r, moe_W2i, Wm_r, Wm_i, FF, W1S);
    // L2: 128-tile, 1D grid 160 = 8 xcd-bands x (5 tm x 4 tn); band=5
    cgemm128<false,true,false,false,false><<<160, blk, 0, stream>>>(
        u_r, u_i, 2048, 2048, Wm_r, Wm_i, 0, W1S, 32, 0,
        bM2, FF, nullptr, y_r, y_i, 0, FF, 2048, 5, nullptr, te128);
    combine_kernel<<<NPAD128, blk, 0, stream>>>(order, xr, xi, y_r, y_i, out);
}